// Round 5
// baseline (1500.044 us; speedup 1.0000x reference)
//
#include <hip/hip_runtime.h>
#include <hip/hip_bf16.h>
#include <stdint.h>

#define BB 2
#define LLEN 1024
#define MM 25
#define KK 32

// d_out is FLOAT32 (reference outputs are f32), concatenated in return order:
// (V, E, E_idx, Y_nodes, Y_edges, Y_m) — offsets in f32 elements.
#define OFF_V   0
#define OFF_E   6553600
#define OFF_EI  14942208
#define OFF_YN  15007744
#define OFF_YE  21561344
#define OFF_YM  185401344

__constant__ int g_PA[24] = {0,2,3,4,1,1,1,1,0,0,0,4,4,3,0,2,3,4,2,3,4,2,3,2};
__constant__ int g_PB[24] = {0,2,3,4,0,2,3,4,2,3,4,2,3,2,1,1,1,1,0,0,0,4,4,3};

__device__ __forceinline__ float rbf_val(float d, int r) {
    float mu = 2.0f + (20.0f / 15.0f) * (float)r;
    float z = (d - mu) * 0.8f;   // /1.25
    return __expf(-z * z);
}

// ---------------------------------------------------------------- top-k kernel
__global__ __launch_bounds__(256) void k_topk(
    const float* __restrict__ X, const float* __restrict__ mask,
    int* __restrict__ eidx, float* __restrict__ dnb,
    float* __restrict__ outEI)
{
    __shared__ float sD[LLEN];
    __shared__ float sMaxA[256];
    __shared__ unsigned long long sB[256];
    int row = blockIdx.x;            // b*L + i
    int b = row >> 10, i = row & 1023;
    int tid = threadIdx.x;
    const float* Xb = X + (size_t)b * LLEN * 12;
    float cax = Xb[i*12+3], cay = Xb[i*12+4], caz = Xb[i*12+5];
    float mi = mask[row];
    float lmax = 0.0f;
    for (int j = tid; j < LLEN; j += 256) {
        float dx = cax - Xb[j*12+3];
        float dy = cay - Xb[j*12+4];
        float dz = caz - Xb[j*12+5];
        float d = sqrtf(dx*dx + dy*dy + dz*dz + 1e-6f) * (mi * mask[b*LLEN + j]);
        sD[j] = d;
        lmax = fmaxf(lmax, d);
    }
    sMaxA[tid] = lmax;
    __syncthreads();
    for (int w = 128; w > 0; w >>= 1) {
        if (tid < w) sMaxA[tid] = fmaxf(sMaxA[tid], sMaxA[tid + w]);
        __syncthreads();
    }
    float rmax = sMaxA[0];
    for (int j = tid; j < LLEN; j += 256) {
        float m2 = mi * mask[b*LLEN + j];
        sD[j] = sD[j] + (1.0f - m2) * rmax;
    }
    __syncthreads();
    for (int it = 0; it < KK; ++it) {
        unsigned long long best = ~0ull;
        for (int j = tid; j < LLEN; j += 256) {
            unsigned long long p = ((unsigned long long)__float_as_uint(sD[j]) << 32) | (unsigned)j;
            if (p < best) best = p;
        }
        sB[tid] = best;
        __syncthreads();
        for (int w = 128; w > 0; w >>= 1) {
            if (tid < w) { if (sB[tid + w] < sB[tid]) sB[tid] = sB[tid + w]; }
            __syncthreads();
        }
        if (tid == 0) {
            unsigned long long wv = sB[0];
            int jw = (int)(wv & 0xffffffffu);
            float dv = __uint_as_float((unsigned)(wv >> 32));
            sD[jw] = __uint_as_float(0x7f800000u);   // +inf
            eidx[row*KK + it] = jw;
            dnb[row*KK + it] = dv;
            outEI[row*KK + it] = (float)jw;
        }
        __syncthreads();
    }
}

// ---------------------------------------------------------------- edge kernel
#define FSTR 420
__global__ __launch_bounds__(256) void k_edges(
    const float* __restrict__ X,
    const int* __restrict__ Ridx, const int* __restrict__ chain,
    const float* __restrict__ posW, const float* __restrict__ posb,
    const float* __restrict__ edgeW,
    const float* __restrict__ lnEg, const float* __restrict__ lnEb,
    const int* __restrict__ eidx, const float* __restrict__ dnb,
    float* __restrict__ outE)
{
    __shared__ float fls[KK * FSTR];     // 32 x 416 feature rows (padded)
    __shared__ float aj[KK][16];         // neighbor atoms: N,Ca,C,O,Cb (15 floats)
    __shared__ float ai[16];
    __shared__ int   didx[KK];
    int row = blockIdx.x;
    int b = row >> 10, i = row & 1023;
    int tid = threadIdx.x;
    const float* Xb = X + (size_t)b * LLEN * 12;

    if (tid < KK) {
        int k = tid;
        int j = eidx[row*KK + k];
        const float* xr = Xb + j*12;
        float nx=xr[0], ny=xr[1], nz=xr[2];
        float ax=xr[3], ay=xr[4], az=xr[5];
        float cx=xr[6], cy=xr[7], cz=xr[8];
        float bx=ax-nx, by=ay-ny, bz=az-nz;
        float vx=cx-ax, vy=cy-ay, vz=cz-az;
        float qx = by*vz - bz*vy, qy = bz*vx - bx*vz, qz = bx*vy - by*vx;
        aj[k][0]=nx; aj[k][1]=ny; aj[k][2]=nz;
        aj[k][3]=ax; aj[k][4]=ay; aj[k][5]=az;
        aj[k][6]=cx; aj[k][7]=cy; aj[k][8]=cz;
        aj[k][9]=xr[9]; aj[k][10]=xr[10]; aj[k][11]=xr[11];
        aj[k][12] = -0.58273431f*qx + 0.56802827f*bx - 0.54067466f*vx + ax;
        aj[k][13] = -0.58273431f*qy + 0.56802827f*by - 0.54067466f*vy + ay;
        aj[k][14] = -0.58273431f*qz + 0.56802827f*bz - 0.54067466f*vz + az;
        int off = Ridx[row] - Ridx[b*LLEN + j];
        int ec = (chain[row] == chain[b*LLEN + j]) ? 1 : 0;
        int dc = off + 32; dc = dc < 0 ? 0 : (dc > 64 ? 64 : dc);
        didx[k] = ec ? dc : 65;
    }
    if (tid == 64) {
        const float* xr = Xb + i*12;
        float nx=xr[0], ny=xr[1], nz=xr[2];
        float ax=xr[3], ay=xr[4], az=xr[5];
        float cx=xr[6], cy=xr[7], cz=xr[8];
        float bx=ax-nx, by=ay-ny, bz=az-nz;
        float vx=cx-ax, vy=cy-ay, vz=cz-az;
        float qx = by*vz - bz*vy, qy = bz*vx - bx*vz, qz = bx*vy - by*vx;
        ai[0]=nx; ai[1]=ny; ai[2]=nz;
        ai[3]=ax; ai[4]=ay; ai[5]=az;
        ai[6]=cx; ai[7]=cy; ai[8]=cz;
        ai[9]=xr[9]; ai[10]=xr[10]; ai[11]=xr[11];
        ai[12] = -0.58273431f*qx + 0.56802827f*bx - 0.54067466f*vx + ax;
        ai[13] = -0.58273431f*qy + 0.56802827f*by - 0.54067466f*vy + ay;
        ai[14] = -0.58273431f*qz + 0.56802827f*bz - 0.54067466f*vz + az;
    }
    __syncthreads();

    for (int item = tid; item < KK * 26; item += 256) {
        int k = item / 26, it = item - k * 26;
        float* f = fls + k * FSTR;
        if (it == 0) {
            int d = didx[k];
            #pragma unroll
            for (int c = 0; c < 16; ++c) f[c] = posW[d*16 + c] + posb[c];
        } else {
            float dist;
            if (it == 1) {
                dist = dnb[row*KK + k];
            } else {
                int p = it - 2;
                int a = g_PA[p], q = g_PB[p];
                float dx = ai[a*3+0] - aj[k][q*3+0];
                float dy = ai[a*3+1] - aj[k][q*3+1];
                float dz = ai[a*3+2] - aj[k][q*3+2];
                dist = sqrtf(dx*dx + dy*dy + dz*dz + 1e-6f);
            }
            int base = 16 + (it - 1) * 16;
            #pragma unroll
            for (int r = 0; r < 16; ++r) f[base + r] = rbf_val(dist, r);
        }
    }
    __syncthreads();

    int k = tid >> 3, q = tid & 7, n0 = q * 16;
    float acc[16];
    #pragma unroll
    for (int u = 0; u < 16; ++u) acc[u] = 0.0f;
    const float* fk = fls + k * FSTR;
    #pragma unroll 4
    for (int c = 0; c < 416; ++c) {
        float v = fk[c];
        const float4* w = (const float4*)(edgeW + (size_t)c * 128 + n0);
        float4 w0 = w[0], w1 = w[1], w2 = w[2], w3 = w[3];
        acc[0]  = fmaf(v, w0.x, acc[0]);  acc[1]  = fmaf(v, w0.y, acc[1]);
        acc[2]  = fmaf(v, w0.z, acc[2]);  acc[3]  = fmaf(v, w0.w, acc[3]);
        acc[4]  = fmaf(v, w1.x, acc[4]);  acc[5]  = fmaf(v, w1.y, acc[5]);
        acc[6]  = fmaf(v, w1.z, acc[6]);  acc[7]  = fmaf(v, w1.w, acc[7]);
        acc[8]  = fmaf(v, w2.x, acc[8]);  acc[9]  = fmaf(v, w2.y, acc[9]);
        acc[10] = fmaf(v, w2.z, acc[10]); acc[11] = fmaf(v, w2.w, acc[11]);
        acc[12] = fmaf(v, w3.x, acc[12]); acc[13] = fmaf(v, w3.y, acc[13]);
        acc[14] = fmaf(v, w3.z, acc[14]); acc[15] = fmaf(v, w3.w, acc[15]);
    }
    float s = 0.0f;
    #pragma unroll
    for (int u = 0; u < 16; ++u) s += acc[u];
    s += __shfl_xor(s, 1); s += __shfl_xor(s, 2); s += __shfl_xor(s, 4);
    float mean = s * (1.0f/128.0f);
    float s2 = 0.0f;
    #pragma unroll
    for (int u = 0; u < 16; ++u) { float c0 = acc[u] - mean; s2 += c0*c0; }
    s2 += __shfl_xor(s2, 1); s2 += __shfl_xor(s2, 2); s2 += __shfl_xor(s2, 4);
    float var = s2 * (1.0f/128.0f);
    float inv = rsqrtf(var + 1e-5f);
    float4 o4[4];
    #pragma unroll
    for (int g4 = 0; g4 < 4; ++g4) {
        float* e = (float*)&o4[g4];
        #pragma unroll
        for (int j = 0; j < 4; ++j) {
            int u = g4*4 + j;
            e[j] = (acc[u] - mean)*inv*lnEg[n0+u] + lnEb[n0+u];
        }
    }
    float4* dst = (float4*)(outE + (size_t)row * KK * 128 + (size_t)k * 128 + n0);
    dst[0] = o4[0]; dst[1] = o4[1]; dst[2] = o4[2]; dst[3] = o4[3];
}

// ---------------------------------------------------------------- node (V) kernel
#define FSTR2 149
__global__ __launch_bounds__(256) void k_nodes(
    const float* __restrict__ X, const float* __restrict__ Y,
    const int* __restrict__ Yt,
    const float* __restrict__ typeW, const float* __restrict__ typeb,
    const int* __restrict__ ptab,
    const float* __restrict__ npdW, const float* __restrict__ npdb,
    const float* __restrict__ lnNg, const float* __restrict__ lnNb,
    float* __restrict__ outV)
{
    __shared__ float fls[MM * FSTR2];
    __shared__ float sat[15];   // N,Ca,C,O,Cb
    __shared__ float sfr[9];    // e1,e2,e3
    int row = blockIdx.x;
    int b = row >> 10, i = row & 1023;
    int tid = threadIdx.x;

    if (tid == 0) {
        const float* xr = X + ((size_t)b * LLEN + i) * 12;
        float nx=xr[0], ny=xr[1], nz=xr[2];
        float ax=xr[3], ay=xr[4], az=xr[5];
        float cx=xr[6], cy=xr[7], cz=xr[8];
        float bx=ax-nx, by=ay-ny, bz=az-nz;
        float vx=cx-ax, vy=cy-ay, vz=cz-az;
        float qx = by*vz - bz*vy, qy = bz*vx - bx*vz, qz = bx*vy - by*vx;
        sat[0]=nx; sat[1]=ny; sat[2]=nz;
        sat[3]=ax; sat[4]=ay; sat[5]=az;
        sat[6]=cx; sat[7]=cy; sat[8]=cz;
        sat[9]=xr[9]; sat[10]=xr[10]; sat[11]=xr[11];
        sat[12] = -0.58273431f*qx + 0.56802827f*bx - 0.54067466f*vx + ax;
        sat[13] = -0.58273431f*qy + 0.56802827f*by - 0.54067466f*vy + ay;
        sat[14] = -0.58273431f*qz + 0.56802827f*bz - 0.54067466f*vz + az;
        float e1x = nx-ax, e1y = ny-ay, e1z = nz-az;
        float n1 = fmaxf(sqrtf(e1x*e1x+e1y*e1y+e1z*e1z), 1e-12f);
        e1x/=n1; e1y/=n1; e1z/=n1;
        float dd = e1x*vx + e1y*vy + e1z*vz;
        float u2x = vx - e1x*dd, u2y = vy - e1y*dd, u2z = vz - e1z*dd;
        float n2 = fmaxf(sqrtf(u2x*u2x+u2y*u2y+u2z*u2z), 1e-12f);
        u2x/=n2; u2y/=n2; u2z/=n2;
        float e3x = e1y*u2z - e1z*u2y;
        float e3y = e1z*u2x - e1x*u2z;
        float e3z = e1x*u2y - e1y*u2x;
        sfr[0]=e1x; sfr[1]=e1y; sfr[2]=e1z;
        sfr[3]=u2x; sfr[4]=u2y; sfr[5]=u2z;
        sfr[6]=e3x; sfr[7]=e3y; sfr[8]=e3z;
    }
    __syncthreads();
    const float* Yb = Y + (size_t)row * MM * 3;
    for (int item = tid; item < MM * 10; item += 256) {
        int m = item / 10, it = item - m * 10;
        float* f = fls + m * FSTR2;
        if (it < 5) {
            float dx = sat[it*3+0] - Yb[m*3+0];
            float dy = sat[it*3+1] - Yb[m*3+1];
            float dz = sat[it*3+2] - Yb[m*3+2];
            float dist = sqrtf(dx*dx + dy*dy + dz*dz + 1e-6f);
            #pragma unroll
            for (int r = 0; r < 16; ++r) f[it*16 + r] = rbf_val(dist, r);
        } else if (it < 9) {
            int qq = it - 5;
            int t = Yt[row*MM + m];
            int p1 = ptab[120 + t], p2 = ptab[240 + t];
            #pragma unroll
            for (int c = 0; c < 16; ++c) {
                int cc = qq*16 + c;
                f[80 + cc] = typeW[t*64 + cc] + typeW[(120+p1)*64 + cc]
                           + typeW[(139+p2)*64 + cc] + typeb[cc];
            }
        } else {
            float vx = Yb[m*3+0] - sat[3];
            float vy = Yb[m*3+1] - sat[4];
            float vz = Yb[m*3+2] - sat[5];
            float l0 = sfr[0]*vx + sfr[1]*vy + sfr[2]*vz;
            float l1 = sfr[3]*vx + sfr[4]*vy + sfr[5]*vz;
            float l2 = sfr[6]*vx + sfr[7]*vy + sfr[8]*vz;
            float rxy  = sqrtf(l0*l0 + l1*l1 + 1e-8f);
            float rxyz = sqrtf(l0*l0 + l1*l1 + l2*l2) + 1e-8f;
            f[144] = l0 / rxy;
            f[145] = l1 / rxy;
            f[146] = rxy / rxyz;
            f[147] = l2 / rxyz;
        }
    }
    __syncthreads();
    int k = tid >> 3, q = tid & 7, n0 = q * 16;
    if (k < MM) {
        float acc[16];
        #pragma unroll
        for (int u = 0; u < 16; ++u) acc[u] = 0.0f;
        const float* fk = fls + k * FSTR2;
        #pragma unroll 4
        for (int c = 0; c < 148; ++c) {
            float v = fk[c];
            const float4* w = (const float4*)(npdW + (size_t)c * 128 + n0);
            float4 w0 = w[0], w1 = w[1], w2 = w[2], w3 = w[3];
            acc[0]  = fmaf(v, w0.x, acc[0]);  acc[1]  = fmaf(v, w0.y, acc[1]);
            acc[2]  = fmaf(v, w0.z, acc[2]);  acc[3]  = fmaf(v, w0.w, acc[3]);
            acc[4]  = fmaf(v, w1.x, acc[4]);  acc[5]  = fmaf(v, w1.y, acc[5]);
            acc[6]  = fmaf(v, w1.z, acc[6]);  acc[7]  = fmaf(v, w1.w, acc[7]);
            acc[8]  = fmaf(v, w2.x, acc[8]);  acc[9]  = fmaf(v, w2.y, acc[9]);
            acc[10] = fmaf(v, w2.z, acc[10]); acc[11] = fmaf(v, w2.w, acc[11]);
            acc[12] = fmaf(v, w3.x, acc[12]); acc[13] = fmaf(v, w3.y, acc[13]);
            acc[14] = fmaf(v, w3.z, acc[14]); acc[15] = fmaf(v, w3.w, acc[15]);
        }
        #pragma unroll
        for (int u = 0; u < 16; ++u) acc[u] += npdb[n0 + u];
        float s = 0.0f;
        #pragma unroll
        for (int u = 0; u < 16; ++u) s += acc[u];
        s += __shfl_xor(s, 1); s += __shfl_xor(s, 2); s += __shfl_xor(s, 4);
        float mean = s * (1.0f/128.0f);
        float s2 = 0.0f;
        #pragma unroll
        for (int u = 0; u < 16; ++u) { float c0 = acc[u] - mean; s2 += c0*c0; }
        s2 += __shfl_xor(s2, 1); s2 += __shfl_xor(s2, 2); s2 += __shfl_xor(s2, 4);
        float var = s2 * (1.0f/128.0f);
        float inv = rsqrtf(var + 1e-5f);
        float4 o4[4];
        #pragma unroll
        for (int g4 = 0; g4 < 4; ++g4) {
            float* e = (float*)&o4[g4];
            #pragma unroll
            for (int j = 0; j < 4; ++j) {
                int u = g4*4 + j;
                e[j] = (acc[u] - mean)*inv*lnNg[n0+u] + lnNb[n0+u];
            }
        }
        float4* dst = (float4*)(outV + ((size_t)row * MM + k) * 128 + n0);
        dst[0] = o4[0]; dst[1] = o4[1]; dst[2] = o4[2]; dst[3] = o4[3];
    }
}

// ---------------------------------------------------------------- Y_edges kernel
__global__ __launch_bounds__(256) void k_yedges(
    const float* __restrict__ Y, const float* __restrict__ yeW,
    const float* __restrict__ lnYEg, const float* __restrict__ lnYEb,
    float* __restrict__ outYE)
{
    __shared__ float sy[MM][4];
    int row = blockIdx.x;
    int tid = threadIdx.x;
    int wv = tid >> 6, lane = tid & 63;
    float w0[16], w1[16];
    #pragma unroll
    for (int r = 0; r < 16; ++r) {
        w0[r] = yeW[r*128 + lane];
        w1[r] = yeW[r*128 + 64 + lane];
    }
    float g0 = lnYEg[lane], g1 = lnYEg[64+lane];
    float b0 = lnYEb[lane], b1 = lnYEb[64+lane];
    if (tid < MM*3) sy[tid/3][tid%3] = Y[(size_t)row * MM * 3 + tid];
    __syncthreads();
    int r = lane & 15;
    float mu = 2.0f + (20.0f/15.0f) * (float)r;
    for (int p = wv; p < MM*MM; p += 4) {
        int m1 = p / 25, m2 = p - 25*m1;
        float dx = sy[m1][0] - sy[m2][0];
        float dy = sy[m1][1] - sy[m2][1];
        float dz = sy[m1][2] - sy[m2][2];
        float d = sqrtf(dx*dx + dy*dy + dz*dz + 1e-6f);
        float z = (d - mu) * 0.8f;
        float e = __expf(-z*z);
        float acc0 = 0.0f, acc1 = 0.0f;
        #pragma unroll
        for (int j = 0; j < 16; ++j) {
            float rv = __shfl(e, j, 16);
            acc0 = fmaf(rv, w0[j], acc0);
            acc1 = fmaf(rv, w1[j], acc1);
        }
        float s = acc0 + acc1, s2 = acc0*acc0 + acc1*acc1;
        #pragma unroll
        for (int o = 1; o < 64; o <<= 1) { s += __shfl_xor(s, o); s2 += __shfl_xor(s2, o); }
        float mean = s * (1.0f/128.0f);
        float var  = s2 * (1.0f/128.0f) - mean*mean;
        float inv  = rsqrtf(var + 1e-5f);
        size_t base = ((size_t)row * 625 + p) * 128;
        outYE[base + lane]      = (acc0 - mean)*inv*g0 + b0;
        outYE[base + 64 + lane] = (acc1 - mean)*inv*g1 + b1;
    }
}

// ---------------------------------------------------------------- Y_nodes + Y_m kernel
__global__ __launch_bounds__(256) void k_ynodes(
    const int* __restrict__ Yt, const float* __restrict__ Ym,
    const int* __restrict__ ptab, const float* __restrict__ ynW,
    const float* __restrict__ lnYNg, const float* __restrict__ lnYNb,
    float* __restrict__ outYN, float* __restrict__ outYM)
{
    int wv = threadIdx.x >> 6, lane = threadIdx.x & 63;
    int row = blockIdx.x * 4 + wv;      // < 51200
    int t = Yt[row];
    int p1 = ptab[120 + t], p2 = ptab[240 + t];
    int r0 = t, r1 = 120 + p1, r2 = 139 + p2;
    float x0 = ynW[r0*128 + lane] + ynW[r1*128 + lane] + ynW[r2*128 + lane];
    float x1 = ynW[r0*128 + 64 + lane] + ynW[r1*128 + 64 + lane] + ynW[r2*128 + 64 + lane];
    float s = x0 + x1, s2 = x0*x0 + x1*x1;
    #pragma unroll
    for (int o = 1; o < 64; o <<= 1) { s += __shfl_xor(s, o); s2 += __shfl_xor(s2, o); }
    float mean = s * (1.0f/128.0f);
    float var  = s2 * (1.0f/128.0f) - mean*mean;
    float inv  = rsqrtf(var + 1e-5f);
    size_t base = (size_t)row * 128;
    outYN[base + lane]      = (x0 - mean)*inv*lnYNg[lane]    + lnYNb[lane];
    outYN[base + 64 + lane] = (x1 - mean)*inv*lnYNg[64+lane] + lnYNb[64+lane];
    if (lane == 0) outYM[row] = Ym[row];
}

// ---------------------------------------------------------------- launcher
extern "C" void kernel_launch(void* const* d_in, const int* in_sizes, int n_in,
                              void* d_out, int out_size, void* d_ws, size_t ws_size,
                              hipStream_t stream) {
    const float* X     = (const float*)d_in[0];
    const float* Y     = (const float*)d_in[1];
    const float* Ym    = (const float*)d_in[2];
    const int*   Yt    = (const int*)d_in[3];
    const float* mask  = (const float*)d_in[4];
    const int*   Ridx  = (const int*)d_in[5];
    const int*   chain = (const int*)d_in[6];
    const float* posW  = (const float*)d_in[7];
    const float* posb  = (const float*)d_in[8];
    const float* edgeW = (const float*)d_in[9];
    const float* lnEg  = (const float*)d_in[10];
    const float* lnEb  = (const float*)d_in[11];
    const float* npdW  = (const float*)d_in[12];
    const float* npdb  = (const float*)d_in[13];
    const float* lnNg  = (const float*)d_in[14];
    const float* lnNb  = (const float*)d_in[15];
    const float* typeW = (const float*)d_in[16];
    const float* typeb = (const float*)d_in[17];
    const float* ynW   = (const float*)d_in[18];
    const float* yeW   = (const float*)d_in[19];
    const float* lnYEg = (const float*)d_in[20];
    const float* lnYEb = (const float*)d_in[21];
    const float* lnYNg = (const float*)d_in[22];
    const float* lnYNb = (const float*)d_in[23];
    const int*   ptab  = (const int*)d_in[24];

    float* o = (float*)d_out;
    // Scratch in the head of the Y_edges output region: written by k_topk,
    // read by k_edges, then fully overwritten by k_yedges before validation.
    int*   eidx = (int*)(o + OFF_YE);
    float* dnb  = (float*)(o + OFF_YE) + BB*LLEN*KK;

    k_topk  <<<BB*LLEN, 256, 0, stream>>>(X, mask, eidx, dnb, o + OFF_EI);
    k_edges <<<BB*LLEN, 256, 0, stream>>>(X, Ridx, chain, posW, posb, edgeW,
                                          lnEg, lnEb, eidx, dnb, o + OFF_E);
    k_nodes <<<BB*LLEN, 256, 0, stream>>>(X, Y, Yt, typeW, typeb, ptab,
                                          npdW, npdb, lnNg, lnNb, o + OFF_V);
    k_yedges<<<BB*LLEN, 256, 0, stream>>>(Y, yeW, lnYEg, lnYEb, o + OFF_YE);
    k_ynodes<<<BB*LLEN*MM/4, 256, 0, stream>>>(Yt, Ym, ptab, ynW,
                                               lnYNg, lnYNb, o + OFF_YN, o + OFF_YM);
}

// Round 6
// 784.925 us; speedup vs baseline: 1.9111x; 1.9111x over previous
//
#include <hip/hip_runtime.h>
#include <hip/hip_bf16.h>
#include <stdint.h>

#define BB 2
#define LLEN 1024
#define MM 25
#define KK 32

// d_out is FLOAT32, concatenated in return order:
// (V, E, E_idx, Y_nodes, Y_edges, Y_m) — offsets in f32 elements.
#define OFF_V   0
#define OFF_E   6553600
#define OFF_EI  14942208
#define OFF_YN  15007744
#define OFF_YE  21561344
#define OFF_YM  185401344

#define KD 416          // K dim of edge GEMM (16 pos + 25*16 rbf)
#define KP 424          // padded LDS row stride (bf16): 848 B, 16B-aligned, 2-way-bank max

typedef __attribute__((ext_vector_type(8))) short short8_t;   // 8 bf16 = 4 VGPR
typedef __attribute__((ext_vector_type(4))) float f32x4;

__constant__ int g_PA[24] = {0,2,3,4,1,1,1,1,0,0,0,4,4,3,0,2,3,4,2,3,4,2,3,2};
__constant__ int g_PB[24] = {0,2,3,4,0,2,3,4,2,3,4,2,3,2,1,1,1,1,0,0,0,4,4,3};

__device__ __forceinline__ float rbf_val(float d, int r) {
    float mu = 2.0f + (20.0f / 15.0f) * (float)r;
    float z = (d - mu) * 0.8f;   // /1.25
    return __expf(-z * z);
}

// ---------------------------------------------------------------- top-k kernel
__global__ __launch_bounds__(256) void k_topk(
    const float* __restrict__ X, const float* __restrict__ mask,
    int* __restrict__ eidx, float* __restrict__ dnb,
    float* __restrict__ outEI)
{
    __shared__ float sD[LLEN];
    __shared__ float sMaxA[256];
    __shared__ unsigned long long sB[256];
    int row = blockIdx.x;            // b*L + i
    int b = row >> 10, i = row & 1023;
    int tid = threadIdx.x;
    const float* Xb = X + (size_t)b * LLEN * 12;
    float cax = Xb[i*12+3], cay = Xb[i*12+4], caz = Xb[i*12+5];
    float mi = mask[row];
    float lmax = 0.0f;
    for (int j = tid; j < LLEN; j += 256) {
        float dx = cax - Xb[j*12+3];
        float dy = cay - Xb[j*12+4];
        float dz = caz - Xb[j*12+5];
        float d = sqrtf(dx*dx + dy*dy + dz*dz + 1e-6f) * (mi * mask[b*LLEN + j]);
        sD[j] = d;
        lmax = fmaxf(lmax, d);
    }
    sMaxA[tid] = lmax;
    __syncthreads();
    for (int w = 128; w > 0; w >>= 1) {
        if (tid < w) sMaxA[tid] = fmaxf(sMaxA[tid], sMaxA[tid + w]);
        __syncthreads();
    }
    float rmax = sMaxA[0];
    for (int j = tid; j < LLEN; j += 256) {
        float m2 = mi * mask[b*LLEN + j];
        sD[j] = sD[j] + (1.0f - m2) * rmax;
    }
    __syncthreads();
    for (int it = 0; it < KK; ++it) {
        unsigned long long best = ~0ull;
        for (int j = tid; j < LLEN; j += 256) {
            unsigned long long p = ((unsigned long long)__float_as_uint(sD[j]) << 32) | (unsigned)j;
            if (p < best) best = p;
        }
        sB[tid] = best;
        __syncthreads();
        for (int w = 128; w > 0; w >>= 1) {
            if (tid < w) { if (sB[tid + w] < sB[tid]) sB[tid] = sB[tid + w]; }
            __syncthreads();
        }
        if (tid == 0) {
            unsigned long long wv = sB[0];
            int jw = (int)(wv & 0xffffffffu);
            float dv = __uint_as_float((unsigned)(wv >> 32));
            sD[jw] = __uint_as_float(0x7f800000u);   // +inf
            eidx[row*KK + it] = jw;
            dnb[row*KK + it] = dv;
            outEI[row*KK + it] = (float)jw;
        }
        __syncthreads();
    }
}

// ------------------------------------------------- B-pack prep (edgeW -> bf16 frag order)
// Bp[(ks*8+t)*64 + lane][j] = W[k = ks*32 + (lane>>4)*8 + j][n = t*16 + (lane&15)]
__global__ __launch_bounds__(256) void k_prep(
    const float* __restrict__ W, __hip_bfloat16* __restrict__ Bp)
{
    int idx = blockIdx.x * 256 + threadIdx.x;      // 13*8*64 = 6656 slots
    if (idx >= 6656) return;
    int lane = idx & 63, tt = (idx >> 6) & 7, ks = idx >> 9;
    int k0 = ks*32 + (lane >> 4)*8;
    int n  = tt*16 + (lane & 15);
    __hip_bfloat16* dst = Bp + (size_t)idx * 8;
    #pragma unroll
    for (int j = 0; j < 8; ++j) dst[j] = __float2bfloat16(W[(size_t)(k0 + j)*128 + n]);
}

// ---------------------------------------------------------------- edge kernel (MFMA)
__global__ __launch_bounds__(256) void k_edges(
    const float* __restrict__ X,
    const int* __restrict__ Ridx, const int* __restrict__ chain,
    const float* __restrict__ posW, const float* __restrict__ posb,
    const __hip_bfloat16* __restrict__ Bpack,
    const float* __restrict__ lnEg, const float* __restrict__ lnEb,
    const int* __restrict__ eidx, const float* __restrict__ dnb,
    float* __restrict__ outE)
{
    __shared__ __align__(16) __hip_bfloat16 A[64 * KP];   // 53 KB feature tile (bf16, K-major)
    __shared__ float aj[64][16];
    __shared__ float ai[2][16];
    __shared__ int   didx[64];
    int r0 = blockIdx.x * 2;            // two residue-rows per block (same batch: 1024 even)
    int b  = r0 >> 10;
    int tid = threadIdx.x;
    const float* Xb = X + (size_t)b * LLEN * 12;

    if (tid < 64) {                      // per-edge neighbor atoms
        int e = tid, row = r0 + (e >> 5), k = e & 31;
        int j = eidx[row*KK + k];
        const float* xr = Xb + j*12;
        float nx=xr[0], ny=xr[1], nz=xr[2];
        float ax=xr[3], ay=xr[4], az=xr[5];
        float cx=xr[6], cy=xr[7], cz=xr[8];
        float bx=ax-nx, by=ay-ny, bz=az-nz;
        float vx=cx-ax, vy=cy-ay, vz=cz-az;
        float qx = by*vz - bz*vy, qy = bz*vx - bx*vz, qz = bx*vy - by*vx;
        aj[e][0]=nx; aj[e][1]=ny; aj[e][2]=nz;
        aj[e][3]=ax; aj[e][4]=ay; aj[e][5]=az;
        aj[e][6]=cx; aj[e][7]=cy; aj[e][8]=cz;
        aj[e][9]=xr[9]; aj[e][10]=xr[10]; aj[e][11]=xr[11];
        aj[e][12] = -0.58273431f*qx + 0.56802827f*bx - 0.54067466f*vx + ax;
        aj[e][13] = -0.58273431f*qy + 0.56802827f*by - 0.54067466f*vy + ay;
        aj[e][14] = -0.58273431f*qz + 0.56802827f*bz - 0.54067466f*vz + az;
        int off = Ridx[row] - Ridx[b*LLEN + j];
        int ec = (chain[row] == chain[b*LLEN + j]) ? 1 : 0;
        int dc = off + 32; dc = dc < 0 ? 0 : (dc > 64 ? 64 : dc);
        didx[e] = ec ? dc : 65;
    }
    if (tid >= 64 && tid < 66) {         // center atoms for the 2 rows
        int rl = tid - 64;
        int i = (r0 + rl) & 1023;
        const float* xr = Xb + i*12;
        float nx=xr[0], ny=xr[1], nz=xr[2];
        float ax=xr[3], ay=xr[4], az=xr[5];
        float cx=xr[6], cy=xr[7], cz=xr[8];
        float bx=ax-nx, by=ay-ny, bz=az-nz;
        float vx=cx-ax, vy=cy-ay, vz=cz-az;
        float qx = by*vz - bz*vy, qy = bz*vx - bx*vz, qz = bx*vy - by*vx;
        ai[rl][0]=nx; ai[rl][1]=ny; ai[rl][2]=nz;
        ai[rl][3]=ax; ai[rl][4]=ay; ai[rl][5]=az;
        ai[rl][6]=cx; ai[rl][7]=cy; ai[rl][8]=cz;
        ai[rl][9]=xr[9]; ai[rl][10]=xr[10]; ai[rl][11]=xr[11];
        ai[rl][12] = -0.58273431f*qx + 0.56802827f*bx - 0.54067466f*vx + ax;
        ai[rl][13] = -0.58273431f*qy + 0.56802827f*by - 0.54067466f*vy + ay;
        ai[rl][14] = -0.58273431f*qz + 0.56802827f*bz - 0.54067466f*vz + az;
    }
    __syncthreads();

    // features -> bf16 A tile: 64 edges x 26 items (1 pos + 25 rbf groups)
    for (int item = tid; item < 64 * 26; item += 256) {
        int e = item / 26, it = item - e * 26;
        int rl = e >> 5;
        __hip_bfloat16* f = A + e * KP;
        if (it == 0) {
            int d = didx[e];
            #pragma unroll
            for (int c = 0; c < 16; ++c) f[c] = __float2bfloat16(posW[d*16 + c] + posb[c]);
        } else {
            float dist;
            if (it == 1) {
                dist = dnb[(r0 + rl)*KK + (e & 31)];
            } else {
                int p = it - 2;
                int a = g_PA[p], q = g_PB[p];
                float dx = ai[rl][a*3+0] - aj[e][q*3+0];
                float dy = ai[rl][a*3+1] - aj[e][q*3+1];
                float dz = ai[rl][a*3+2] - aj[e][q*3+2];
                dist = sqrtf(dx*dx + dy*dy + dz*dz + 1e-6f);
            }
            int base = 16 + (it - 1) * 16;
            #pragma unroll
            for (int r = 0; r < 16; ++r) f[base + r] = __float2bfloat16(rbf_val(dist, r));
        }
    }
    __syncthreads();

    // MFMA GEMM: per wave 16 edges x 128 outputs, K = 13*32
    int wid = tid >> 6, lane = tid & 63;
    int col16 = lane & 15, kg = lane >> 4;
    f32x4 acc[8];
    #pragma unroll
    for (int t = 0; t < 8; ++t) acc[t] = (f32x4){0.f, 0.f, 0.f, 0.f};
    const __hip_bfloat16* Ar = A + (wid*16 + col16) * KP + kg * 8;
    const short8_t* Bp = (const short8_t*)Bpack;
    for (int ks = 0; ks < 13; ++ks) {
        short8_t a = *(const short8_t*)(Ar + ks*32);
        #pragma unroll
        for (int t = 0; t < 8; ++t) {
            short8_t bf = Bp[(ks*8 + t)*64 + lane];
            acc[t] = __builtin_amdgcn_mfma_f32_16x16x32_bf16(a, bf, acc[t], 0, 0, 0);
        }
    }

    // LN epilogue (in-wave): C/D layout row=(lane>>4)*4+reg, col=lane&15
    float g[8], be[8];
    #pragma unroll
    for (int t = 0; t < 8; ++t) { g[t] = lnEg[t*16 + col16]; be[t] = lnEb[t*16 + col16]; }
    #pragma unroll
    for (int r = 0; r < 4; ++r) {
        float s = 0.0f;
        #pragma unroll
        for (int t = 0; t < 8; ++t) s += acc[t][r];
        s += __shfl_xor(s, 1); s += __shfl_xor(s, 2);
        s += __shfl_xor(s, 4); s += __shfl_xor(s, 8);
        float mean = s * (1.0f/128.0f);
        float q2 = 0.0f;
        #pragma unroll
        for (int t = 0; t < 8; ++t) { float c0 = acc[t][r] - mean; q2 += c0*c0; }
        q2 += __shfl_xor(q2, 1); q2 += __shfl_xor(q2, 2);
        q2 += __shfl_xor(q2, 4); q2 += __shfl_xor(q2, 8);
        float inv = rsqrtf(q2 * (1.0f/128.0f) + 1e-5f);
        int eb  = wid*16 + kg*4 + r;
        int row = r0 + (eb >> 5), kk = eb & 31;
        float* dst = outE + ((size_t)row*KK + kk)*128 + col16;
        #pragma unroll
        for (int t = 0; t < 8; ++t) dst[t*16] = (acc[t][r] - mean)*inv*g[t] + be[t];
    }
}

// ---------------------------------------------------------------- node (V) kernel
#define FSTR2 149
__global__ __launch_bounds__(256) void k_nodes(
    const float* __restrict__ X, const float* __restrict__ Y,
    const int* __restrict__ Yt,
    const float* __restrict__ typeW, const float* __restrict__ typeb,
    const int* __restrict__ ptab,
    const float* __restrict__ npdW, const float* __restrict__ npdb,
    const float* __restrict__ lnNg, const float* __restrict__ lnNb,
    float* __restrict__ outV)
{
    __shared__ float fls[MM * FSTR2];
    __shared__ float sat[15];   // N,Ca,C,O,Cb
    __shared__ float sfr[9];    // e1,e2,e3
    int row = blockIdx.x;
    int b = row >> 10, i = row & 1023;
    int tid = threadIdx.x;

    if (tid == 0) {
        const float* xr = X + ((size_t)b * LLEN + i) * 12;
        float nx=xr[0], ny=xr[1], nz=xr[2];
        float ax=xr[3], ay=xr[4], az=xr[5];
        float cx=xr[6], cy=xr[7], cz=xr[8];
        float bx=ax-nx, by=ay-ny, bz=az-nz;
        float vx=cx-ax, vy=cy-ay, vz=cz-az;
        float qx = by*vz - bz*vy, qy = bz*vx - bx*vz, qz = bx*vy - by*vx;
        sat[0]=nx; sat[1]=ny; sat[2]=nz;
        sat[3]=ax; sat[4]=ay; sat[5]=az;
        sat[6]=cx; sat[7]=cy; sat[8]=cz;
        sat[9]=xr[9]; sat[10]=xr[10]; sat[11]=xr[11];
        sat[12] = -0.58273431f*qx + 0.56802827f*bx - 0.54067466f*vx + ax;
        sat[13] = -0.58273431f*qy + 0.56802827f*by - 0.54067466f*vy + ay;
        sat[14] = -0.58273431f*qz + 0.56802827f*bz - 0.54067466f*vz + az;
        float e1x = nx-ax, e1y = ny-ay, e1z = nz-az;
        float n1 = fmaxf(sqrtf(e1x*e1x+e1y*e1y+e1z*e1z), 1e-12f);
        e1x/=n1; e1y/=n1; e1z/=n1;
        float dd = e1x*vx + e1y*vy + e1z*vz;
        float u2x = vx - e1x*dd, u2y = vy - e1y*dd, u2z = vz - e1z*dd;
        float n2 = fmaxf(sqrtf(u2x*u2x+u2y*u2y+u2z*u2z), 1e-12f);
        u2x/=n2; u2y/=n2; u2z/=n2;
        float e3x = e1y*u2z - e1z*u2y;
        float e3y = e1z*u2x - e1x*u2z;
        float e3z = e1x*u2y - e1y*u2x;
        sfr[0]=e1x; sfr[1]=e1y; sfr[2]=e1z;
        sfr[3]=u2x; sfr[4]=u2y; sfr[5]=u2z;
        sfr[6]=e3x; sfr[7]=e3y; sfr[8]=e3z;
    }
    __syncthreads();
    const float* Yb = Y + (size_t)row * MM * 3;
    for (int item = tid; item < MM * 10; item += 256) {
        int m = item / 10, it = item - m * 10;
        float* f = fls + m * FSTR2;
        if (it < 5) {
            float dx = sat[it*3+0] - Yb[m*3+0];
            float dy = sat[it*3+1] - Yb[m*3+1];
            float dz = sat[it*3+2] - Yb[m*3+2];
            float dist = sqrtf(dx*dx + dy*dy + dz*dz + 1e-6f);
            #pragma unroll
            for (int r = 0; r < 16; ++r) f[it*16 + r] = rbf_val(dist, r);
        } else if (it < 9) {
            int qq = it - 5;
            int t = Yt[row*MM + m];
            int p1 = ptab[120 + t], p2 = ptab[240 + t];
            #pragma unroll
            for (int c = 0; c < 16; ++c) {
                int cc = qq*16 + c;
                f[80 + cc] = typeW[t*64 + cc] + typeW[(120+p1)*64 + cc]
                           + typeW[(139+p2)*64 + cc] + typeb[cc];
            }
        } else {
            float vx = Yb[m*3+0] - sat[3];
            float vy = Yb[m*3+1] - sat[4];
            float vz = Yb[m*3+2] - sat[5];
            float l0 = sfr[0]*vx + sfr[1]*vy + sfr[2]*vz;
            float l1 = sfr[3]*vx + sfr[4]*vy + sfr[5]*vz;
            float l2 = sfr[6]*vx + sfr[7]*vy + sfr[8]*vz;
            float rxy  = sqrtf(l0*l0 + l1*l1 + 1e-8f);
            float rxyz = sqrtf(l0*l0 + l1*l1 + l2*l2) + 1e-8f;
            f[144] = l0 / rxy;
            f[145] = l1 / rxy;
            f[146] = rxy / rxyz;
            f[147] = l2 / rxyz;
        }
    }
    __syncthreads();
    int k = tid >> 3, q = tid & 7, n0 = q * 16;
    if (k < MM) {
        float acc[16];
        #pragma unroll
        for (int u = 0; u < 16; ++u) acc[u] = 0.0f;
        const float* fk = fls + k * FSTR2;
        #pragma unroll 4
        for (int c = 0; c < 148; ++c) {
            float v = fk[c];
            const float4* w = (const float4*)(npdW + (size_t)c * 128 + n0);
            float4 w0 = w[0], w1 = w[1], w2 = w[2], w3 = w[3];
            acc[0]  = fmaf(v, w0.x, acc[0]);  acc[1]  = fmaf(v, w0.y, acc[1]);
            acc[2]  = fmaf(v, w0.z, acc[2]);  acc[3]  = fmaf(v, w0.w, acc[3]);
            acc[4]  = fmaf(v, w1.x, acc[4]);  acc[5]  = fmaf(v, w1.y, acc[5]);
            acc[6]  = fmaf(v, w1.z, acc[6]);  acc[7]  = fmaf(v, w1.w, acc[7]);
            acc[8]  = fmaf(v, w2.x, acc[8]);  acc[9]  = fmaf(v, w2.y, acc[9]);
            acc[10] = fmaf(v, w2.z, acc[10]); acc[11] = fmaf(v, w2.w, acc[11]);
            acc[12] = fmaf(v, w3.x, acc[12]); acc[13] = fmaf(v, w3.y, acc[13]);
            acc[14] = fmaf(v, w3.z, acc[14]); acc[15] = fmaf(v, w3.w, acc[15]);
        }
        #pragma unroll
        for (int u = 0; u < 16; ++u) acc[u] += npdb[n0 + u];
        float s = 0.0f;
        #pragma unroll
        for (int u = 0; u < 16; ++u) s += acc[u];
        s += __shfl_xor(s, 1); s += __shfl_xor(s, 2); s += __shfl_xor(s, 4);
        float mean = s * (1.0f/128.0f);
        float s2 = 0.0f;
        #pragma unroll
        for (int u = 0; u < 16; ++u) { float c0 = acc[u] - mean; s2 += c0*c0; }
        s2 += __shfl_xor(s2, 1); s2 += __shfl_xor(s2, 2); s2 += __shfl_xor(s2, 4);
        float var = s2 * (1.0f/128.0f);
        float inv = rsqrtf(var + 1e-5f);
        float4 o4[4];
        #pragma unroll
        for (int g4 = 0; g4 < 4; ++g4) {
            float* e = (float*)&o4[g4];
            #pragma unroll
            for (int j = 0; j < 4; ++j) {
                int u = g4*4 + j;
                e[j] = (acc[u] - mean)*inv*lnNg[n0+u] + lnNb[n0+u];
            }
        }
        float4* dst = (float4*)(outV + ((size_t)row * MM + k) * 128 + n0);
        dst[0] = o4[0]; dst[1] = o4[1]; dst[2] = o4[2]; dst[3] = o4[3];
    }
}

// ---------------------------------------------------------------- Y_edges kernel
__global__ __launch_bounds__(256) void k_yedges(
    const float* __restrict__ Y, const float* __restrict__ yeW,
    const float* __restrict__ lnYEg, const float* __restrict__ lnYEb,
    float* __restrict__ outYE)
{
    __shared__ float sy[MM][4];
    int row = blockIdx.x;
    int tid = threadIdx.x;
    int wv = tid >> 6, lane = tid & 63;
    float w0[16], w1[16];
    #pragma unroll
    for (int r = 0; r < 16; ++r) {
        w0[r] = yeW[r*128 + lane];
        w1[r] = yeW[r*128 + 64 + lane];
    }
    float g0 = lnYEg[lane], g1 = lnYEg[64+lane];
    float b0 = lnYEb[lane], b1 = lnYEb[64+lane];
    if (tid < MM*3) sy[tid/3][tid%3] = Y[(size_t)row * MM * 3 + tid];
    __syncthreads();
    int r = lane & 15;
    float mu = 2.0f + (20.0f/15.0f) * (float)r;
    for (int p = wv; p < MM*MM; p += 4) {
        int m1 = p / 25, m2 = p - 25*m1;
        float dx = sy[m1][0] - sy[m2][0];
        float dy = sy[m1][1] - sy[m2][1];
        float dz = sy[m1][2] - sy[m2][2];
        float d = sqrtf(dx*dx + dy*dy + dz*dz + 1e-6f);
        float z = (d - mu) * 0.8f;
        float e = __expf(-z*z);
        float acc0 = 0.0f, acc1 = 0.0f;
        #pragma unroll
        for (int j = 0; j < 16; ++j) {
            float rv = __shfl(e, j, 16);
            acc0 = fmaf(rv, w0[j], acc0);
            acc1 = fmaf(rv, w1[j], acc1);
        }
        float s = acc0 + acc1, s2 = acc0*acc0 + acc1*acc1;
        #pragma unroll
        for (int o = 1; o < 64; o <<= 1) { s += __shfl_xor(s, o); s2 += __shfl_xor(s2, o); }
        float mean = s * (1.0f/128.0f);
        float var  = s2 * (1.0f/128.0f) - mean*mean;
        float inv  = rsqrtf(var + 1e-5f);
        size_t base = ((size_t)row * 625 + p) * 128;
        outYE[base + lane]      = (acc0 - mean)*inv*g0 + b0;
        outYE[base + 64 + lane] = (acc1 - mean)*inv*g1 + b1;
    }
}

// ---------------------------------------------------------------- Y_nodes + Y_m kernel
__global__ __launch_bounds__(256) void k_ynodes(
    const int* __restrict__ Yt, const float* __restrict__ Ym,
    const int* __restrict__ ptab, const float* __restrict__ ynW,
    const float* __restrict__ lnYNg, const float* __restrict__ lnYNb,
    float* __restrict__ outYN, float* __restrict__ outYM)
{
    int wv = threadIdx.x >> 6, lane = threadIdx.x & 63;
    int row = blockIdx.x * 4 + wv;      // < 51200
    int t = Yt[row];
    int p1 = ptab[120 + t], p2 = ptab[240 + t];
    int r0 = t, r1 = 120 + p1, r2 = 139 + p2;
    float x0 = ynW[r0*128 + lane] + ynW[r1*128 + lane] + ynW[r2*128 + lane];
    float x1 = ynW[r0*128 + 64 + lane] + ynW[r1*128 + 64 + lane] + ynW[r2*128 + 64 + lane];
    float s = x0 + x1, s2 = x0*x0 + x1*x1;
    #pragma unroll
    for (int o = 1; o < 64; o <<= 1) { s += __shfl_xor(s, o); s2 += __shfl_xor(s2, o); }
    float mean = s * (1.0f/128.0f);
    float var  = s2 * (1.0f/128.0f) - mean*mean;
    float inv  = rsqrtf(var + 1e-5f);
    size_t base = (size_t)row * 128;
    outYN[base + lane]      = (x0 - mean)*inv*lnYNg[lane]    + lnYNb[lane];
    outYN[base + 64 + lane] = (x1 - mean)*inv*lnYNg[64+lane] + lnYNb[64+lane];
    if (lane == 0) outYM[row] = Ym[row];
}

// ---------------------------------------------------------------- launcher
extern "C" void kernel_launch(void* const* d_in, const int* in_sizes, int n_in,
                              void* d_out, int out_size, void* d_ws, size_t ws_size,
                              hipStream_t stream) {
    const float* X     = (const float*)d_in[0];
    const float* Y     = (const float*)d_in[1];
    const float* Ym    = (const float*)d_in[2];
    const int*   Yt    = (const int*)d_in[3];
    const float* mask  = (const float*)d_in[4];
    const int*   Ridx  = (const int*)d_in[5];
    const int*   chain = (const int*)d_in[6];
    const float* posW  = (const float*)d_in[7];
    const float* posb  = (const float*)d_in[8];
    const float* edgeW = (const float*)d_in[9];
    const float* lnEg  = (const float*)d_in[10];
    const float* lnEb  = (const float*)d_in[11];
    const float* npdW  = (const float*)d_in[12];
    const float* npdb  = (const float*)d_in[13];
    const float* lnNg  = (const float*)d_in[14];
    const float* lnNb  = (const float*)d_in[15];
    const float* typeW = (const float*)d_in[16];
    const float* typeb = (const float*)d_in[17];
    const float* ynW   = (const float*)d_in[18];
    const float* yeW   = (const float*)d_in[19];
    const float* lnYEg = (const float*)d_in[20];
    const float* lnYEb = (const float*)d_in[21];
    const float* lnYNg = (const float*)d_in[22];
    const float* lnYNb = (const float*)d_in[23];
    const int*   ptab  = (const int*)d_in[24];

    float* o = (float*)d_out;
    // Scratch in the head of the Y_edges output region: written by k_topk/k_prep,
    // read by k_edges, then fully overwritten by k_yedges before validation.
    int*   eidx = (int*)(o + OFF_YE);                          // 256 KB
    float* dnb  = (float*)(o + OFF_YE) + BB*LLEN*KK;           // 256 KB
    __hip_bfloat16* Bpack = (__hip_bfloat16*)(dnb + BB*LLEN*KK); // 104 KB, 16B-aligned

    k_prep  <<<26, 256, 0, stream>>>(edgeW, Bpack);
    k_topk  <<<BB*LLEN, 256, 0, stream>>>(X, mask, eidx, dnb, o + OFF_EI);
    k_edges <<<BB*LLEN/2, 256, 0, stream>>>(X, Ridx, chain, posW, posb, Bpack,
                                            lnEg, lnEb, eidx, dnb, o + OFF_E);
    k_nodes <<<BB*LLEN, 256, 0, stream>>>(X, Y, Yt, typeW, typeb, ptab,
                                          npdW, npdb, lnNg, lnNb, o + OFF_V);
    k_yedges<<<BB*LLEN, 256, 0, stream>>>(Y, yeW, lnYEg, lnYEb, o + OFF_YE);
    k_ynodes<<<BB*LLEN*MM/4, 256, 0, stream>>>(Yt, Ym, ptab, ynW,
                                               lnYNg, lnYNb, o + OFF_YN, o + OFF_YM);
}

// Round 7
// 483.606 us; speedup vs baseline: 3.1018x; 1.6231x over previous
//
#include <hip/hip_runtime.h>
#include <hip/hip_bf16.h>
#include <stdint.h>

#define BB 2
#define LLEN 1024
#define MM 25
#define KK 32

// d_out is FLOAT32, concatenated in return order:
// (V, E, E_idx, Y_nodes, Y_edges, Y_m) — offsets in f32 elements.
#define OFF_V   0
#define OFF_E   6553600
#define OFF_EI  14942208
#define OFF_YN  15007744
#define OFF_YE  21561344
#define OFF_YM  185401344

#define KD 416          // K dim of edge GEMM (16 pos + 25*16 rbf)
#define KP 424          // padded LDS row stride (bf16)

typedef __attribute__((ext_vector_type(8))) short short8_t;   // 8 bf16 = 4 VGPR
typedef __attribute__((ext_vector_type(4))) float f32x4;

__constant__ int g_PA[24] = {0,2,3,4,1,1,1,1,0,0,0,4,4,3,0,2,3,4,2,3,4,2,3,2};
__constant__ int g_PB[24] = {0,2,3,4,0,2,3,4,2,3,4,2,3,2,1,1,1,1,0,0,0,4,4,3};

__device__ __forceinline__ float rbf_val(float d, int r) {
    float mu = 2.0f + (20.0f / 15.0f) * (float)r;
    float z = (d - mu) * 0.8f;   // /1.25
    return __expf(-z * z);
}

// ---------------------------------------------------------------- top-k kernel
__global__ __launch_bounds__(256) void k_topk(
    const float* __restrict__ X, const float* __restrict__ mask,
    int* __restrict__ eidx, float* __restrict__ dnb,
    float* __restrict__ outEI)
{
    __shared__ float sD[LLEN];
    __shared__ float sMaxA[256];
    __shared__ unsigned long long sB[256];
    int row = blockIdx.x;            // b*L + i
    int b = row >> 10, i = row & 1023;
    int tid = threadIdx.x;
    const float* Xb = X + (size_t)b * LLEN * 12;
    float cax = Xb[i*12+3], cay = Xb[i*12+4], caz = Xb[i*12+5];
    float mi = mask[row];
    float lmax = 0.0f;
    for (int j = tid; j < LLEN; j += 256) {
        float dx = cax - Xb[j*12+3];
        float dy = cay - Xb[j*12+4];
        float dz = caz - Xb[j*12+5];
        float d = sqrtf(dx*dx + dy*dy + dz*dz + 1e-6f) * (mi * mask[b*LLEN + j]);
        sD[j] = d;
        lmax = fmaxf(lmax, d);
    }
    sMaxA[tid] = lmax;
    __syncthreads();
    for (int w = 128; w > 0; w >>= 1) {
        if (tid < w) sMaxA[tid] = fmaxf(sMaxA[tid], sMaxA[tid + w]);
        __syncthreads();
    }
    float rmax = sMaxA[0];
    for (int j = tid; j < LLEN; j += 256) {
        float m2 = mi * mask[b*LLEN + j];
        sD[j] = sD[j] + (1.0f - m2) * rmax;
    }
    __syncthreads();
    for (int it = 0; it < KK; ++it) {
        unsigned long long best = ~0ull;
        for (int j = tid; j < LLEN; j += 256) {
            unsigned long long p = ((unsigned long long)__float_as_uint(sD[j]) << 32) | (unsigned)j;
            if (p < best) best = p;
        }
        sB[tid] = best;
        __syncthreads();
        for (int w = 128; w > 0; w >>= 1) {
            if (tid < w) { if (sB[tid + w] < sB[tid]) sB[tid] = sB[tid + w]; }
            __syncthreads();
        }
        if (tid == 0) {
            unsigned long long wv = sB[0];
            int jw = (int)(wv & 0xffffffffu);
            float dv = __uint_as_float((unsigned)(wv >> 32));
            sD[jw] = __uint_as_float(0x7f800000u);   // +inf
            eidx[row*KK + it] = jw;
            dnb[row*KK + it] = dv;
            outEI[row*KK + it] = (float)jw;
        }
        __syncthreads();
    }
}

// ------------------------------------------------- B-pack prep (edgeW + yeW -> bf16 frag order)
// slots [0,6656): Bp[(ks*8+t)*64+lane][j] = edgeW[ks*32+(lane>>4)*8+j][t*16+(lane&15)]
// slots [6656,7168): Bp2[t*64+lane][j] = (kg<2) ? yeW[kg*8+j][t*16+(lane&15)] : 0
__global__ __launch_bounds__(256) void k_prep(
    const float* __restrict__ W, const float* __restrict__ yeW,
    __hip_bfloat16* __restrict__ Bp, __hip_bfloat16* __restrict__ Bp2)
{
    int idx = blockIdx.x * 256 + threadIdx.x;
    if (idx < 6656) {
        int lane = idx & 63, tt = (idx >> 6) & 7, ks = idx >> 9;
        int k0 = ks*32 + (lane >> 4)*8;
        int n  = tt*16 + (lane & 15);
        __hip_bfloat16* dst = Bp + (size_t)idx * 8;
        #pragma unroll
        for (int j = 0; j < 8; ++j) dst[j] = __float2bfloat16(W[(size_t)(k0 + j)*128 + n]);
    } else if (idx < 7168) {
        int i2 = idx - 6656;
        int lane = i2 & 63, tt = i2 >> 6;
        int kg = lane >> 4;
        int n  = tt*16 + (lane & 15);
        __hip_bfloat16* dst = Bp2 + (size_t)i2 * 8;
        #pragma unroll
        for (int j = 0; j < 8; ++j) {
            float v = (kg < 2) ? yeW[(size_t)(kg*8 + j)*128 + n] : 0.0f;
            dst[j] = __float2bfloat16(v);
        }
    }
}

// ---------------------------------------------------------------- edge kernel (MFMA)
__global__ __launch_bounds__(256) void k_edges(
    const float* __restrict__ X,
    const int* __restrict__ Ridx, const int* __restrict__ chain,
    const float* __restrict__ posW, const float* __restrict__ posb,
    const __hip_bfloat16* __restrict__ Bpack,
    const float* __restrict__ lnEg, const float* __restrict__ lnEb,
    const int* __restrict__ eidx, const float* __restrict__ dnb,
    float* __restrict__ outE)
{
    __shared__ __align__(16) __hip_bfloat16 A[64 * KP];   // 53 KB feature tile
    __shared__ float aj[64][16];
    __shared__ float ai[2][16];
    __shared__ int   didx[64];
    int r0 = blockIdx.x * 2;
    int b  = r0 >> 10;
    int tid = threadIdx.x;
    const float* Xb = X + (size_t)b * LLEN * 12;

    if (tid < 64) {
        int e = tid, row = r0 + (e >> 5), k = e & 31;
        int j = eidx[row*KK + k];
        const float* xr = Xb + j*12;
        float nx=xr[0], ny=xr[1], nz=xr[2];
        float ax=xr[3], ay=xr[4], az=xr[5];
        float cx=xr[6], cy=xr[7], cz=xr[8];
        float bx=ax-nx, by=ay-ny, bz=az-nz;
        float vx=cx-ax, vy=cy-ay, vz=cz-az;
        float qx = by*vz - bz*vy, qy = bz*vx - bx*vz, qz = bx*vy - by*vx;
        aj[e][0]=nx; aj[e][1]=ny; aj[e][2]=nz;
        aj[e][3]=ax; aj[e][4]=ay; aj[e][5]=az;
        aj[e][6]=cx; aj[e][7]=cy; aj[e][8]=cz;
        aj[e][9]=xr[9]; aj[e][10]=xr[10]; aj[e][11]=xr[11];
        aj[e][12] = -0.58273431f*qx + 0.56802827f*bx - 0.54067466f*vx + ax;
        aj[e][13] = -0.58273431f*qy + 0.56802827f*by - 0.54067466f*vy + ay;
        aj[e][14] = -0.58273431f*qz + 0.56802827f*bz - 0.54067466f*vz + az;
        int off = Ridx[row] - Ridx[b*LLEN + j];
        int ec = (chain[row] == chain[b*LLEN + j]) ? 1 : 0;
        int dc = off + 32; dc = dc < 0 ? 0 : (dc > 64 ? 64 : dc);
        didx[e] = ec ? dc : 65;
    }
    if (tid >= 64 && tid < 66) {
        int rl = tid - 64;
        int i = (r0 + rl) & 1023;
        const float* xr = Xb + i*12;
        float nx=xr[0], ny=xr[1], nz=xr[2];
        float ax=xr[3], ay=xr[4], az=xr[5];
        float cx=xr[6], cy=xr[7], cz=xr[8];
        float bx=ax-nx, by=ay-ny, bz=az-nz;
        float vx=cx-ax, vy=cy-ay, vz=cz-az;
        float qx = by*vz - bz*vy, qy = bz*vx - bx*vz, qz = bx*vy - by*vx;
        ai[rl][0]=nx; ai[rl][1]=ny; ai[rl][2]=nz;
        ai[rl][3]=ax; ai[rl][4]=ay; ai[rl][5]=az;
        ai[rl][6]=cx; ai[rl][7]=cy; ai[rl][8]=cz;
        ai[rl][9]=xr[9]; ai[rl][10]=xr[10]; ai[rl][11]=xr[11];
        ai[rl][12] = -0.58273431f*qx + 0.56802827f*bx - 0.54067466f*vx + ax;
        ai[rl][13] = -0.58273431f*qy + 0.56802827f*by - 0.54067466f*vy + ay;
        ai[rl][14] = -0.58273431f*qz + 0.56802827f*bz - 0.54067466f*vz + az;
    }
    __syncthreads();

    for (int item = tid; item < 64 * 26; item += 256) {
        int e = item / 26, it = item - e * 26;
        int rl = e >> 5;
        __hip_bfloat16* f = A + e * KP;
        if (it == 0) {
            int d = didx[e];
            #pragma unroll
            for (int c = 0; c < 16; ++c) f[c] = __float2bfloat16(posW[d*16 + c] + posb[c]);
        } else {
            float dist;
            if (it == 1) {
                dist = dnb[(r0 + rl)*KK + (e & 31)];
            } else {
                int p = it - 2;
                int a = g_PA[p], q = g_PB[p];
                float dx = ai[rl][a*3+0] - aj[e][q*3+0];
                float dy = ai[rl][a*3+1] - aj[e][q*3+1];
                float dz = ai[rl][a*3+2] - aj[e][q*3+2];
                dist = sqrtf(dx*dx + dy*dy + dz*dz + 1e-6f);
            }
            int base = 16 + (it - 1) * 16;
            #pragma unroll
            for (int r = 0; r < 16; ++r) f[base + r] = __float2bfloat16(rbf_val(dist, r));
        }
    }
    __syncthreads();

    int wid = tid >> 6, lane = tid & 63;
    int col16 = lane & 15, kg = lane >> 4;
    f32x4 acc[8];
    #pragma unroll
    for (int t = 0; t < 8; ++t) acc[t] = (f32x4){0.f, 0.f, 0.f, 0.f};
    const __hip_bfloat16* Ar = A + (wid*16 + col16) * KP + kg * 8;
    const short8_t* Bp = (const short8_t*)Bpack;
    for (int ks = 0; ks < 13; ++ks) {
        short8_t a = *(const short8_t*)(Ar + ks*32);
        #pragma unroll
        for (int t = 0; t < 8; ++t) {
            short8_t bf = Bp[(ks*8 + t)*64 + lane];
            acc[t] = __builtin_amdgcn_mfma_f32_16x16x32_bf16(a, bf, acc[t], 0, 0, 0);
        }
    }

    float g[8], be[8];
    #pragma unroll
    for (int t = 0; t < 8; ++t) { g[t] = lnEg[t*16 + col16]; be[t] = lnEb[t*16 + col16]; }
    #pragma unroll
    for (int r = 0; r < 4; ++r) {
        float s = 0.0f;
        #pragma unroll
        for (int t = 0; t < 8; ++t) s += acc[t][r];
        s += __shfl_xor(s, 1); s += __shfl_xor(s, 2);
        s += __shfl_xor(s, 4); s += __shfl_xor(s, 8);
        float mean = s * (1.0f/128.0f);
        float q2 = 0.0f;
        #pragma unroll
        for (int t = 0; t < 8; ++t) { float c0 = acc[t][r] - mean; q2 += c0*c0; }
        q2 += __shfl_xor(q2, 1); q2 += __shfl_xor(q2, 2);
        q2 += __shfl_xor(q2, 4); q2 += __shfl_xor(q2, 8);
        float inv = rsqrtf(q2 * (1.0f/128.0f) + 1e-5f);
        int eb  = wid*16 + kg*4 + r;
        int row = r0 + (eb >> 5), kk = eb & 31;
        float* dst = outE + ((size_t)row*KK + kk)*128 + col16;
        #pragma unroll
        for (int t = 0; t < 8; ++t) dst[t*16] = (acc[t][r] - mean)*inv*g[t] + be[t];
    }
}

// ---------------------------------------------------------------- node (V) kernel
#define FSTR2 149
__global__ __launch_bounds__(256) void k_nodes(
    const float* __restrict__ X, const float* __restrict__ Y,
    const int* __restrict__ Yt,
    const float* __restrict__ typeW, const float* __restrict__ typeb,
    const int* __restrict__ ptab,
    const float* __restrict__ npdW, const float* __restrict__ npdb,
    const float* __restrict__ lnNg, const float* __restrict__ lnNb,
    float* __restrict__ outV)
{
    __shared__ float fls[MM * FSTR2];
    __shared__ float sat[15];
    __shared__ float sfr[9];
    int row = blockIdx.x;
    int b = row >> 10, i = row & 1023;
    int tid = threadIdx.x;

    if (tid == 0) {
        const float* xr = X + ((size_t)b * LLEN + i) * 12;
        float nx=xr[0], ny=xr[1], nz=xr[2];
        float ax=xr[3], ay=xr[4], az=xr[5];
        float cx=xr[6], cy=xr[7], cz=xr[8];
        float bx=ax-nx, by=ay-ny, bz=az-nz;
        float vx=cx-ax, vy=cy-ay, vz=cz-az;
        float qx = by*vz - bz*vy, qy = bz*vx - bx*vz, qz = bx*vy - by*vx;
        sat[0]=nx; sat[1]=ny; sat[2]=nz;
        sat[3]=ax; sat[4]=ay; sat[5]=az;
        sat[6]=cx; sat[7]=cy; sat[8]=cz;
        sat[9]=xr[9]; sat[10]=xr[10]; sat[11]=xr[11];
        sat[12] = -0.58273431f*qx + 0.56802827f*bx - 0.54067466f*vx + ax;
        sat[13] = -0.58273431f*qy + 0.56802827f*by - 0.54067466f*vy + ay;
        sat[14] = -0.58273431f*qz + 0.56802827f*bz - 0.54067466f*vz + az;
        float e1x = nx-ax, e1y = ny-ay, e1z = nz-az;
        float n1 = fmaxf(sqrtf(e1x*e1x+e1y*e1y+e1z*e1z), 1e-12f);
        e1x/=n1; e1y/=n1; e1z/=n1;
        float dd = e1x*vx + e1y*vy + e1z*vz;
        float u2x = vx - e1x*dd, u2y = vy - e1y*dd, u2z = vz - e1z*dd;
        float n2 = fmaxf(sqrtf(u2x*u2x+u2y*u2y+u2z*u2z), 1e-12f);
        u2x/=n2; u2y/=n2; u2z/=n2;
        float e3x = e1y*u2z - e1z*u2y;
        float e3y = e1z*u2x - e1x*u2z;
        float e3z = e1x*u2y - e1y*u2x;
        sfr[0]=e1x; sfr[1]=e1y; sfr[2]=e1z;
        sfr[3]=u2x; sfr[4]=u2y; sfr[5]=u2z;
        sfr[6]=e3x; sfr[7]=e3y; sfr[8]=e3z;
    }
    __syncthreads();
    const float* Yb = Y + (size_t)row * MM * 3;
    for (int item = tid; item < MM * 10; item += 256) {
        int m = item / 10, it = item - m * 10;
        float* f = fls + m * FSTR2;
        if (it < 5) {
            float dx = sat[it*3+0] - Yb[m*3+0];
            float dy = sat[it*3+1] - Yb[m*3+1];
            float dz = sat[it*3+2] - Yb[m*3+2];
            float dist = sqrtf(dx*dx + dy*dy + dz*dz + 1e-6f);
            #pragma unroll
            for (int r = 0; r < 16; ++r) f[it*16 + r] = rbf_val(dist, r);
        } else if (it < 9) {
            int qq = it - 5;
            int t = Yt[row*MM + m];
            int p1 = ptab[120 + t], p2 = ptab[240 + t];
            #pragma unroll
            for (int c = 0; c < 16; ++c) {
                int cc = qq*16 + c;
                f[80 + cc] = typeW[t*64 + cc] + typeW[(120+p1)*64 + cc]
                           + typeW[(139+p2)*64 + cc] + typeb[cc];
            }
        } else {
            float vx = Yb[m*3+0] - sat[3];
            float vy = Yb[m*3+1] - sat[4];
            float vz = Yb[m*3+2] - sat[5];
            float l0 = sfr[0]*vx + sfr[1]*vy + sfr[2]*vz;
            float l1 = sfr[3]*vx + sfr[4]*vy + sfr[5]*vz;
            float l2 = sfr[6]*vx + sfr[7]*vy + sfr[8]*vz;
            float rxy  = sqrtf(l0*l0 + l1*l1 + 1e-8f);
            float rxyz = sqrtf(l0*l0 + l1*l1 + l2*l2) + 1e-8f;
            f[144] = l0 / rxy;
            f[145] = l1 / rxy;
            f[146] = rxy / rxyz;
            f[147] = l2 / rxyz;
        }
    }
    __syncthreads();
    int k = tid >> 3, q = tid & 7, n0 = q * 16;
    if (k < MM) {
        float acc[16];
        #pragma unroll
        for (int u = 0; u < 16; ++u) acc[u] = 0.0f;
        const float* fk = fls + k * FSTR2;
        #pragma unroll 4
        for (int c = 0; c < 148; ++c) {
            float v = fk[c];
            const float4* w = (const float4*)(npdW + (size_t)c * 128 + n0);
            float4 w0 = w[0], w1 = w[1], w2 = w[2], w3 = w[3];
            acc[0]  = fmaf(v, w0.x, acc[0]);  acc[1]  = fmaf(v, w0.y, acc[1]);
            acc[2]  = fmaf(v, w0.z, acc[2]);  acc[3]  = fmaf(v, w0.w, acc[3]);
            acc[4]  = fmaf(v, w1.x, acc[4]);  acc[5]  = fmaf(v, w1.y, acc[5]);
            acc[6]  = fmaf(v, w1.z, acc[6]);  acc[7]  = fmaf(v, w1.w, acc[7]);
            acc[8]  = fmaf(v, w2.x, acc[8]);  acc[9]  = fmaf(v, w2.y, acc[9]);
            acc[10] = fmaf(v, w2.z, acc[10]); acc[11] = fmaf(v, w2.w, acc[11]);
            acc[12] = fmaf(v, w3.x, acc[12]); acc[13] = fmaf(v, w3.y, acc[13]);
            acc[14] = fmaf(v, w3.z, acc[14]); acc[15] = fmaf(v, w3.w, acc[15]);
        }
        #pragma unroll
        for (int u = 0; u < 16; ++u) acc[u] += npdb[n0 + u];
        float s = 0.0f;
        #pragma unroll
        for (int u = 0; u < 16; ++u) s += acc[u];
        s += __shfl_xor(s, 1); s += __shfl_xor(s, 2); s += __shfl_xor(s, 4);
        float mean = s * (1.0f/128.0f);
        float s2 = 0.0f;
        #pragma unroll
        for (int u = 0; u < 16; ++u) { float c0 = acc[u] - mean; s2 += c0*c0; }
        s2 += __shfl_xor(s2, 1); s2 += __shfl_xor(s2, 2); s2 += __shfl_xor(s2, 4);
        float var = s2 * (1.0f/128.0f);
        float inv = rsqrtf(var + 1e-5f);
        float4 o4[4];
        #pragma unroll
        for (int g4 = 0; g4 < 4; ++g4) {
            float* e = (float*)&o4[g4];
            #pragma unroll
            for (int j = 0; j < 4; ++j) {
                int u = g4*4 + j;
                e[j] = (acc[u] - mean)*inv*lnNg[n0+u] + lnNb[n0+u];
            }
        }
        float4* dst = (float4*)(outV + ((size_t)row * MM + k) * 128 + n0);
        dst[0] = o4[0]; dst[1] = o4[1]; dst[2] = o4[2]; dst[3] = o4[3];
    }
}

// ---------------------------------------------------------------- Y_edges kernel (MFMA)
// out[pair][n] = LN( Σ_r rbf(d(pair))[r] * yeW[r][n] );  M=row*625 pairs, K=16 (pad 32), N=128
__global__ __launch_bounds__(256) void k_yedges(
    const float* __restrict__ Y,
    const __hip_bfloat16* __restrict__ Bpack2,
    const float* __restrict__ lnYEg, const float* __restrict__ lnYEb,
    float* __restrict__ outYE)
{
    __shared__ __align__(16) float sy4[32][4];     // ligand coords (padded, zero tail)
    int row = blockIdx.x;
    int tid = threadIdx.x;
    int wv = tid >> 6, lane = tid & 63;
    int col16 = lane & 15, kg = lane >> 4;

    if (tid < 32) { sy4[tid][0]=0.f; sy4[tid][1]=0.f; sy4[tid][2]=0.f; sy4[tid][3]=0.f; }
    __syncthreads();
    if (tid < MM*3) ((float*)sy4)[ (tid/3)*4 + (tid%3) ] = Y[(size_t)row * MM * 3 + tid];

    // B fragments + LN params (held in regs across all tiles)
    short8_t bfr[8];
    const short8_t* B2 = (const short8_t*)Bpack2;
    #pragma unroll
    for (int t = 0; t < 8; ++t) bfr[t] = B2[t*64 + lane];
    float g[8], be[8];
    #pragma unroll
    for (int t = 0; t < 8; ++t) { g[t] = lnYEg[t*16 + col16]; be[t] = lnYEb[t*16 + col16]; }
    __syncthreads();

    float* outR = outYE + (size_t)row * 625 * 128;
    for (int T = wv; T < 40; T += 4) {             // 40 tiles of 16 pairs (625 = 39*16+1)
        int p0 = T * 16;
        int p  = p0 + col16;                        // this lane's pair (A-row)
        int pc = p < 624 ? p : 624;                 // clamp for safety (tail garbage ok)
        int m1 = pc / 25, m2 = pc - 25*m1;
        float dx = sy4[m1][0] - sy4[m2][0];
        float dy = sy4[m1][1] - sy4[m2][1];
        float dz = sy4[m1][2] - sy4[m2][2];
        float d = sqrtf(dx*dx + dy*dy + dz*dz + 1e-6f);
        // A-frag: pair=lane&15, k=kg*8+j (k<16 real, else 0)
        union { short8_t v; __hip_bfloat16 h[8]; } ua;
        if (kg < 2) {
            #pragma unroll
            for (int j = 0; j < 8; ++j) ua.h[j] = __float2bfloat16(rbf_val(d, kg*8 + j));
        } else {
            ua.v = (short8_t){0,0,0,0,0,0,0,0};
        }
        f32x4 acc[8];
        #pragma unroll
        for (int t = 0; t < 8; ++t)
            acc[t] = __builtin_amdgcn_mfma_f32_16x16x32_bf16(ua.v, bfr[t],
                         (f32x4){0.f,0.f,0.f,0.f}, 0, 0, 0);
        // LN + store: D row = kg*4+r (pair), col = t*16+col16
        #pragma unroll
        for (int r = 0; r < 4; ++r) {
            float s = 0.0f;
            #pragma unroll
            for (int t = 0; t < 8; ++t) s += acc[t][r];
            s += __shfl_xor(s, 1); s += __shfl_xor(s, 2);
            s += __shfl_xor(s, 4); s += __shfl_xor(s, 8);
            float mean = s * (1.0f/128.0f);
            float q2 = 0.0f;
            #pragma unroll
            for (int t = 0; t < 8; ++t) { float c0 = acc[t][r] - mean; q2 += c0*c0; }
            q2 += __shfl_xor(q2, 1); q2 += __shfl_xor(q2, 2);
            q2 += __shfl_xor(q2, 4); q2 += __shfl_xor(q2, 8);
            float inv = rsqrtf(q2 * (1.0f/128.0f) + 1e-5f);
            int pr = p0 + kg*4 + r;
            if (pr < 625) {
                float* dst = outR + (size_t)pr * 128 + col16;
                #pragma unroll
                for (int t = 0; t < 8; ++t) dst[t*16] = (acc[t][r] - mean)*inv*g[t] + be[t];
            }
        }
    }
}

// ---------------------------------------------------------------- Y_nodes + Y_m kernel
__global__ __launch_bounds__(256) void k_ynodes(
    const int* __restrict__ Yt, const float* __restrict__ Ym,
    const int* __restrict__ ptab, const float* __restrict__ ynW,
    const float* __restrict__ lnYNg, const float* __restrict__ lnYNb,
    float* __restrict__ outYN, float* __restrict__ outYM)
{
    int wv = threadIdx.x >> 6, lane = threadIdx.x & 63;
    int row = blockIdx.x * 4 + wv;      // < 51200
    int t = Yt[row];
    int p1 = ptab[120 + t], p2 = ptab[240 + t];
    int r0 = t, r1 = 120 + p1, r2 = 139 + p2;
    float x0 = ynW[r0*128 + lane] + ynW[r1*128 + lane] + ynW[r2*128 + lane];
    float x1 = ynW[r0*128 + 64 + lane] + ynW[r1*128 + 64 + lane] + ynW[r2*128 + 64 + lane];
    float s = x0 + x1, s2 = x0*x0 + x1*x1;
    #pragma unroll
    for (int o = 1; o < 64; o <<= 1) { s += __shfl_xor(s, o); s2 += __shfl_xor(s2, o); }
    float mean = s * (1.0f/128.0f);
    float var  = s2 * (1.0f/128.0f) - mean*mean;
    float inv  = rsqrtf(var + 1e-5f);
    size_t base = (size_t)row * 128;
    outYN[base + lane]      = (x0 - mean)*inv*lnYNg[lane]    + lnYNb[lane];
    outYN[base + 64 + lane] = (x1 - mean)*inv*lnYNg[64+lane] + lnYNb[64+lane];
    if (lane == 0) outYM[row] = Ym[row];
}

// ---------------------------------------------------------------- launcher
extern "C" void kernel_launch(void* const* d_in, const int* in_sizes, int n_in,
                              void* d_out, int out_size, void* d_ws, size_t ws_size,
                              hipStream_t stream) {
    const float* X     = (const float*)d_in[0];
    const float* Y     = (const float*)d_in[1];
    const float* Ym    = (const float*)d_in[2];
    const int*   Yt    = (const int*)d_in[3];
    const float* mask  = (const float*)d_in[4];
    const int*   Ridx  = (const int*)d_in[5];
    const int*   chain = (const int*)d_in[6];
    const float* posW  = (const float*)d_in[7];
    const float* posb  = (const float*)d_in[8];
    const float* edgeW = (const float*)d_in[9];
    const float* lnEg  = (const float*)d_in[10];
    const float* lnEb  = (const float*)d_in[11];
    const float* npdW  = (const float*)d_in[12];
    const float* npdb  = (const float*)d_in[13];
    const float* lnNg  = (const float*)d_in[14];
    const float* lnNb  = (const float*)d_in[15];
    const float* typeW = (const float*)d_in[16];
    const float* typeb = (const float*)d_in[17];
    const float* ynW   = (const float*)d_in[18];
    const float* yeW   = (const float*)d_in[19];
    const float* lnYEg = (const float*)d_in[20];
    const float* lnYEb = (const float*)d_in[21];
    const float* lnYNg = (const float*)d_in[22];
    const float* lnYNb = (const float*)d_in[23];
    const int*   ptab  = (const int*)d_in[24];

    float* o = (float*)d_out;
    // Scratch in the head of the Y_nodes region: written by k_prep/k_topk,
    // read by k_edges (eidx,dnb,Bpack) and k_yedges (Bpack2), then fully
    // overwritten by k_ynodes (launched LAST) before validation.
    int*   eidx = (int*)(o + OFF_YN);                             // 256 KB
    float* dnb  = (float*)(o + OFF_YN) + BB*LLEN*KK;              // 256 KB
    __hip_bfloat16* Bpack  = (__hip_bfloat16*)(dnb + BB*LLEN*KK); // 104 KB
    __hip_bfloat16* Bpack2 = Bpack + 6656*8;                      // 8 KB

    k_prep  <<<28, 256, 0, stream>>>(edgeW, yeW, Bpack, Bpack2);
    k_topk  <<<BB*LLEN, 256, 0, stream>>>(X, mask, eidx, dnb, o + OFF_EI);
    k_edges <<<BB*LLEN/2, 256, 0, stream>>>(X, Ridx, chain, posW, posb, Bpack,
                                            lnEg, lnEb, eidx, dnb, o + OFF_E);
    k_nodes <<<BB*LLEN, 256, 0, stream>>>(X, Y, Yt, typeW, typeb, ptab,
                                          npdW, npdb, lnNg, lnNb, o + OFF_V);
    k_yedges<<<BB*LLEN, 256, 0, stream>>>(Y, Bpack2, lnYEg, lnYEb, o + OFF_YE);
    k_ynodes<<<BB*LLEN*MM/4, 256, 0, stream>>>(Yt, Ym, ptab, ynW,
                                               lnYNg, lnYNb, o + OFF_YN, o + OFF_YM);
}

// Round 8
// 262.952 us; speedup vs baseline: 5.7046x; 1.8391x over previous
//
#include <hip/hip_runtime.h>
#include <hip/hip_bf16.h>
#include <stdint.h>

#define BB 2
#define LLEN 1024
#define MM 25
#define KK 32

// d_out is FLOAT32, concatenated in return order:
// (V, E, E_idx, Y_nodes, Y_edges, Y_m) — offsets in f32 elements.
#define OFF_V   0
#define OFF_E   6553600
#define OFF_EI  14942208
#define OFF_YN  15007744
#define OFF_YE  21561344
#define OFF_YM  185401344

#define KD 416          // K dim of edge GEMM
#define KP 424          // edge A-tile row stride (bf16)
#define KP2 168         // node A-tile row stride (bf16), K=148 pad 160
#define NR 5            // rows per k_nodes block (125 atoms -> 128 A-rows)

typedef __attribute__((ext_vector_type(8))) short short8_t;   // 8 bf16 = 4 VGPR
typedef __attribute__((ext_vector_type(4))) float f32x4;

__constant__ int g_PA[24] = {0,2,3,4,1,1,1,1,0,0,0,4,4,3,0,2,3,4,2,3,4,2,3,2};
__constant__ int g_PB[24] = {0,2,3,4,0,2,3,4,2,3,4,2,3,2,1,1,1,1,0,0,0,4,4,3};

__device__ __forceinline__ float rbf_val(float d, int r) {
    float mu = 2.0f + (20.0f / 15.0f) * (float)r;
    float z = (d - mu) * 0.8f;   // /1.25
    return __expf(-z * z);
}

// ---------------------------------------------------------------- top-k kernel
__global__ __launch_bounds__(256) void k_topk(
    const float* __restrict__ X, const float* __restrict__ mask,
    int* __restrict__ eidx, float* __restrict__ dnb,
    float* __restrict__ outEI)
{
    __shared__ float sD[LLEN];
    __shared__ float sMaxA[256];
    __shared__ unsigned long long sB[256];
    int row = blockIdx.x;            // b*L + i
    int b = row >> 10, i = row & 1023;
    int tid = threadIdx.x;
    const float* Xb = X + (size_t)b * LLEN * 12;
    float cax = Xb[i*12+3], cay = Xb[i*12+4], caz = Xb[i*12+5];
    float mi = mask[row];
    float lmax = 0.0f;
    for (int j = tid; j < LLEN; j += 256) {
        float dx = cax - Xb[j*12+3];
        float dy = cay - Xb[j*12+4];
        float dz = caz - Xb[j*12+5];
        float d = sqrtf(dx*dx + dy*dy + dz*dz + 1e-6f) * (mi * mask[b*LLEN + j]);
        sD[j] = d;
        lmax = fmaxf(lmax, d);
    }
    sMaxA[tid] = lmax;
    __syncthreads();
    for (int w = 128; w > 0; w >>= 1) {
        if (tid < w) sMaxA[tid] = fmaxf(sMaxA[tid], sMaxA[tid + w]);
        __syncthreads();
    }
    float rmax = sMaxA[0];
    for (int j = tid; j < LLEN; j += 256) {
        float m2 = mi * mask[b*LLEN + j];
        sD[j] = sD[j] + (1.0f - m2) * rmax;
    }
    __syncthreads();
    for (int it = 0; it < KK; ++it) {
        unsigned long long best = ~0ull;
        for (int j = tid; j < LLEN; j += 256) {
            unsigned long long p = ((unsigned long long)__float_as_uint(sD[j]) << 32) | (unsigned)j;
            if (p < best) best = p;
        }
        sB[tid] = best;
        __syncthreads();
        for (int w = 128; w > 0; w >>= 1) {
            if (tid < w) { if (sB[tid + w] < sB[tid]) sB[tid] = sB[tid + w]; }
            __syncthreads();
        }
        if (tid == 0) {
            unsigned long long wv = sB[0];
            int jw = (int)(wv & 0xffffffffu);
            float dv = __uint_as_float((unsigned)(wv >> 32));
            sD[jw] = __uint_as_float(0x7f800000u);   // +inf
            eidx[row*KK + it] = jw;
            dnb[row*KK + it] = dv;
            outEI[row*KK + it] = (float)jw;
        }
        __syncthreads();
    }
}

// ------------------------------------------------- B-pack prep -> bf16 frag order
// [0,6656):    edgeW  (13 ksteps)    [6656,7168): yeW (1 kstep, K=16 pad 32)
// [7168,9728): npdW   (5 ksteps, K=148 pad 160, zero-padded)
__global__ __launch_bounds__(256) void k_prep(
    const float* __restrict__ W, const float* __restrict__ yeW,
    const float* __restrict__ npdW,
    __hip_bfloat16* __restrict__ Bp, __hip_bfloat16* __restrict__ Bp2,
    __hip_bfloat16* __restrict__ Bp3)
{
    int idx = blockIdx.x * 256 + threadIdx.x;
    if (idx < 6656) {
        int lane = idx & 63, tt = (idx >> 6) & 7, ks = idx >> 9;
        int k0 = ks*32 + (lane >> 4)*8;
        int n  = tt*16 + (lane & 15);
        __hip_bfloat16* dst = Bp + (size_t)idx * 8;
        #pragma unroll
        for (int j = 0; j < 8; ++j) dst[j] = __float2bfloat16(W[(size_t)(k0 + j)*128 + n]);
    } else if (idx < 7168) {
        int i2 = idx - 6656;
        int lane = i2 & 63, tt = i2 >> 6;
        int kg = lane >> 4;
        int n  = tt*16 + (lane & 15);
        __hip_bfloat16* dst = Bp2 + (size_t)i2 * 8;
        #pragma unroll
        for (int j = 0; j < 8; ++j) {
            float v = (kg < 2) ? yeW[(size_t)(kg*8 + j)*128 + n] : 0.0f;
            dst[j] = __float2bfloat16(v);
        }
    } else if (idx < 9728) {
        int i3 = idx - 7168;
        int lane = i3 & 63, tt = (i3 >> 6) & 7, ks = i3 >> 9;   // ks < 5
        int k0 = ks*32 + (lane >> 4)*8;
        int n  = tt*16 + (lane & 15);
        __hip_bfloat16* dst = Bp3 + (size_t)i3 * 8;
        #pragma unroll
        for (int j = 0; j < 8; ++j) {
            int k = k0 + j;
            float v = (k < 148) ? npdW[(size_t)k*128 + n] : 0.0f;
            dst[j] = __float2bfloat16(v);
        }
    }
}

// ---------------------------------------------------------------- edge kernel (MFMA)
__global__ __launch_bounds__(256) void k_edges(
    const float* __restrict__ X,
    const int* __restrict__ Ridx, const int* __restrict__ chain,
    const float* __restrict__ posW, const float* __restrict__ posb,
    const __hip_bfloat16* __restrict__ Bpack,
    const float* __restrict__ lnEg, const float* __restrict__ lnEb,
    const int* __restrict__ eidx, const float* __restrict__ dnb,
    float* __restrict__ outE)
{
    __shared__ __align__(16) __hip_bfloat16 A[64 * KP];   // 53 KB feature tile
    __shared__ float aj[64][16];
    __shared__ float ai[2][16];
    __shared__ int   didx[64];
    int r0 = blockIdx.x * 2;
    int b  = r0 >> 10;
    int tid = threadIdx.x;
    const float* Xb = X + (size_t)b * LLEN * 12;

    if (tid < 64) {
        int e = tid, row = r0 + (e >> 5), k = e & 31;
        int j = eidx[row*KK + k];
        const float* xr = Xb + j*12;
        float nx=xr[0], ny=xr[1], nz=xr[2];
        float ax=xr[3], ay=xr[4], az=xr[5];
        float cx=xr[6], cy=xr[7], cz=xr[8];
        float bx=ax-nx, by=ay-ny, bz=az-nz;
        float vx=cx-ax, vy=cy-ay, vz=cz-az;
        float qx = by*vz - bz*vy, qy = bz*vx - bx*vz, qz = bx*vy - by*vx;
        aj[e][0]=nx; aj[e][1]=ny; aj[e][2]=nz;
        aj[e][3]=ax; aj[e][4]=ay; aj[e][5]=az;
        aj[e][6]=cx; aj[e][7]=cy; aj[e][8]=cz;
        aj[e][9]=xr[9]; aj[e][10]=xr[10]; aj[e][11]=xr[11];
        aj[e][12] = -0.58273431f*qx + 0.56802827f*bx - 0.54067466f*vx + ax;
        aj[e][13] = -0.58273431f*qy + 0.56802827f*by - 0.54067466f*vy + ay;
        aj[e][14] = -0.58273431f*qz + 0.56802827f*bz - 0.54067466f*vz + az;
        int off = Ridx[row] - Ridx[b*LLEN + j];
        int ec = (chain[row] == chain[b*LLEN + j]) ? 1 : 0;
        int dc = off + 32; dc = dc < 0 ? 0 : (dc > 64 ? 64 : dc);
        didx[e] = ec ? dc : 65;
    }
    if (tid >= 64 && tid < 66) {
        int rl = tid - 64;
        int i = (r0 + rl) & 1023;
        const float* xr = Xb + i*12;
        float nx=xr[0], ny=xr[1], nz=xr[2];
        float ax=xr[3], ay=xr[4], az=xr[5];
        float cx=xr[6], cy=xr[7], cz=xr[8];
        float bx=ax-nx, by=ay-ny, bz=az-nz;
        float vx=cx-ax, vy=cy-ay, vz=cz-az;
        float qx = by*vz - bz*vy, qy = bz*vx - bx*vz, qz = bx*vy - by*vx;
        ai[rl][0]=nx; ai[rl][1]=ny; ai[rl][2]=nz;
        ai[rl][3]=ax; ai[rl][4]=ay; ai[rl][5]=az;
        ai[rl][6]=cx; ai[rl][7]=cy; ai[rl][8]=cz;
        ai[rl][9]=xr[9]; ai[rl][10]=xr[10]; ai[rl][11]=xr[11];
        ai[rl][12] = -0.58273431f*qx + 0.56802827f*bx - 0.54067466f*vx + ax;
        ai[rl][13] = -0.58273431f*qy + 0.56802827f*by - 0.54067466f*vy + ay;
        ai[rl][14] = -0.58273431f*qz + 0.56802827f*bz - 0.54067466f*vz + az;
    }
    __syncthreads();

    for (int item = tid; item < 64 * 26; item += 256) {
        int e = item / 26, it = item - e * 26;
        int rl = e >> 5;
        __hip_bfloat16* f = A + e * KP;
        if (it == 0) {
            int d = didx[e];
            #pragma unroll
            for (int c = 0; c < 16; ++c) f[c] = __float2bfloat16(posW[d*16 + c] + posb[c]);
        } else {
            float dist;
            if (it == 1) {
                dist = dnb[(r0 + rl)*KK + (e & 31)];
            } else {
                int p = it - 2;
                int a = g_PA[p], q = g_PB[p];
                float dx = ai[rl][a*3+0] - aj[e][q*3+0];
                float dy = ai[rl][a*3+1] - aj[e][q*3+1];
                float dz = ai[rl][a*3+2] - aj[e][q*3+2];
                dist = sqrtf(dx*dx + dy*dy + dz*dz + 1e-6f);
            }
            int base = 16 + (it - 1) * 16;
            #pragma unroll
            for (int r = 0; r < 16; ++r) f[base + r] = __float2bfloat16(rbf_val(dist, r));
        }
    }
    __syncthreads();

    int wid = tid >> 6, lane = tid & 63;
    int col16 = lane & 15, kg = lane >> 4;
    f32x4 acc[8];
    #pragma unroll
    for (int t = 0; t < 8; ++t) acc[t] = (f32x4){0.f, 0.f, 0.f, 0.f};
    const __hip_bfloat16* Ar = A + (wid*16 + col16) * KP + kg * 8;
    const short8_t* Bp = (const short8_t*)Bpack;
    for (int ks = 0; ks < 13; ++ks) {
        short8_t a = *(const short8_t*)(Ar + ks*32);
        #pragma unroll
        for (int t = 0; t < 8; ++t) {
            short8_t bf = Bp[(ks*8 + t)*64 + lane];
            acc[t] = __builtin_amdgcn_mfma_f32_16x16x32_bf16(a, bf, acc[t], 0, 0, 0);
        }
    }

    float g[8], be[8];
    #pragma unroll
    for (int t = 0; t < 8; ++t) { g[t] = lnEg[t*16 + col16]; be[t] = lnEb[t*16 + col16]; }
    #pragma unroll
    for (int r = 0; r < 4; ++r) {
        float s = 0.0f;
        #pragma unroll
        for (int t = 0; t < 8; ++t) s += acc[t][r];
        s += __shfl_xor(s, 1); s += __shfl_xor(s, 2);
        s += __shfl_xor(s, 4); s += __shfl_xor(s, 8);
        float mean = s * (1.0f/128.0f);
        float q2 = 0.0f;
        #pragma unroll
        for (int t = 0; t < 8; ++t) { float c0 = acc[t][r] - mean; q2 += c0*c0; }
        q2 += __shfl_xor(q2, 1); q2 += __shfl_xor(q2, 2);
        q2 += __shfl_xor(q2, 4); q2 += __shfl_xor(q2, 8);
        float inv = rsqrtf(q2 * (1.0f/128.0f) + 1e-5f);
        int eb  = wid*16 + kg*4 + r;
        int row = r0 + (eb >> 5), kk = eb & 31;
        float* dst = outE + ((size_t)row*KK + kk)*128 + col16;
        #pragma unroll
        for (int t = 0; t < 8; ++t) dst[t*16] = (acc[t][r] - mean)*inv*g[t] + be[t];
    }
}

// ---------------------------------------------------------------- node (V) kernel (MFMA)
// V[row,m] = LN( feat(148) @ npdW + npdb ); block = 5 rows = 125 atoms -> 128 A-rows
__global__ __launch_bounds__(256) void k_nodes(
    const float* __restrict__ X, const float* __restrict__ Y,
    const int* __restrict__ Yt,
    const float* __restrict__ typeW, const float* __restrict__ typeb,
    const int* __restrict__ ptab,
    const __hip_bfloat16* __restrict__ Bpack3, const float* __restrict__ npdb,
    const float* __restrict__ lnNg, const float* __restrict__ lnNb,
    float* __restrict__ outV)
{
    __shared__ __align__(16) __hip_bfloat16 A[128 * KP2];   // 42 KB
    __shared__ float sat[NR][15];
    __shared__ float sfr[NR][9];
    int r0 = blockIdx.x * NR;
    int nrows = (2048 - r0) < NR ? (2048 - r0) : NR;
    int natoms = nrows * MM;
    int tid = threadIdx.x;

    if (tid < nrows) {
        int row = r0 + tid;
        int b = row >> 10, i = row & 1023;
        const float* xr = X + ((size_t)b * LLEN + i) * 12;
        float nx=xr[0], ny=xr[1], nz=xr[2];
        float ax=xr[3], ay=xr[4], az=xr[5];
        float cx=xr[6], cy=xr[7], cz=xr[8];
        float bx=ax-nx, by=ay-ny, bz=az-nz;
        float vx=cx-ax, vy=cy-ay, vz=cz-az;
        float qx = by*vz - bz*vy, qy = bz*vx - bx*vz, qz = bx*vy - by*vx;
        sat[tid][0]=nx; sat[tid][1]=ny; sat[tid][2]=nz;
        sat[tid][3]=ax; sat[tid][4]=ay; sat[tid][5]=az;
        sat[tid][6]=cx; sat[tid][7]=cy; sat[tid][8]=cz;
        sat[tid][9]=xr[9]; sat[tid][10]=xr[10]; sat[tid][11]=xr[11];
        sat[tid][12] = -0.58273431f*qx + 0.56802827f*bx - 0.54067466f*vx + ax;
        sat[tid][13] = -0.58273431f*qy + 0.56802827f*by - 0.54067466f*vy + ay;
        sat[tid][14] = -0.58273431f*qz + 0.56802827f*bz - 0.54067466f*vz + az;
        float e1x = nx-ax, e1y = ny-ay, e1z = nz-az;
        float n1 = fmaxf(sqrtf(e1x*e1x+e1y*e1y+e1z*e1z), 1e-12f);
        e1x/=n1; e1y/=n1; e1z/=n1;
        float dd = e1x*vx + e1y*vy + e1z*vz;
        float u2x = vx - e1x*dd, u2y = vy - e1y*dd, u2z = vz - e1z*dd;
        float n2 = fmaxf(sqrtf(u2x*u2x+u2y*u2y+u2z*u2z), 1e-12f);
        u2x/=n2; u2y/=n2; u2z/=n2;
        sfr[tid][0]=e1x; sfr[tid][1]=e1y; sfr[tid][2]=e1z;
        sfr[tid][3]=u2x; sfr[tid][4]=u2y; sfr[tid][5]=u2z;
        sfr[tid][6]=e1y*u2z - e1z*u2y;
        sfr[tid][7]=e1z*u2x - e1x*u2z;
        sfr[tid][8]=e1x*u2y - e1y*u2x;
    }
    __syncthreads();

    for (int item = tid; item < natoms * 10; item += 256) {
        int a = item / 10, it = item - a * 10;
        int rl = a / MM, m = a - rl * MM;
        int row = r0 + rl;
        const float* Yb = Y + (size_t)row * MM * 3 + m * 3;
        __hip_bfloat16* f = A + a * KP2;
        if (it < 5) {
            float dx = sat[rl][it*3+0] - Yb[0];
            float dy = sat[rl][it*3+1] - Yb[1];
            float dz = sat[rl][it*3+2] - Yb[2];
            float dist = sqrtf(dx*dx + dy*dy + dz*dz + 1e-6f);
            #pragma unroll
            for (int r = 0; r < 16; ++r) f[it*16 + r] = __float2bfloat16(rbf_val(dist, r));
        } else if (it < 9) {
            int qq = it - 5;
            int t = Yt[row*MM + m];
            int p1 = ptab[120 + t], p2 = ptab[240 + t];
            #pragma unroll
            for (int c = 0; c < 16; ++c) {
                int cc = qq*16 + c;
                f[80 + cc] = __float2bfloat16(typeW[t*64 + cc] + typeW[(120+p1)*64 + cc]
                           + typeW[(139+p2)*64 + cc] + typeb[cc]);
            }
        } else {
            float vx = Yb[0] - sat[rl][3];
            float vy = Yb[1] - sat[rl][4];
            float vz = Yb[2] - sat[rl][5];
            float l0 = sfr[rl][0]*vx + sfr[rl][1]*vy + sfr[rl][2]*vz;
            float l1 = sfr[rl][3]*vx + sfr[rl][4]*vy + sfr[rl][5]*vz;
            float l2 = sfr[rl][6]*vx + sfr[rl][7]*vy + sfr[rl][8]*vz;
            float rxy  = sqrtf(l0*l0 + l1*l1 + 1e-8f);
            float rxyz = sqrtf(l0*l0 + l1*l1 + l2*l2) + 1e-8f;
            f[144] = __float2bfloat16(l0 / rxy);
            f[145] = __float2bfloat16(l1 / rxy);
            f[146] = __float2bfloat16(rxy / rxyz);
            f[147] = __float2bfloat16(l2 / rxyz);
            // zero K-pad (B is also zero there; avoids NaN*0)
            #pragma unroll
            for (int c = 148; c < 160; ++c) f[c] = __float2bfloat16(0.0f);
        }
    }
    __syncthreads();

    int wid = tid >> 6, lane = tid & 63;
    int col16 = lane & 15, kg = lane >> 4;
    const short8_t* Bp = (const short8_t*)Bpack3;
    float g[8], be[8], bias[8];
    #pragma unroll
    for (int t = 0; t < 8; ++t) {
        g[t] = lnNg[t*16 + col16]; be[t] = lnNb[t*16 + col16];
        bias[t] = npdb[t*16 + col16];
    }
    #pragma unroll
    for (int half = 0; half < 2; ++half) {
        int tile = wid + half*4;
        int abase = tile * 16;
        if (abase < natoms) {
            const __hip_bfloat16* Ar = A + (abase + col16) * KP2 + kg * 8;
            f32x4 acc[8];
            #pragma unroll
            for (int t = 0; t < 8; ++t) acc[t] = (f32x4){0.f, 0.f, 0.f, 0.f};
            for (int ks = 0; ks < 5; ++ks) {
                short8_t a = *(const short8_t*)(Ar + ks*32);
                #pragma unroll
                for (int t = 0; t < 8; ++t) {
                    short8_t bf = Bp[(ks*8 + t)*64 + lane];
                    acc[t] = __builtin_amdgcn_mfma_f32_16x16x32_bf16(a, bf, acc[t], 0, 0, 0);
                }
            }
            #pragma unroll
            for (int r = 0; r < 4; ++r) {
                float s = 0.0f;
                #pragma unroll
                for (int t = 0; t < 8; ++t) { acc[t][r] += bias[t]; s += acc[t][r]; }
                s += __shfl_xor(s, 1); s += __shfl_xor(s, 2);
                s += __shfl_xor(s, 4); s += __shfl_xor(s, 8);
                float mean = s * (1.0f/128.0f);
                float q2 = 0.0f;
                #pragma unroll
                for (int t = 0; t < 8; ++t) { float c0 = acc[t][r] - mean; q2 += c0*c0; }
                q2 += __shfl_xor(q2, 1); q2 += __shfl_xor(q2, 2);
                q2 += __shfl_xor(q2, 4); q2 += __shfl_xor(q2, 8);
                float inv = rsqrtf(q2 * (1.0f/128.0f) + 1e-5f);
                int aa = abase + kg*4 + r;
                if (aa < natoms) {
                    float* dst = outV + ((size_t)r0 * MM + aa) * 128 + col16;
                    #pragma unroll
                    for (int t = 0; t < 8; ++t) dst[t*16] = (acc[t][r] - mean)*inv*g[t] + be[t];
                }
            }
        }
    }
}

// ---------------------------------------------------------------- Y_edges kernel (MFMA, staged stores)
__global__ __launch_bounds__(256) void k_yedges(
    const float* __restrict__ Y,
    const __hip_bfloat16* __restrict__ Bpack2,
    const float* __restrict__ lnYEg, const float* __restrict__ lnYEb,
    float* __restrict__ outYE)
{
    __shared__ __align__(16) float sy4[32][4];
    __shared__ __align__(16) float stage[4][16*132];   // per-wave 8.4 KB stage
    int row = blockIdx.x;
    int tid = threadIdx.x;
    int wv = tid >> 6, lane = tid & 63;
    int col16 = lane & 15, kg = lane >> 4;

    if (tid < 32) { sy4[tid][0]=0.f; sy4[tid][1]=0.f; sy4[tid][2]=0.f; sy4[tid][3]=0.f; }
    __syncthreads();
    if (tid < MM*3) ((float*)sy4)[ (tid/3)*4 + (tid%3) ] = Y[(size_t)row * MM * 3 + tid];

    short8_t bfr[8];
    const short8_t* B2 = (const short8_t*)Bpack2;
    #pragma unroll
    for (int t = 0; t < 8; ++t) bfr[t] = B2[t*64 + lane];
    float g[8], be[8];
    #pragma unroll
    for (int t = 0; t < 8; ++t) { g[t] = lnYEg[t*16 + col16]; be[t] = lnYEb[t*16 + col16]; }
    __syncthreads();

    float* outR = outYE + (size_t)row * 625 * 128;
    float* sbuf = stage[wv];
    for (int T = wv; T < 40; T += 4) {             // 40 tiles of 16 pairs (625 = 39*16+1)
        int p0 = T * 16;
        int p  = p0 + col16;
        int pc = p < 624 ? p : 624;
        int m1 = pc / 25, m2 = pc - 25*m1;
        float dx = sy4[m1][0] - sy4[m2][0];
        float dy = sy4[m1][1] - sy4[m2][1];
        float dz = sy4[m1][2] - sy4[m2][2];
        float d = sqrtf(dx*dx + dy*dy + dz*dz + 1e-6f);
        union { short8_t v; __hip_bfloat16 h[8]; } ua;
        if (kg < 2) {
            #pragma unroll
            for (int j = 0; j < 8; ++j) ua.h[j] = __float2bfloat16(rbf_val(d, kg*8 + j));
        } else {
            ua.v = (short8_t){0,0,0,0,0,0,0,0};
        }
        f32x4 acc[8];
        #pragma unroll
        for (int t = 0; t < 8; ++t)
            acc[t] = __builtin_amdgcn_mfma_f32_16x16x32_bf16(ua.v, bfr[t],
                         (f32x4){0.f,0.f,0.f,0.f}, 0, 0, 0);
        // LN -> per-wave LDS stage (stride 132 words: 2-way bank = free, 16B-aligned rows)
        #pragma unroll
        for (int r = 0; r < 4; ++r) {
            float s = 0.0f;
            #pragma unroll
            for (int t = 0; t < 8; ++t) s += acc[t][r];
            s += __shfl_xor(s, 1); s += __shfl_xor(s, 2);
            s += __shfl_xor(s, 4); s += __shfl_xor(s, 8);
            float mean = s * (1.0f/128.0f);
            float q2 = 0.0f;
            #pragma unroll
            for (int t = 0; t < 8; ++t) { float c0 = acc[t][r] - mean; q2 += c0*c0; }
            q2 += __shfl_xor(q2, 1); q2 += __shfl_xor(q2, 2);
            q2 += __shfl_xor(q2, 4); q2 += __shfl_xor(q2, 8);
            float inv = rsqrtf(q2 * (1.0f/128.0f) + 1e-5f);
            float* sr = sbuf + (kg*4 + r) * 132;
            #pragma unroll
            for (int t = 0; t < 8; ++t) sr[t*16 + col16] = (acc[t][r] - mean)*inv*g[t] + be[t];
        }
        // coalesced readback + store: 8 x 1KB contiguous per wave
        #pragma unroll
        for (int it = 0; it < 8; ++it) {
            int off = it*256 + lane*4;                 // 0..2044
            int rr = (off >> 7), cc = off & 127;
            float4 v = *(const float4*)(sbuf + rr*132 + cc);
            int gbase = p0*128 + off;
            if (gbase < 80000) *(float4*)(outR + gbase) = v;   // 625*128
        }
    }
}

// ---------------------------------------------------------------- Y_nodes + Y_m kernel
__global__ __launch_bounds__(256) void k_ynodes(
    const int* __restrict__ Yt, const float* __restrict__ Ym,
    const int* __restrict__ ptab, const float* __restrict__ ynW,
    const float* __restrict__ lnYNg, const float* __restrict__ lnYNb,
    float* __restrict__ outYN, float* __restrict__ outYM)
{
    int wv = threadIdx.x >> 6, lane = threadIdx.x & 63;
    int row = blockIdx.x * 4 + wv;      // < 51200
    int t = Yt[row];
    int p1 = ptab[120 + t], p2 = ptab[240 + t];
    int r0 = t, r1 = 120 + p1, r2 = 139 + p2;
    float x0 = ynW[r0*128 + lane] + ynW[r1*128 + lane] + ynW[r2*128 + lane];
    float x1 = ynW[r0*128 + 64 + lane] + ynW[r1*128 + 64 + lane] + ynW[r2*128 + 64 + lane];
    float s = x0 + x1, s2 = x0*x0 + x1*x1;
    #pragma unroll
    for (int o = 1; o < 64; o <<= 1) { s += __shfl_xor(s, o); s2 += __shfl_xor(s2, o); }
    float mean = s * (1.0f/128.0f);
    float var  = s2 * (1.0f/128.0f) - mean*mean;
    float inv  = rsqrtf(var + 1e-5f);
    size_t base = (size_t)row * 128;
    outYN[base + lane]      = (x0 - mean)*inv*lnYNg[lane]    + lnYNb[lane];
    outYN[base + 64 + lane] = (x1 - mean)*inv*lnYNg[64+lane] + lnYNb[64+lane];
    if (lane == 0) outYM[row] = Ym[row];
}

// ---------------------------------------------------------------- launcher
extern "C" void kernel_launch(void* const* d_in, const int* in_sizes, int n_in,
                              void* d_out, int out_size, void* d_ws, size_t ws_size,
                              hipStream_t stream) {
    const float* X     = (const float*)d_in[0];
    const float* Y     = (const float*)d_in[1];
    const float* Ym    = (const float*)d_in[2];
    const int*   Yt    = (const int*)d_in[3];
    const float* mask  = (const float*)d_in[4];
    const int*   Ridx  = (const int*)d_in[5];
    const int*   chain = (const int*)d_in[6];
    const float* posW  = (const float*)d_in[7];
    const float* posb  = (const float*)d_in[8];
    const float* edgeW = (const float*)d_in[9];
    const float* lnEg  = (const float*)d_in[10];
    const float* lnEb  = (const float*)d_in[11];
    const float* npdW  = (const float*)d_in[12];
    const float* npdb  = (const float*)d_in[13];
    const float* lnNg  = (const float*)d_in[14];
    const float* lnNb  = (const float*)d_in[15];
    const float* typeW = (const float*)d_in[16];
    const float* typeb = (const float*)d_in[17];
    const float* ynW   = (const float*)d_in[18];
    const float* yeW   = (const float*)d_in[19];
    const float* lnYEg = (const float*)d_in[20];
    const float* lnYEb = (const float*)d_in[21];
    const float* lnYNg = (const float*)d_in[22];
    const float* lnYNb = (const float*)d_in[23];
    const int*   ptab  = (const int*)d_in[24];

    float* o = (float*)d_out;
    // Scratch in the head of the Y_nodes region: written by k_prep/k_topk,
    // read by k_edges/k_nodes/k_yedges, then fully overwritten by k_ynodes
    // (launched LAST) before validation.
    int*   eidx = (int*)(o + OFF_YN);                             // 256 KB
    float* dnb  = (float*)(o + OFF_YN) + BB*LLEN*KK;              // 256 KB
    __hip_bfloat16* Bpack  = (__hip_bfloat16*)(dnb + BB*LLEN*KK); // 104 KB
    __hip_bfloat16* Bpack2 = Bpack + 6656*8;                      // 8 KB
    __hip_bfloat16* Bpack3 = Bpack2 + 512*8;                      // 40 KB

    k_prep  <<<38, 256, 0, stream>>>(edgeW, yeW, npdW, Bpack, Bpack2, Bpack3);
    k_topk  <<<BB*LLEN, 256, 0, stream>>>(X, mask, eidx, dnb, o + OFF_EI);
    k_edges <<<BB*LLEN/2, 256, 0, stream>>>(X, Ridx, chain, posW, posb, Bpack,
                                            lnEg, lnEb, eidx, dnb, o + OFF_E);
    k_nodes <<<(BB*LLEN + NR - 1)/NR, 256, 0, stream>>>(X, Y, Yt, typeW, typeb, ptab,
                                          Bpack3, npdb, lnNg, lnNb, o + OFF_V);
    k_yedges<<<BB*LLEN, 256, 0, stream>>>(Y, Bpack2, lnYEg, lnYEb, o + OFF_YE);
    k_ynodes<<<BB*LLEN*MM/4, 256, 0, stream>>>(Yt, Ym, ptab, ynW,
                                               lnYNg, lnYNb, o + OFF_YN, o + OFF_YM);
}

// Round 9
// 251.386 us; speedup vs baseline: 5.9671x; 1.0460x over previous
//
#include <hip/hip_runtime.h>
#include <hip/hip_bf16.h>
#include <stdint.h>

#define BB 2
#define LLEN 1024
#define MM 25
#define KK 32

// d_out is FLOAT32, concatenated in return order:
// (V, E, E_idx, Y_nodes, Y_edges, Y_m) — offsets in f32 elements.
#define OFF_V   0
#define OFF_E   6553600
#define OFF_EI  14942208
#define OFF_YN  15007744
#define OFF_YE  21561344
#define OFF_YM  185401344

#define KD 416          // K dim of edge GEMM
#define KP 424          // edge A-tile row stride (bf16)
#define KP2 168         // node A-tile row stride (bf16), K=148 pad 160
#define NR 5            // rows per k_nodes block (125 atoms -> 128 A-rows)

typedef __attribute__((ext_vector_type(8))) short short8_t;   // 8 bf16 = 4 VGPR
typedef __attribute__((ext_vector_type(4))) float f32x4;

__constant__ int g_PA[24] = {0,2,3,4,1,1,1,1,0,0,0,4,4,3,0,2,3,4,2,3,4,2,3,2};
__constant__ int g_PB[24] = {0,2,3,4,0,2,3,4,2,3,4,2,3,2,1,1,1,1,0,0,0,4,4,3};

__device__ __forceinline__ float rbf_val(float d, int r) {
    float mu = 2.0f + (20.0f / 15.0f) * (float)r;
    float z = (d - mu) * 0.8f;   // /1.25
    return __expf(-z * z);
}

// ---------------------------------------------------------------- top-k kernel
// wave-per-row in-register tournament: lane l holds candidates q*64+l (q<16)
// packed as (f32bits<<32)|j — identical ascending/tie-break semantics to the
// validated LDS-tree version, zero barriers.
__global__ __launch_bounds__(256) void k_topk(
    const float* __restrict__ X, const float* __restrict__ mask,
    int* __restrict__ eidx, float* __restrict__ dnb,
    float* __restrict__ outEI)
{
    int wid = threadIdx.x >> 6, lane = threadIdx.x & 63;
    int row = blockIdx.x * 4 + wid;          // 512 blocks * 4 = 2048 rows
    int b = row >> 10, i = row & 1023;
    const float* Xb = X + (size_t)b * LLEN * 12;
    const float* mb = mask + b * LLEN;
    float cax = Xb[i*12+3], cay = Xb[i*12+4], caz = Xb[i*12+5];
    float mi = mask[row];

    float df[16], mm[16];
    float lmax = 0.0f;
    #pragma unroll
    for (int q = 0; q < 16; ++q) {
        int j = q*64 + lane;
        float dx = cax - Xb[j*12+3];
        float dy = cay - Xb[j*12+4];
        float dz = caz - Xb[j*12+5];
        float m2 = mi * mb[j];
        float d = sqrtf(dx*dx + dy*dy + dz*dz + 1e-6f) * m2;
        df[q] = d; mm[q] = m2;
        lmax = fmaxf(lmax, d);
    }
    #pragma unroll
    for (int o = 32; o > 0; o >>= 1) lmax = fmaxf(lmax, __shfl_xor(lmax, o));

    unsigned long long pack[16];
    #pragma unroll
    for (int q = 0; q < 16; ++q) {
        float da = df[q] + (1.0f - mm[q]) * lmax;
        pack[q] = ((unsigned long long)__float_as_uint(da) << 32) | (unsigned)(q*64 + lane);
    }

    int   myJw = 0;
    float myDv = 0.0f;
    for (int it = 0; it < KK; ++it) {
        unsigned long long lmin = pack[0];
        #pragma unroll
        for (int q = 1; q < 16; ++q) if (pack[q] < lmin) lmin = pack[q];
        #pragma unroll
        for (int o = 32; o > 0; o >>= 1) {
            unsigned long long other = __shfl_xor(lmin, o);
            if (other < lmin) lmin = other;
        }
        int jw = (int)(lmin & 0xffffffffu);
        if (lane == it) { myJw = jw; myDv = __uint_as_float((unsigned)(lmin >> 32)); }
        int lw = jw & 63, qw = jw >> 6;
        #pragma unroll
        for (int q = 0; q < 16; ++q)
            if (lane == lw && q == qw) pack[q] = ~0ull;
    }
    if (lane < KK) {
        eidx[row*KK + lane]  = myJw;
        dnb [row*KK + lane]  = myDv;
        outEI[row*KK + lane] = (float)myJw;
    }
}

// ------------------------------------------------- B-pack prep -> bf16 frag order
// [0,6656):    edgeW  (13 ksteps)    [6656,7168): yeW (1 kstep, K=16 pad 32)
// [7168,9728): npdW   (5 ksteps, K=148 pad 160, zero-padded)
__global__ __launch_bounds__(256) void k_prep(
    const float* __restrict__ W, const float* __restrict__ yeW,
    const float* __restrict__ npdW,
    __hip_bfloat16* __restrict__ Bp, __hip_bfloat16* __restrict__ Bp2,
    __hip_bfloat16* __restrict__ Bp3)
{
    int idx = blockIdx.x * 256 + threadIdx.x;
    if (idx < 6656) {
        int lane = idx & 63, tt = (idx >> 6) & 7, ks = idx >> 9;
        int k0 = ks*32 + (lane >> 4)*8;
        int n  = tt*16 + (lane & 15);
        __hip_bfloat16* dst = Bp + (size_t)idx * 8;
        #pragma unroll
        for (int j = 0; j < 8; ++j) dst[j] = __float2bfloat16(W[(size_t)(k0 + j)*128 + n]);
    } else if (idx < 7168) {
        int i2 = idx - 6656;
        int lane = i2 & 63, tt = i2 >> 6;
        int kg = lane >> 4;
        int n  = tt*16 + (lane & 15);
        __hip_bfloat16* dst = Bp2 + (size_t)i2 * 8;
        #pragma unroll
        for (int j = 0; j < 8; ++j) {
            float v = (kg < 2) ? yeW[(size_t)(kg*8 + j)*128 + n] : 0.0f;
            dst[j] = __float2bfloat16(v);
        }
    } else if (idx < 9728) {
        int i3 = idx - 7168;
        int lane = i3 & 63, tt = (i3 >> 6) & 7, ks = i3 >> 9;   // ks < 5
        int k0 = ks*32 + (lane >> 4)*8;
        int n  = tt*16 + (lane & 15);
        __hip_bfloat16* dst = Bp3 + (size_t)i3 * 8;
        #pragma unroll
        for (int j = 0; j < 8; ++j) {
            int k = k0 + j;
            float v = (k < 148) ? npdW[(size_t)k*128 + n] : 0.0f;
            dst[j] = __float2bfloat16(v);
        }
    }
}

// ---------------------------------------------------------------- edge kernel (MFMA)
__global__ __launch_bounds__(256) void k_edges(
    const float* __restrict__ X,
    const int* __restrict__ Ridx, const int* __restrict__ chain,
    const float* __restrict__ posW, const float* __restrict__ posb,
    const __hip_bfloat16* __restrict__ Bpack,
    const float* __restrict__ lnEg, const float* __restrict__ lnEb,
    const int* __restrict__ eidx, const float* __restrict__ dnb,
    float* __restrict__ outE)
{
    __shared__ __align__(16) __hip_bfloat16 A[64 * KP];   // 53 KB; reused as store stage
    __shared__ float aj[64][16];
    __shared__ float ai[2][16];
    __shared__ int   didx[64];
    int r0 = blockIdx.x * 2;
    int b  = r0 >> 10;
    int tid = threadIdx.x;
    const float* Xb = X + (size_t)b * LLEN * 12;

    if (tid < 64) {
        int e = tid, row = r0 + (e >> 5), k = e & 31;
        int j = eidx[row*KK + k];
        const float* xr = Xb + j*12;
        float nx=xr[0], ny=xr[1], nz=xr[2];
        float ax=xr[3], ay=xr[4], az=xr[5];
        float cx=xr[6], cy=xr[7], cz=xr[8];
        float bx=ax-nx, by=ay-ny, bz=az-nz;
        float vx=cx-ax, vy=cy-ay, vz=cz-az;
        float qx = by*vz - bz*vy, qy = bz*vx - bx*vz, qz = bx*vy - by*vx;
        aj[e][0]=nx; aj[e][1]=ny; aj[e][2]=nz;
        aj[e][3]=ax; aj[e][4]=ay; aj[e][5]=az;
        aj[e][6]=cx; aj[e][7]=cy; aj[e][8]=cz;
        aj[e][9]=xr[9]; aj[e][10]=xr[10]; aj[e][11]=xr[11];
        aj[e][12] = -0.58273431f*qx + 0.56802827f*bx - 0.54067466f*vx + ax;
        aj[e][13] = -0.58273431f*qy + 0.56802827f*by - 0.54067466f*vy + ay;
        aj[e][14] = -0.58273431f*qz + 0.56802827f*bz - 0.54067466f*vz + az;
        int off = Ridx[row] - Ridx[b*LLEN + j];
        int ec = (chain[row] == chain[b*LLEN + j]) ? 1 : 0;
        int dc = off + 32; dc = dc < 0 ? 0 : (dc > 64 ? 64 : dc);
        didx[e] = ec ? dc : 65;
    }
    if (tid >= 64 && tid < 66) {
        int rl = tid - 64;
        int i = (r0 + rl) & 1023;
        const float* xr = Xb + i*12;
        float nx=xr[0], ny=xr[1], nz=xr[2];
        float ax=xr[3], ay=xr[4], az=xr[5];
        float cx=xr[6], cy=xr[7], cz=xr[8];
        float bx=ax-nx, by=ay-ny, bz=az-nz;
        float vx=cx-ax, vy=cy-ay, vz=cz-az;
        float qx = by*vz - bz*vy, qy = bz*vx - bx*vz, qz = bx*vy - by*vx;
        ai[rl][0]=nx; ai[rl][1]=ny; ai[rl][2]=nz;
        ai[rl][3]=ax; ai[rl][4]=ay; ai[rl][5]=az;
        ai[rl][6]=cx; ai[rl][7]=cy; ai[rl][8]=cz;
        ai[rl][9]=xr[9]; ai[rl][10]=xr[10]; ai[rl][11]=xr[11];
        ai[rl][12] = -0.58273431f*qx + 0.56802827f*bx - 0.54067466f*vx + ax;
        ai[rl][13] = -0.58273431f*qy + 0.56802827f*by - 0.54067466f*vy + ay;
        ai[rl][14] = -0.58273431f*qz + 0.56802827f*bz - 0.54067466f*vz + az;
    }
    __syncthreads();

    for (int item = tid; item < 64 * 26; item += 256) {
        int e = item / 26, it = item - e * 26;
        int rl = e >> 5;
        __hip_bfloat16* f = A + e * KP;
        if (it == 0) {
            int d = didx[e];
            #pragma unroll
            for (int c = 0; c < 16; ++c) f[c] = __float2bfloat16(posW[d*16 + c] + posb[c]);
        } else {
            float dist;
            if (it == 1) {
                dist = dnb[(r0 + rl)*KK + (e & 31)];
            } else {
                int p = it - 2;
                int a = g_PA[p], q = g_PB[p];
                float dx = ai[rl][a*3+0] - aj[e][q*3+0];
                float dy = ai[rl][a*3+1] - aj[e][q*3+1];
                float dz = ai[rl][a*3+2] - aj[e][q*3+2];
                dist = sqrtf(dx*dx + dy*dy + dz*dz + 1e-6f);
            }
            int base = 16 + (it - 1) * 16;
            #pragma unroll
            for (int r = 0; r < 16; ++r) f[base + r] = __float2bfloat16(rbf_val(dist, r));
        }
    }
    __syncthreads();

    int wid = tid >> 6, lane = tid & 63;
    int col16 = lane & 15, kg = lane >> 4;
    f32x4 acc[8];
    #pragma unroll
    for (int t = 0; t < 8; ++t) acc[t] = (f32x4){0.f, 0.f, 0.f, 0.f};
    const __hip_bfloat16* Ar = A + (wid*16 + col16) * KP + kg * 8;
    const short8_t* Bp = (const short8_t*)Bpack;
    for (int ks = 0; ks < 13; ++ks) {
        short8_t a = *(const short8_t*)(Ar + ks*32);
        #pragma unroll
        for (int t = 0; t < 8; ++t) {
            short8_t bf = Bp[(ks*8 + t)*64 + lane];
            acc[t] = __builtin_amdgcn_mfma_f32_16x16x32_bf16(a, bf, acc[t], 0, 0, 0);
        }
    }
    __syncthreads();   // all waves done reading A; safe to reuse as stage

    float* sbuf = (float*)A + wid * (16*132);   // per-wave 8.4 KB stage (stride 132)
    float g[8], be[8];
    #pragma unroll
    for (int t = 0; t < 8; ++t) { g[t] = lnEg[t*16 + col16]; be[t] = lnEb[t*16 + col16]; }
    #pragma unroll
    for (int r = 0; r < 4; ++r) {
        float s = 0.0f;
        #pragma unroll
        for (int t = 0; t < 8; ++t) s += acc[t][r];
        s += __shfl_xor(s, 1); s += __shfl_xor(s, 2);
        s += __shfl_xor(s, 4); s += __shfl_xor(s, 8);
        float mean = s * (1.0f/128.0f);
        float q2 = 0.0f;
        #pragma unroll
        for (int t = 0; t < 8; ++t) { float c0 = acc[t][r] - mean; q2 += c0*c0; }
        q2 += __shfl_xor(q2, 1); q2 += __shfl_xor(q2, 2);
        q2 += __shfl_xor(q2, 4); q2 += __shfl_xor(q2, 8);
        float inv = rsqrtf(q2 * (1.0f/128.0f) + 1e-5f);
        float* sr = sbuf + (kg*4 + r) * 132;
        #pragma unroll
        for (int t = 0; t < 8; ++t) sr[t*16 + col16] = (acc[t][r] - mean)*inv*g[t] + be[t];
    }
    // coalesced store: wave's 16 edges are contiguous 8 KB at (r0*32 + wid*16)*128
    float* gdst = outE + ((size_t)r0 * KK + wid*16) * 128;
    #pragma unroll
    for (int it = 0; it < 8; ++it) {
        int off = it*256 + lane*4;
        int rr = off >> 7, cc = off & 127;
        float4 v = *(const float4*)(sbuf + rr*132 + cc);
        *(float4*)(gdst + off) = v;
    }
}

// ---------------------------------------------------------------- node (V) kernel (MFMA)
__global__ __launch_bounds__(256) void k_nodes(
    const float* __restrict__ X, const float* __restrict__ Y,
    const int* __restrict__ Yt,
    const float* __restrict__ typeW, const float* __restrict__ typeb,
    const int* __restrict__ ptab,
    const __hip_bfloat16* __restrict__ Bpack3, const float* __restrict__ npdb,
    const float* __restrict__ lnNg, const float* __restrict__ lnNb,
    float* __restrict__ outV)
{
    __shared__ __align__(16) __hip_bfloat16 A[128 * KP2];   // 42 KB
    __shared__ float sat[NR][15];
    __shared__ float sfr[NR][9];
    int r0 = blockIdx.x * NR;
    int nrows = (2048 - r0) < NR ? (2048 - r0) : NR;
    int natoms = nrows * MM;
    int tid = threadIdx.x;

    if (tid < nrows) {
        int row = r0 + tid;
        int b = row >> 10, i = row & 1023;
        const float* xr = X + ((size_t)b * LLEN + i) * 12;
        float nx=xr[0], ny=xr[1], nz=xr[2];
        float ax=xr[3], ay=xr[4], az=xr[5];
        float cx=xr[6], cy=xr[7], cz=xr[8];
        float bx=ax-nx, by=ay-ny, bz=az-nz;
        float vx=cx-ax, vy=cy-ay, vz=cz-az;
        float qx = by*vz - bz*vy, qy = bz*vx - bx*vz, qz = bx*vy - by*vx;
        sat[tid][0]=nx; sat[tid][1]=ny; sat[tid][2]=nz;
        sat[tid][3]=ax; sat[tid][4]=ay; sat[tid][5]=az;
        sat[tid][6]=cx; sat[tid][7]=cy; sat[tid][8]=cz;
        sat[tid][9]=xr[9]; sat[tid][10]=xr[10]; sat[tid][11]=xr[11];
        sat[tid][12] = -0.58273431f*qx + 0.56802827f*bx - 0.54067466f*vx + ax;
        sat[tid][13] = -0.58273431f*qy + 0.56802827f*by - 0.54067466f*vy + ay;
        sat[tid][14] = -0.58273431f*qz + 0.56802827f*bz - 0.54067466f*vz + az;
        float e1x = nx-ax, e1y = ny-ay, e1z = nz-az;
        float n1 = fmaxf(sqrtf(e1x*e1x+e1y*e1y+e1z*e1z), 1e-12f);
        e1x/=n1; e1y/=n1; e1z/=n1;
        float dd = e1x*vx + e1y*vy + e1z*vz;
        float u2x = vx - e1x*dd, u2y = vy - e1y*dd, u2z = vz - e1z*dd;
        float n2 = fmaxf(sqrtf(u2x*u2x+u2y*u2y+u2z*u2z), 1e-12f);
        u2x/=n2; u2y/=n2; u2z/=n2;
        sfr[tid][0]=e1x; sfr[tid][1]=e1y; sfr[tid][2]=e1z;
        sfr[tid][3]=u2x; sfr[tid][4]=u2y; sfr[tid][5]=u2z;
        sfr[tid][6]=e1y*u2z - e1z*u2y;
        sfr[tid][7]=e1z*u2x - e1x*u2z;
        sfr[tid][8]=e1x*u2y - e1y*u2x;
    }
    __syncthreads();

    for (int item = tid; item < natoms * 10; item += 256) {
        int a = item / 10, it = item - a * 10;
        int rl = a / MM, m = a - rl * MM;
        int row = r0 + rl;
        const float* Yb = Y + (size_t)row * MM * 3 + m * 3;
        __hip_bfloat16* f = A + a * KP2;
        if (it < 5) {
            float dx = sat[rl][it*3+0] - Yb[0];
            float dy = sat[rl][it*3+1] - Yb[1];
            float dz = sat[rl][it*3+2] - Yb[2];
            float dist = sqrtf(dx*dx + dy*dy + dz*dz + 1e-6f);
            #pragma unroll
            for (int r = 0; r < 16; ++r) f[it*16 + r] = __float2bfloat16(rbf_val(dist, r));
        } else if (it < 9) {
            int qq = it - 5;
            int t = Yt[row*MM + m];
            int p1 = ptab[120 + t], p2 = ptab[240 + t];
            #pragma unroll
            for (int c = 0; c < 16; ++c) {
                int cc = qq*16 + c;
                f[80 + cc] = __float2bfloat16(typeW[t*64 + cc] + typeW[(120+p1)*64 + cc]
                           + typeW[(139+p2)*64 + cc] + typeb[cc]);
            }
        } else {
            float vx = Yb[0] - sat[rl][3];
            float vy = Yb[1] - sat[rl][4];
            float vz = Yb[2] - sat[rl][5];
            float l0 = sfr[rl][0]*vx + sfr[rl][1]*vy + sfr[rl][2]*vz;
            float l1 = sfr[rl][3]*vx + sfr[rl][4]*vy + sfr[rl][5]*vz;
            float l2 = sfr[rl][6]*vx + sfr[rl][7]*vy + sfr[rl][8]*vz;
            float rxy  = sqrtf(l0*l0 + l1*l1 + 1e-8f);
            float rxyz = sqrtf(l0*l0 + l1*l1 + l2*l2) + 1e-8f;
            f[144] = __float2bfloat16(l0 / rxy);
            f[145] = __float2bfloat16(l1 / rxy);
            f[146] = __float2bfloat16(rxy / rxyz);
            f[147] = __float2bfloat16(l2 / rxyz);
            #pragma unroll
            for (int c = 148; c < 160; ++c) f[c] = __float2bfloat16(0.0f);
        }
    }
    __syncthreads();

    int wid = tid >> 6, lane = tid & 63;
    int col16 = lane & 15, kg = lane >> 4;
    const short8_t* Bp = (const short8_t*)Bpack3;
    float g[8], be[8], bias[8];
    #pragma unroll
    for (int t = 0; t < 8; ++t) {
        g[t] = lnNg[t*16 + col16]; be[t] = lnNb[t*16 + col16];
        bias[t] = npdb[t*16 + col16];
    }
    #pragma unroll
    for (int half = 0; half < 2; ++half) {
        int tile = wid + half*4;
        int abase = tile * 16;
        if (abase < natoms) {
            const __hip_bfloat16* Ar = A + (abase + col16) * KP2 + kg * 8;
            f32x4 acc[8];
            #pragma unroll
            for (int t = 0; t < 8; ++t) acc[t] = (f32x4){0.f, 0.f, 0.f, 0.f};
            for (int ks = 0; ks < 5; ++ks) {
                short8_t a = *(const short8_t*)(Ar + ks*32);
                #pragma unroll
                for (int t = 0; t < 8; ++t) {
                    short8_t bf = Bp[(ks*8 + t)*64 + lane];
                    acc[t] = __builtin_amdgcn_mfma_f32_16x16x32_bf16(a, bf, acc[t], 0, 0, 0);
                }
            }
            #pragma unroll
            for (int r = 0; r < 4; ++r) {
                float s = 0.0f;
                #pragma unroll
                for (int t = 0; t < 8; ++t) { acc[t][r] += bias[t]; s += acc[t][r]; }
                s += __shfl_xor(s, 1); s += __shfl_xor(s, 2);
                s += __shfl_xor(s, 4); s += __shfl_xor(s, 8);
                float mean = s * (1.0f/128.0f);
                float q2 = 0.0f;
                #pragma unroll
                for (int t = 0; t < 8; ++t) { float c0 = acc[t][r] - mean; q2 += c0*c0; }
                q2 += __shfl_xor(q2, 1); q2 += __shfl_xor(q2, 2);
                q2 += __shfl_xor(q2, 4); q2 += __shfl_xor(q2, 8);
                float inv = rsqrtf(q2 * (1.0f/128.0f) + 1e-5f);
                int aa = abase + kg*4 + r;
                if (aa < natoms) {
                    float* dst = outV + ((size_t)r0 * MM + aa) * 128 + col16;
                    #pragma unroll
                    for (int t = 0; t < 8; ++t) dst[t*16] = (acc[t][r] - mean)*inv*g[t] + be[t];
                }
            }
        }
    }
}

// ---------------------------------------------------------------- Y_edges kernel (MFMA, staged stores)
__global__ __launch_bounds__(256) void k_yedges(
    const float* __restrict__ Y,
    const __hip_bfloat16* __restrict__ Bpack2,
    const float* __restrict__ lnYEg, const float* __restrict__ lnYEb,
    float* __restrict__ outYE)
{
    __shared__ __align__(16) float sy4[32][4];
    __shared__ __align__(16) float stage[4][16*132];   // per-wave 8.4 KB stage
    int row = blockIdx.x;
    int tid = threadIdx.x;
    int wv = tid >> 6, lane = tid & 63;
    int col16 = lane & 15, kg = lane >> 4;

    if (tid < 32) { sy4[tid][0]=0.f; sy4[tid][1]=0.f; sy4[tid][2]=0.f; sy4[tid][3]=0.f; }
    __syncthreads();
    if (tid < MM*3) ((float*)sy4)[ (tid/3)*4 + (tid%3) ] = Y[(size_t)row * MM * 3 + tid];

    short8_t bfr[8];
    const short8_t* B2 = (const short8_t*)Bpack2;
    #pragma unroll
    for (int t = 0; t < 8; ++t) bfr[t] = B2[t*64 + lane];
    float g[8], be[8];
    #pragma unroll
    for (int t = 0; t < 8; ++t) { g[t] = lnYEg[t*16 + col16]; be[t] = lnYEb[t*16 + col16]; }
    __syncthreads();

    float* outR = outYE + (size_t)row * 625 * 128;
    float* sbuf = stage[wv];
    for (int T = wv; T < 40; T += 4) {
        int p0 = T * 16;
        int p  = p0 + col16;
        int pc = p < 624 ? p : 624;
        int m1 = pc / 25, m2 = pc - 25*m1;
        float dx = sy4[m1][0] - sy4[m2][0];
        float dy = sy4[m1][1] - sy4[m2][1];
        float dz = sy4[m1][2] - sy4[m2][2];
        float d = sqrtf(dx*dx + dy*dy + dz*dz + 1e-6f);
        union { short8_t v; __hip_bfloat16 h[8]; } ua;
        if (kg < 2) {
            #pragma unroll
            for (int j = 0; j < 8; ++j) ua.h[j] = __float2bfloat16(rbf_val(d, kg*8 + j));
        } else {
            ua.v = (short8_t){0,0,0,0,0,0,0,0};
        }
        f32x4 acc[8];
        #pragma unroll
        for (int t = 0; t < 8; ++t)
            acc[t] = __builtin_amdgcn_mfma_f32_16x16x32_bf16(ua.v, bfr[t],
                         (f32x4){0.f,0.f,0.f,0.f}, 0, 0, 0);
        #pragma unroll
        for (int r = 0; r < 4; ++r) {
            float s = 0.0f;
            #pragma unroll
            for (int t = 0; t < 8; ++t) s += acc[t][r];
            s += __shfl_xor(s, 1); s += __shfl_xor(s, 2);
            s += __shfl_xor(s, 4); s += __shfl_xor(s, 8);
            float mean = s * (1.0f/128.0f);
            float q2 = 0.0f;
            #pragma unroll
            for (int t = 0; t < 8; ++t) { float c0 = acc[t][r] - mean; q2 += c0*c0; }
            q2 += __shfl_xor(q2, 1); q2 += __shfl_xor(q2, 2);
            q2 += __shfl_xor(q2, 4); q2 += __shfl_xor(q2, 8);
            float inv = rsqrtf(q2 * (1.0f/128.0f) + 1e-5f);
            float* sr = sbuf + (kg*4 + r) * 132;
            #pragma unroll
            for (int t = 0; t < 8; ++t) sr[t*16 + col16] = (acc[t][r] - mean)*inv*g[t] + be[t];
        }
        #pragma unroll
        for (int it = 0; it < 8; ++it) {
            int off = it*256 + lane*4;
            int rr = (off >> 7), cc = off & 127;
            float4 v = *(const float4*)(sbuf + rr*132 + cc);
            int gbase = p0*128 + off;
            if (gbase < 80000) *(float4*)(outR + gbase) = v;   // 625*128
        }
    }
}

// ---------------------------------------------------------------- Y_nodes + Y_m kernel
__global__ __launch_bounds__(256) void k_ynodes(
    const int* __restrict__ Yt, const float* __restrict__ Ym,
    const int* __restrict__ ptab, const float* __restrict__ ynW,
    const float* __restrict__ lnYNg, const float* __restrict__ lnYNb,
    float* __restrict__ outYN, float* __restrict__ outYM)
{
    int wv = threadIdx.x >> 6, lane = threadIdx.x & 63;
    int row = blockIdx.x * 4 + wv;      // < 51200
    int t = Yt[row];
    int p1 = ptab[120 + t], p2 = ptab[240 + t];
    int r0 = t, r1 = 120 + p1, r2 = 139 + p2;
    float x0 = ynW[r0*128 + lane] + ynW[r1*128 + lane] + ynW[r2*128 + lane];
    float x1 = ynW[r0*128 + 64 + lane] + ynW[r1*128 + 64 + lane] + ynW[r2*128 + 64 + lane];
    float s = x0 + x1, s2 = x0*x0 + x1*x1;
    #pragma unroll
    for (int o = 1; o < 64; o <<= 1) { s += __shfl_xor(s, o); s2 += __shfl_xor(s2, o); }
    float mean = s * (1.0f/128.0f);
    float var  = s2 * (1.0f/128.0f) - mean*mean;
    float inv  = rsqrtf(var + 1e-5f);
    size_t base = (size_t)row * 128;
    outYN[base + lane]      = (x0 - mean)*inv*lnYNg[lane]    + lnYNb[lane];
    outYN[base + 64 + lane] = (x1 - mean)*inv*lnYNg[64+lane] + lnYNb[64+lane];
    if (lane == 0) outYM[row] = Ym[row];
}

// ---------------------------------------------------------------- launcher
extern "C" void kernel_launch(void* const* d_in, const int* in_sizes, int n_in,
                              void* d_out, int out_size, void* d_ws, size_t ws_size,
                              hipStream_t stream) {
    const float* X     = (const float*)d_in[0];
    const float* Y     = (const float*)d_in[1];
    const float* Ym    = (const float*)d_in[2];
    const int*   Yt    = (const int*)d_in[3];
    const float* mask  = (const float*)d_in[4];
    const int*   Ridx  = (const int*)d_in[5];
    const int*   chain = (const int*)d_in[6];
    const float* posW  = (const float*)d_in[7];
    const float* posb  = (const float*)d_in[8];
    const float* edgeW = (const float*)d_in[9];
    const float* lnEg  = (const float*)d_in[10];
    const float* lnEb  = (const float*)d_in[11];
    const float* npdW  = (const float*)d_in[12];
    const float* npdb  = (const float*)d_in[13];
    const float* lnNg  = (const float*)d_in[14];
    const float* lnNb  = (const float*)d_in[15];
    const float* typeW = (const float*)d_in[16];
    const float* typeb = (const float*)d_in[17];
    const float* ynW   = (const float*)d_in[18];
    const float* yeW   = (const float*)d_in[19];
    const float* lnYEg = (const float*)d_in[20];
    const float* lnYEb = (const float*)d_in[21];
    const float* lnYNg = (const float*)d_in[22];
    const float* lnYNb = (const float*)d_in[23];
    const int*   ptab  = (const int*)d_in[24];

    float* o = (float*)d_out;
    // Scratch in the head of the Y_nodes region: written by k_prep/k_topk,
    // read by k_edges/k_nodes/k_yedges, then fully overwritten by k_ynodes
    // (launched LAST) before validation.
    int*   eidx = (int*)(o + OFF_YN);                             // 256 KB
    float* dnb  = (float*)(o + OFF_YN) + BB*LLEN*KK;              // 256 KB
    __hip_bfloat16* Bpack  = (__hip_bfloat16*)(dnb + BB*LLEN*KK); // 104 KB
    __hip_bfloat16* Bpack2 = Bpack + 6656*8;                      // 8 KB
    __hip_bfloat16* Bpack3 = Bpack2 + 512*8;                      // 40 KB

    k_prep  <<<38, 256, 0, stream>>>(edgeW, yeW, npdW, Bpack, Bpack2, Bpack3);
    k_topk  <<<BB*LLEN/4, 256, 0, stream>>>(X, mask, eidx, dnb, o + OFF_EI);
    k_edges <<<BB*LLEN/2, 256, 0, stream>>>(X, Ridx, chain, posW, posb, Bpack,
                                            lnEg, lnEb, eidx, dnb, o + OFF_E);
    k_nodes <<<(BB*LLEN + NR - 1)/NR, 256, 0, stream>>>(X, Y, Yt, typeW, typeb, ptab,
                                          Bpack3, npdb, lnNg, lnNb, o + OFF_V);
    k_yedges<<<BB*LLEN, 256, 0, stream>>>(Y, Bpack2, lnYEg, lnYEb, o + OFF_YE);
    k_ynodes<<<BB*LLEN*MM/4, 256, 0, stream>>>(Yt, Ym, ptab, ynW,
                                               lnYNg, lnYNb, o + OFF_YN, o + OFF_YM);
}

// Round 10
// 241.793 us; speedup vs baseline: 6.2038x; 1.0397x over previous
//
#include <hip/hip_runtime.h>
#include <hip/hip_bf16.h>
#include <stdint.h>

#define BB 2
#define LLEN 1024
#define MM 25
#define KK 32

// d_out is FLOAT32, concatenated in return order:
// (V, E, E_idx, Y_nodes, Y_edges, Y_m) — offsets in f32 elements.
#define OFF_V   0
#define OFF_E   6553600
#define OFF_EI  14942208
#define OFF_YN  15007744
#define OFF_YE  21561344
#define OFF_YM  185401344

#define KD 416
#define KP 424          // edge A-tile row stride (bf16), 848B = 53*16
#define KP2 168         // node A-tile row stride (bf16), 336B = 21*16
#define NR 5            // rows per k_nodes block

#define SCRATCH_BYTES (680*1024)

typedef __attribute__((ext_vector_type(8))) short short8_t;   // 8 bf16 = 4 VGPR
typedef __attribute__((ext_vector_type(4))) float f32x4;

__constant__ int g_PA[24] = {0,2,3,4,1,1,1,1,0,0,0,4,4,3,0,2,3,4,2,3,4,2,3,2};
__constant__ int g_PB[24] = {0,2,3,4,0,2,3,4,2,3,4,2,3,2,1,1,1,1,0,0,0,4,4,3};

__device__ __forceinline__ float rbf_val(float d, int r) {
    float mu = 2.0f + (20.0f / 15.0f) * (float)r;
    float z = (d - mu) * 0.8f;
    return __expf(-z * z);
}

// ------------------------------------------------- merged prep + topk
// blocks [0,512): wave-per-row top-k tournament (LDS-staged coords)
// blocks [512,550): B-pack prep (edgeW/yeW/npdW -> bf16 MFMA frag order)
__global__ __launch_bounds__(256) void k_pretopk(
    const float* __restrict__ X, const float* __restrict__ mask,
    const float* __restrict__ W, const float* __restrict__ yeW,
    const float* __restrict__ npdW,
    __hip_bfloat16* __restrict__ Bp, __hip_bfloat16* __restrict__ Bp2,
    __hip_bfloat16* __restrict__ Bp3,
    int* __restrict__ eidx, float* __restrict__ dnb,
    float* __restrict__ outEI)
{
    __shared__ float sx[1024], syy[1024], sz[1024], sm[1024];
    int tid = threadIdx.x;

    if (blockIdx.x >= 512) {              // ---- prep branch
        int idx = (blockIdx.x - 512) * 256 + tid;
        if (idx < 6656) {
            int lane = idx & 63, tt = (idx >> 6) & 7, ks = idx >> 9;
            int k0 = ks*32 + (lane >> 4)*8;
            int n  = tt*16 + (lane & 15);
            __hip_bfloat16* dst = Bp + (size_t)idx * 8;
            #pragma unroll
            for (int j = 0; j < 8; ++j) dst[j] = __float2bfloat16(W[(size_t)(k0 + j)*128 + n]);
        } else if (idx < 7168) {
            int i2 = idx - 6656;
            int lane = i2 & 63, tt = i2 >> 6;
            int kg = lane >> 4;
            int n  = tt*16 + (lane & 15);
            __hip_bfloat16* dst = Bp2 + (size_t)i2 * 8;
            #pragma unroll
            for (int j = 0; j < 8; ++j) {
                float v = (kg < 2) ? yeW[(size_t)(kg*8 + j)*128 + n] : 0.0f;
                dst[j] = __float2bfloat16(v);
            }
        } else if (idx < 9728) {
            int i3 = idx - 7168;
            int lane = i3 & 63, tt = (i3 >> 6) & 7, ks = i3 >> 9;
            int k0 = ks*32 + (lane >> 4)*8;
            int n  = tt*16 + (lane & 15);
            __hip_bfloat16* dst = Bp3 + (size_t)i3 * 8;
            #pragma unroll
            for (int j = 0; j < 8; ++j) {
                int k = k0 + j;
                float v = (k < 148) ? npdW[(size_t)k*128 + n] : 0.0f;
                dst[j] = __float2bfloat16(v);
            }
        }
        return;
    }

    // ---- top-k branch (validated tournament; LDS-staged inputs)
    int wid = tid >> 6, lane = tid & 63;
    int row0 = blockIdx.x * 4;
    int b = row0 >> 10;
    const float* Xb = X + (size_t)b * LLEN * 12;
    const float* mb = mask + b * LLEN;
    for (int j = tid; j < 1024; j += 256) {
        sx[j]  = Xb[j*12+3];
        syy[j] = Xb[j*12+4];
        sz[j]  = Xb[j*12+5];
        sm[j]  = mb[j];
    }
    __syncthreads();

    int row = row0 + wid, i = row & 1023;
    float cax = sx[i], cay = syy[i], caz = sz[i];
    float mi = sm[i];

    float df[16], mm_[16];
    float lmax = 0.0f;
    #pragma unroll
    for (int q = 0; q < 16; ++q) {
        int j = q*64 + lane;
        float dx = cax - sx[j];
        float dy = cay - syy[j];
        float dz = caz - sz[j];
        float m2 = mi * sm[j];
        float d = sqrtf(dx*dx + dy*dy + dz*dz + 1e-6f) * m2;
        df[q] = d; mm_[q] = m2;
        lmax = fmaxf(lmax, d);
    }
    #pragma unroll
    for (int o = 32; o > 0; o >>= 1) lmax = fmaxf(lmax, __shfl_xor(lmax, o));

    unsigned long long pack[16];
    #pragma unroll
    for (int q = 0; q < 16; ++q) {
        float da = df[q] + (1.0f - mm_[q]) * lmax;
        pack[q] = ((unsigned long long)__float_as_uint(da) << 32) | (unsigned)(q*64 + lane);
    }

    int   myJw = 0;
    float myDv = 0.0f;
    for (int it = 0; it < KK; ++it) {
        unsigned long long lmin = pack[0];
        #pragma unroll
        for (int q = 1; q < 16; ++q) if (pack[q] < lmin) lmin = pack[q];
        #pragma unroll
        for (int o = 32; o > 0; o >>= 1) {
            unsigned long long other = __shfl_xor(lmin, o);
            if (other < lmin) lmin = other;
        }
        int jw = (int)(lmin & 0xffffffffu);
        if (lane == it) { myJw = jw; myDv = __uint_as_float((unsigned)(lmin >> 32)); }
        int lw = jw & 63, qw = jw >> 6;
        #pragma unroll
        for (int q = 0; q < 16; ++q)
            if (lane == lw && q == qw) pack[q] = ~0ull;
    }
    if (lane < KK) {
        eidx[row*KK + lane]  = myJw;
        dnb [row*KK + lane]  = myDv;
        outEI[row*KK + lane] = (float)myJw;
    }
}

// ---------------------------------------------------------------- edge kernel (MFMA)
__global__ __launch_bounds__(256) void k_edges(
    const float* __restrict__ X,
    const int* __restrict__ Ridx, const int* __restrict__ chain,
    const float* __restrict__ posW, const float* __restrict__ posb,
    const __hip_bfloat16* __restrict__ Bpack,
    const float* __restrict__ lnEg, const float* __restrict__ lnEb,
    const int* __restrict__ eidx, const float* __restrict__ dnb,
    float* __restrict__ outE)
{
    __shared__ __align__(16) __hip_bfloat16 A[64 * KP];   // 53 KB; reused as store stage
    __shared__ float aj[64][16];
    __shared__ float ai[2][16];
    __shared__ int   didx[64];
    int r0 = blockIdx.x * 2;
    int b  = r0 >> 10;
    int tid = threadIdx.x;
    const float* Xb = X + (size_t)b * LLEN * 12;

    if (tid < 64) {
        int e = tid, row = r0 + (e >> 5), k = e & 31;
        int j = eidx[row*KK + k];
        const float* xr = Xb + j*12;
        float nx=xr[0], ny=xr[1], nz=xr[2];
        float ax=xr[3], ay=xr[4], az=xr[5];
        float cx=xr[6], cy=xr[7], cz=xr[8];
        float bx=ax-nx, by=ay-ny, bz=az-nz;
        float vx=cx-ax, vy=cy-ay, vz=cz-az;
        float qx = by*vz - bz*vy, qy = bz*vx - bx*vz, qz = bx*vy - by*vx;
        aj[e][0]=nx; aj[e][1]=ny; aj[e][2]=nz;
        aj[e][3]=ax; aj[e][4]=ay; aj[e][5]=az;
        aj[e][6]=cx; aj[e][7]=cy; aj[e][8]=cz;
        aj[e][9]=xr[9]; aj[e][10]=xr[10]; aj[e][11]=xr[11];
        aj[e][12] = -0.58273431f*qx + 0.56802827f*bx - 0.54067466f*vx + ax;
        aj[e][13] = -0.58273431f*qy + 0.56802827f*by - 0.54067466f*vy + ay;
        aj[e][14] = -0.58273431f*qz + 0.56802827f*bz - 0.54067466f*vz + az;
        int off = Ridx[row] - Ridx[b*LLEN + j];
        int ec = (chain[row] == chain[b*LLEN + j]) ? 1 : 0;
        int dc = off + 32; dc = dc < 0 ? 0 : (dc > 64 ? 64 : dc);
        didx[e] = ec ? dc : 65;
    }
    if (tid >= 64 && tid < 66) {
        int rl = tid - 64;
        int i = (r0 + rl) & 1023;
        const float* xr = Xb + i*12;
        float nx=xr[0], ny=xr[1], nz=xr[2];
        float ax=xr[3], ay=xr[4], az=xr[5];
        float cx=xr[6], cy=xr[7], cz=xr[8];
        float bx=ax-nx, by=ay-ny, bz=az-nz;
        float vx=cx-ax, vy=cy-ay, vz=cz-az;
        float qx = by*vz - bz*vy, qy = bz*vx - bx*vz, qz = bx*vy - by*vx;
        ai[rl][0]=nx; ai[rl][1]=ny; ai[rl][2]=nz;
        ai[rl][3]=ax; ai[rl][4]=ay; ai[rl][5]=az;
        ai[rl][6]=cx; ai[rl][7]=cy; ai[rl][8]=cz;
        ai[rl][9]=xr[9]; ai[rl][10]=xr[10]; ai[rl][11]=xr[11];
        ai[rl][12] = -0.58273431f*qx + 0.56802827f*bx - 0.54067466f*vx + ax;
        ai[rl][13] = -0.58273431f*qy + 0.56802827f*by - 0.54067466f*vy + ay;
        ai[rl][14] = -0.58273431f*qz + 0.56802827f*bz - 0.54067466f*vz + az;
    }
    __syncthreads();

    for (int item = tid; item < 64 * 26; item += 256) {
        int e = item / 26, it = item - e * 26;
        int rl = e >> 5;
        union { short8_t v[2]; __hip_bfloat16 h[16]; } uf;
        if (it == 0) {
            int d = didx[e];
            #pragma unroll
            for (int c = 0; c < 16; ++c) uf.h[c] = __float2bfloat16(posW[d*16 + c] + posb[c]);
        } else {
            float dist;
            if (it == 1) {
                dist = dnb[(r0 + rl)*KK + (e & 31)];
            } else {
                int p = it - 2;
                int a = g_PA[p], q = g_PB[p];
                float dx = ai[rl][a*3+0] - aj[e][q*3+0];
                float dy = ai[rl][a*3+1] - aj[e][q*3+1];
                float dz = ai[rl][a*3+2] - aj[e][q*3+2];
                dist = sqrtf(dx*dx + dy*dy + dz*dz + 1e-6f);
            }
            #pragma unroll
            for (int r = 0; r < 16; ++r) uf.h[r] = __float2bfloat16(rbf_val(dist, r));
        }
        short8_t* dst = (short8_t*)(A + e * KP + it * 16);
        dst[0] = uf.v[0];
        dst[1] = uf.v[1];
    }
    __syncthreads();

    int wid = tid >> 6, lane = tid & 63;
    int col16 = lane & 15, kg = lane >> 4;
    f32x4 acc[8];
    #pragma unroll
    for (int t = 0; t < 8; ++t) acc[t] = (f32x4){0.f, 0.f, 0.f, 0.f};
    const __hip_bfloat16* Ar = A + (wid*16 + col16) * KP + kg * 8;
    const short8_t* Bp = (const short8_t*)Bpack;
    for (int ks = 0; ks < 13; ++ks) {
        short8_t a = *(const short8_t*)(Ar + ks*32);
        #pragma unroll
        for (int t = 0; t < 8; ++t) {
            short8_t bf = Bp[(ks*8 + t)*64 + lane];
            acc[t] = __builtin_amdgcn_mfma_f32_16x16x32_bf16(a, bf, acc[t], 0, 0, 0);
        }
    }
    __syncthreads();   // all waves done reading A; safe to reuse as stage

    float* sbuf = (float*)A + wid * (16*132);
    float g[8], be[8];
    #pragma unroll
    for (int t = 0; t < 8; ++t) { g[t] = lnEg[t*16 + col16]; be[t] = lnEb[t*16 + col16]; }
    #pragma unroll
    for (int r = 0; r < 4; ++r) {
        float s = 0.0f;
        #pragma unroll
        for (int t = 0; t < 8; ++t) s += acc[t][r];
        s += __shfl_xor(s, 1); s += __shfl_xor(s, 2);
        s += __shfl_xor(s, 4); s += __shfl_xor(s, 8);
        float mean = s * (1.0f/128.0f);
        float q2 = 0.0f;
        #pragma unroll
        for (int t = 0; t < 8; ++t) { float c0 = acc[t][r] - mean; q2 += c0*c0; }
        q2 += __shfl_xor(q2, 1); q2 += __shfl_xor(q2, 2);
        q2 += __shfl_xor(q2, 4); q2 += __shfl_xor(q2, 8);
        float inv = rsqrtf(q2 * (1.0f/128.0f) + 1e-5f);
        float* sr = sbuf + (kg*4 + r) * 132;
        #pragma unroll
        for (int t = 0; t < 8; ++t) sr[t*16 + col16] = (acc[t][r] - mean)*inv*g[t] + be[t];
    }
    float* gdst = outE + ((size_t)r0 * KK + wid*16) * 128;
    #pragma unroll
    for (int it = 0; it < 8; ++it) {
        int off = it*256 + lane*4;
        int rr = off >> 7, cc = off & 127;
        float4 v = *(const float4*)(sbuf + rr*132 + cc);
        *(float4*)(gdst + off) = v;
    }
}

// ---------------------------------------------------------------- node (V) kernel (MFMA)
__global__ __launch_bounds__(256) void k_nodes(
    const float* __restrict__ X, const float* __restrict__ Y,
    const int* __restrict__ Yt,
    const float* __restrict__ typeW, const float* __restrict__ typeb,
    const int* __restrict__ ptab,
    const __hip_bfloat16* __restrict__ Bpack3, const float* __restrict__ npdb,
    const float* __restrict__ lnNg, const float* __restrict__ lnNb,
    float* __restrict__ outV)
{
    __shared__ __align__(16) __hip_bfloat16 A[128 * KP2];   // 42 KB
    __shared__ float sat[NR][15];
    __shared__ float sfr[NR][9];
    int r0 = blockIdx.x * NR;
    int nrows = (2048 - r0) < NR ? (2048 - r0) : NR;
    int natoms = nrows * MM;
    int tid = threadIdx.x;

    if (tid < nrows) {
        int row = r0 + tid;
        int b = row >> 10, i = row & 1023;
        const float* xr = X + ((size_t)b * LLEN + i) * 12;
        float nx=xr[0], ny=xr[1], nz=xr[2];
        float ax=xr[3], ay=xr[4], az=xr[5];
        float cx=xr[6], cy=xr[7], cz=xr[8];
        float bx=ax-nx, by=ay-ny, bz=az-nz;
        float vx=cx-ax, vy=cy-ay, vz=cz-az;
        float qx = by*vz - bz*vy, qy = bz*vx - bx*vz, qz = bx*vy - by*vx;
        sat[tid][0]=nx; sat[tid][1]=ny; sat[tid][2]=nz;
        sat[tid][3]=ax; sat[tid][4]=ay; sat[tid][5]=az;
        sat[tid][6]=cx; sat[tid][7]=cy; sat[tid][8]=cz;
        sat[tid][9]=xr[9]; sat[tid][10]=xr[10]; sat[tid][11]=xr[11];
        sat[tid][12] = -0.58273431f*qx + 0.56802827f*bx - 0.54067466f*vx + ax;
        sat[tid][13] = -0.58273431f*qy + 0.56802827f*by - 0.54067466f*vy + ay;
        sat[tid][14] = -0.58273431f*qz + 0.56802827f*bz - 0.54067466f*vz + az;
        float e1x = nx-ax, e1y = ny-ay, e1z = nz-az;
        float n1 = fmaxf(sqrtf(e1x*e1x+e1y*e1y+e1z*e1z), 1e-12f);
        e1x/=n1; e1y/=n1; e1z/=n1;
        float dd = e1x*vx + e1y*vy + e1z*vz;
        float u2x = vx - e1x*dd, u2y = vy - e1y*dd, u2z = vz - e1z*dd;
        float n2 = fmaxf(sqrtf(u2x*u2x+u2y*u2y+u2z*u2z), 1e-12f);
        u2x/=n2; u2y/=n2; u2z/=n2;
        sfr[tid][0]=e1x; sfr[tid][1]=e1y; sfr[tid][2]=e1z;
        sfr[tid][3]=u2x; sfr[tid][4]=u2y; sfr[tid][5]=u2z;
        sfr[tid][6]=e1y*u2z - e1z*u2y;
        sfr[tid][7]=e1z*u2x - e1x*u2z;
        sfr[tid][8]=e1x*u2y - e1y*u2x;
    }
    __syncthreads();

    for (int item = tid; item < natoms * 10; item += 256) {
        int a = item / 10, it = item - a * 10;
        int rl = a / MM, m = a - rl * MM;
        int row = r0 + rl;
        const float* Yb = Y + (size_t)row * MM * 3 + m * 3;
        union { short8_t v[2]; __hip_bfloat16 h[16]; } uf;
        if (it < 5) {
            float dx = sat[rl][it*3+0] - Yb[0];
            float dy = sat[rl][it*3+1] - Yb[1];
            float dz = sat[rl][it*3+2] - Yb[2];
            float dist = sqrtf(dx*dx + dy*dy + dz*dz + 1e-6f);
            #pragma unroll
            for (int r = 0; r < 16; ++r) uf.h[r] = __float2bfloat16(rbf_val(dist, r));
        } else if (it < 9) {
            int qq = it - 5;
            int t = Yt[row*MM + m];
            int p1 = ptab[120 + t], p2 = ptab[240 + t];
            #pragma unroll
            for (int c = 0; c < 16; ++c) {
                int cc = qq*16 + c;
                uf.h[c] = __float2bfloat16(typeW[t*64 + cc] + typeW[(120+p1)*64 + cc]
                        + typeW[(139+p2)*64 + cc] + typeb[cc]);
            }
        } else {
            float vx = Yb[0] - sat[rl][3];
            float vy = Yb[1] - sat[rl][4];
            float vz = Yb[2] - sat[rl][5];
            float l0 = sfr[rl][0]*vx + sfr[rl][1]*vy + sfr[rl][2]*vz;
            float l1 = sfr[rl][3]*vx + sfr[rl][4]*vy + sfr[rl][5]*vz;
            float l2 = sfr[rl][6]*vx + sfr[rl][7]*vy + sfr[rl][8]*vz;
            float rxy  = sqrtf(l0*l0 + l1*l1 + 1e-8f);
            float rxyz = sqrtf(l0*l0 + l1*l1 + l2*l2) + 1e-8f;
            uf.h[0] = __float2bfloat16(l0 / rxy);
            uf.h[1] = __float2bfloat16(l1 / rxy);
            uf.h[2] = __float2bfloat16(rxy / rxyz);
            uf.h[3] = __float2bfloat16(l2 / rxyz);
            #pragma unroll
            for (int c = 4; c < 16; ++c) uf.h[c] = __float2bfloat16(0.0f);
        }
        short8_t* dst = (short8_t*)(A + a * KP2 + it * 16);
        dst[0] = uf.v[0];
        dst[1] = uf.v[1];
    }
    __syncthreads();

    int wid = tid >> 6, lane = tid & 63;
    int col16 = lane & 15, kg = lane >> 4;
    const short8_t* Bp = (const short8_t*)Bpack3;
    float g[8], be[8], bias[8];
    #pragma unroll
    for (int t = 0; t < 8; ++t) {
        g[t] = lnNg[t*16 + col16]; be[t] = lnNb[t*16 + col16];
        bias[t] = npdb[t*16 + col16];
    }
    #pragma unroll
    for (int half = 0; half < 2; ++half) {
        int tile = wid + half*4;
        int abase = tile * 16;
        if (abase < natoms) {
            const __hip_bfloat16* Ar = A + (abase + col16) * KP2 + kg * 8;
            f32x4 acc[8];
            #pragma unroll
            for (int t = 0; t < 8; ++t) acc[t] = (f32x4){0.f, 0.f, 0.f, 0.f};
            for (int ks = 0; ks < 5; ++ks) {
                short8_t a = *(const short8_t*)(Ar + ks*32);
                #pragma unroll
                for (int t = 0; t < 8; ++t) {
                    short8_t bf = Bp[(ks*8 + t)*64 + lane];
                    acc[t] = __builtin_amdgcn_mfma_f32_16x16x32_bf16(a, bf, acc[t], 0, 0, 0);
                }
            }
            #pragma unroll
            for (int r = 0; r < 4; ++r) {
                float s = 0.0f;
                #pragma unroll
                for (int t = 0; t < 8; ++t) { acc[t][r] += bias[t]; s += acc[t][r]; }
                s += __shfl_xor(s, 1); s += __shfl_xor(s, 2);
                s += __shfl_xor(s, 4); s += __shfl_xor(s, 8);
                float mean = s * (1.0f/128.0f);
                float q2 = 0.0f;
                #pragma unroll
                for (int t = 0; t < 8; ++t) { float c0 = acc[t][r] - mean; q2 += c0*c0; }
                q2 += __shfl_xor(q2, 1); q2 += __shfl_xor(q2, 2);
                q2 += __shfl_xor(q2, 4); q2 += __shfl_xor(q2, 8);
                float inv = rsqrtf(q2 * (1.0f/128.0f) + 1e-5f);
                int aa = abase + kg*4 + r;
                if (aa < natoms) {
                    float* dst = outV + ((size_t)r0 * MM + aa) * 128 + col16;
                    #pragma unroll
                    for (int t = 0; t < 8; ++t) dst[t*16] = (acc[t][r] - mean)*inv*g[t] + be[t];
                }
            }
        }
    }
}

// ---------------------------------------------------------------- merged Y_edges + Y_nodes
// vbid < 2048: Y_edges MFMA block (validated R8 body)
// vbid >= 2048: Y_nodes 4-rows-per-block (validated body)
__global__ __launch_bounds__(256) void k_ymerge(
    int block_base,
    const float* __restrict__ Y,
    const __hip_bfloat16* __restrict__ Bpack2,
    const float* __restrict__ lnYEg, const float* __restrict__ lnYEb,
    float* __restrict__ outYE,
    const int* __restrict__ Yt, const float* __restrict__ Ym,
    const int* __restrict__ ptab, const float* __restrict__ ynW,
    const float* __restrict__ lnYNg, const float* __restrict__ lnYNb,
    float* __restrict__ outYN, float* __restrict__ outYM)
{
    __shared__ __align__(16) float sy4[32][4];
    __shared__ __align__(16) float stage[4][16*132];
    int vbid = blockIdx.x + block_base;
    int tid = threadIdx.x;
    int wv = tid >> 6, lane = tid & 63;

    if (vbid >= BB*LLEN) {                 // ---- Y_nodes branch
        int row = (vbid - BB*LLEN) * 4 + wv;
        int t = Yt[row];
        int p1 = ptab[120 + t], p2 = ptab[240 + t];
        int r0 = t, r1 = 120 + p1, r2 = 139 + p2;
        float x0 = ynW[r0*128 + lane] + ynW[r1*128 + lane] + ynW[r2*128 + lane];
        float x1 = ynW[r0*128 + 64 + lane] + ynW[r1*128 + 64 + lane] + ynW[r2*128 + 64 + lane];
        float s = x0 + x1, s2 = x0*x0 + x1*x1;
        #pragma unroll
        for (int o = 1; o < 64; o <<= 1) { s += __shfl_xor(s, o); s2 += __shfl_xor(s2, o); }
        float mean = s * (1.0f/128.0f);
        float var  = s2 * (1.0f/128.0f) - mean*mean;
        float inv  = rsqrtf(var + 1e-5f);
        size_t base = (size_t)row * 128;
        outYN[base + lane]      = (x0 - mean)*inv*lnYNg[lane]    + lnYNb[lane];
        outYN[base + 64 + lane] = (x1 - mean)*inv*lnYNg[64+lane] + lnYNb[64+lane];
        if (lane == 0) outYM[row] = Ym[row];
        return;
    }

    // ---- Y_edges branch
    int row = vbid;
    int col16 = lane & 15, kg = lane >> 4;

    if (tid < 32) { sy4[tid][0]=0.f; sy4[tid][1]=0.f; sy4[tid][2]=0.f; sy4[tid][3]=0.f; }
    __syncthreads();
    if (tid < MM*3) ((float*)sy4)[ (tid/3)*4 + (tid%3) ] = Y[(size_t)row * MM * 3 + tid];

    short8_t bfr[8];
    const short8_t* B2 = (const short8_t*)Bpack2;
    #pragma unroll
    for (int t = 0; t < 8; ++t) bfr[t] = B2[t*64 + lane];
    float g[8], be[8];
    #pragma unroll
    for (int t = 0; t < 8; ++t) { g[t] = lnYEg[t*16 + col16]; be[t] = lnYEb[t*16 + col16]; }
    __syncthreads();

    float* outR = outYE + (size_t)row * 625 * 128;
    float* sbuf = stage[wv];
    for (int T = wv; T < 40; T += 4) {
        int p0 = T * 16;
        int p  = p0 + col16;
        int pc = p < 624 ? p : 624;
        int m1 = pc / 25, m2 = pc - 25*m1;
        float dx = sy4[m1][0] - sy4[m2][0];
        float dy = sy4[m1][1] - sy4[m2][1];
        float dz = sy4[m1][2] - sy4[m2][2];
        float d = sqrtf(dx*dx + dy*dy + dz*dz + 1e-6f);
        union { short8_t v; __hip_bfloat16 h[8]; } ua;
        if (kg < 2) {
            #pragma unroll
            for (int j = 0; j < 8; ++j) ua.h[j] = __float2bfloat16(rbf_val(d, kg*8 + j));
        } else {
            ua.v = (short8_t){0,0,0,0,0,0,0,0};
        }
        f32x4 acc[8];
        #pragma unroll
        for (int t = 0; t < 8; ++t)
            acc[t] = __builtin_amdgcn_mfma_f32_16x16x32_bf16(ua.v, bfr[t],
                         (f32x4){0.f,0.f,0.f,0.f}, 0, 0, 0);
        #pragma unroll
        for (int r = 0; r < 4; ++r) {
            float s = 0.0f;
            #pragma unroll
            for (int t = 0; t < 8; ++t) s += acc[t][r];
            s += __shfl_xor(s, 1); s += __shfl_xor(s, 2);
            s += __shfl_xor(s, 4); s += __shfl_xor(s, 8);
            float mean = s * (1.0f/128.0f);
            float q2 = 0.0f;
            #pragma unroll
            for (int t = 0; t < 8; ++t) { float c0 = acc[t][r] - mean; q2 += c0*c0; }
            q2 += __shfl_xor(q2, 1); q2 += __shfl_xor(q2, 2);
            q2 += __shfl_xor(q2, 4); q2 += __shfl_xor(q2, 8);
            float inv = rsqrtf(q2 * (1.0f/128.0f) + 1e-5f);
            float* sr = sbuf + (kg*4 + r) * 132;
            #pragma unroll
            for (int t = 0; t < 8; ++t) sr[t*16 + col16] = (acc[t][r] - mean)*inv*g[t] + be[t];
        }
        #pragma unroll
        for (int it = 0; it < 8; ++it) {
            int off = it*256 + lane*4;
            int rr = (off >> 7), cc = off & 127;
            float4 v = *(const float4*)(sbuf + rr*132 + cc);
            int gbase = p0*128 + off;
            if (gbase < 80000) *(float4*)(outR + gbase) = v;   // 625*128
        }
    }
}

// ---------------------------------------------------------------- launcher
extern "C" void kernel_launch(void* const* d_in, const int* in_sizes, int n_in,
                              void* d_out, int out_size, void* d_ws, size_t ws_size,
                              hipStream_t stream) {
    const float* X     = (const float*)d_in[0];
    const float* Y     = (const float*)d_in[1];
    const float* Ym    = (const float*)d_in[2];
    const int*   Yt    = (const int*)d_in[3];
    const float* mask  = (const float*)d_in[4];
    const int*   Ridx  = (const int*)d_in[5];
    const int*   chain = (const int*)d_in[6];
    const float* posW  = (const float*)d_in[7];
    const float* posb  = (const float*)d_in[8];
    const float* edgeW = (const float*)d_in[9];
    const float* lnEg  = (const float*)d_in[10];
    const float* lnEb  = (const float*)d_in[11];
    const float* npdW  = (const float*)d_in[12];
    const float* npdb  = (const float*)d_in[13];
    const float* lnNg  = (const float*)d_in[14];
    const float* lnNb  = (const float*)d_in[15];
    const float* typeW = (const float*)d_in[16];
    const float* typeb = (const float*)d_in[17];
    const float* ynW   = (const float*)d_in[18];
    const float* yeW   = (const float*)d_in[19];
    const float* lnYEg = (const float*)d_in[20];
    const float* lnYEb = (const float*)d_in[21];
    const float* lnYNg = (const float*)d_in[22];
    const float* lnYNb = (const float*)d_in[23];
    const int*   ptab  = (const int*)d_in[24];

    float* o = (float*)d_out;
    // Scratch: prefer d_ws (disjoint from all outputs -> allows ynodes/yedges
    // merge). Fallback: head of the Y_nodes output region (then ynodes must
    // run LAST, separately, as in the validated R9 schedule).
    bool ws_ok = (ws_size >= (size_t)SCRATCH_BYTES);
    char* scratch = ws_ok ? (char*)d_ws : (char*)(o + OFF_YN);
    int*   eidx = (int*)scratch;                                   // 256 KB
    float* dnb  = (float*)(scratch + BB*LLEN*KK*4);                // 256 KB
    __hip_bfloat16* Bpack  = (__hip_bfloat16*)(scratch + 2*BB*LLEN*KK*4); // 104 KB
    __hip_bfloat16* Bpack2 = Bpack + 6656*8;                       // 8 KB
    __hip_bfloat16* Bpack3 = Bpack2 + 512*8;                       // 40 KB

    k_pretopk<<<550, 256, 0, stream>>>(X, mask, edgeW, yeW, npdW,
                                       Bpack, Bpack2, Bpack3,
                                       eidx, dnb, o + OFF_EI);
    k_edges <<<BB*LLEN/2, 256, 0, stream>>>(X, Ridx, chain, posW, posb, Bpack,
                                            lnEg, lnEb, eidx, dnb, o + OFF_E);
    k_nodes <<<(BB*LLEN + NR - 1)/NR, 256, 0, stream>>>(X, Y, Yt, typeW, typeb, ptab,
                                          Bpack3, npdb, lnNg, lnNb, o + OFF_V);
    if (ws_ok) {
        // unified: yedges blocks [0,2048) + ynodes blocks [2048,14848)
        k_ymerge<<<BB*LLEN + BB*LLEN*MM/4, 256, 0, stream>>>(0,
            Y, Bpack2, lnYEg, lnYEb, o + OFF_YE,
            Yt, Ym, ptab, ynW, lnYNg, lnYNb, o + OFF_YN, o + OFF_YM);
    } else {
        k_ymerge<<<BB*LLEN, 256, 0, stream>>>(0,
            Y, Bpack2, lnYEg, lnYEb, o + OFF_YE,
            Yt, Ym, ptab, ynW, lnYNg, lnYNb, o + OFF_YN, o + OFF_YM);
        k_ymerge<<<BB*LLEN*MM/4, 256, 0, stream>>>(BB*LLEN,
            Y, Bpack2, lnYEg, lnYEb, o + OFF_YE,
            Yt, Ym, ptab, ynW, lnYNg, lnYNb, o + OFF_YN, o + OFF_YM);
    }
}

// Round 11
// 239.759 us; speedup vs baseline: 6.2565x; 1.0085x over previous
//
#include <hip/hip_runtime.h>
#include <hip/hip_bf16.h>
#include <stdint.h>

#define BB 2
#define LLEN 1024
#define MM 25
#define KK 32

// d_out is FLOAT32, concatenated in return order:
// (V, E, E_idx, Y_nodes, Y_edges, Y_m) — offsets in f32 elements.
#define OFF_V   0
#define OFF_E   6553600
#define OFF_EI  14942208
#define OFF_YN  15007744
#define OFF_YE  21561344
#define OFF_YM  185401344

#define KP 424          // edge A-tile row stride (bf16)
#define KP2 168         // node A-tile row stride (bf16)
#define NR 5            // rows per nodes block

#define NB_YE  (BB*LLEN)            // 2048
#define NB_E   (BB*LLEN/2)          // 1024
#define NB_N   ((BB*LLEN+NR-1)/NR)  // 410
#define NB_YN  (BB*LLEN*MM/4)       // 12800
#define VB_E   NB_YE                // 2048
#define VB_N   (VB_E + NB_E)        // 3072
#define VB_YN  (VB_N + NB_N)        // 3482
#define VB_END (VB_YN + NB_YN)      // 16282

#define SCRATCH_BYTES (680*1024)

typedef __attribute__((ext_vector_type(8))) short short8_t;
typedef __attribute__((ext_vector_type(4))) float f32x4;

__constant__ int g_PA[24] = {0,2,3,4,1,1,1,1,0,0,0,4,4,3,0,2,3,4,2,3,4,2,3,2};
__constant__ int g_PB[24] = {0,2,3,4,0,2,3,4,2,3,4,2,3,2,1,1,1,1,0,0,0,4,4,3};

__device__ __forceinline__ float rbf_val(float d, int r) {
    float mu = 2.0f + (20.0f / 15.0f) * (float)r;
    float z = (d - mu) * 0.8f;
    return __expf(-z * z);
}

// ------------------------------------------------- merged prep + topk (validated R10)
__global__ __launch_bounds__(256) void k_pretopk(
    const float* __restrict__ X, const float* __restrict__ mask,
    const float* __restrict__ W, const float* __restrict__ yeW,
    const float* __restrict__ npdW,
    __hip_bfloat16* __restrict__ Bp, __hip_bfloat16* __restrict__ Bp2,
    __hip_bfloat16* __restrict__ Bp3,
    int* __restrict__ eidx, float* __restrict__ dnb,
    float* __restrict__ outEI)
{
    __shared__ float sx[1024], syy[1024], sz[1024], sm[1024];
    int tid = threadIdx.x;

    if (blockIdx.x >= 512) {              // ---- prep branch
        int idx = (blockIdx.x - 512) * 256 + tid;
        if (idx < 6656) {
            int lane = idx & 63, tt = (idx >> 6) & 7, ks = idx >> 9;
            int k0 = ks*32 + (lane >> 4)*8;
            int n  = tt*16 + (lane & 15);
            __hip_bfloat16* dst = Bp + (size_t)idx * 8;
            #pragma unroll
            for (int j = 0; j < 8; ++j) dst[j] = __float2bfloat16(W[(size_t)(k0 + j)*128 + n]);
        } else if (idx < 7168) {
            int i2 = idx - 6656;
            int lane = i2 & 63, tt = i2 >> 6;
            int kg = lane >> 4;
            int n  = tt*16 + (lane & 15);
            __hip_bfloat16* dst = Bp2 + (size_t)i2 * 8;
            #pragma unroll
            for (int j = 0; j < 8; ++j) {
                float v = (kg < 2) ? yeW[(size_t)(kg*8 + j)*128 + n] : 0.0f;
                dst[j] = __float2bfloat16(v);
            }
        } else if (idx < 9728) {
            int i3 = idx - 7168;
            int lane = i3 & 63, tt = (i3 >> 6) & 7, ks = i3 >> 9;
            int k0 = ks*32 + (lane >> 4)*8;
            int n  = tt*16 + (lane & 15);
            __hip_bfloat16* dst = Bp3 + (size_t)i3 * 8;
            #pragma unroll
            for (int j = 0; j < 8; ++j) {
                int k = k0 + j;
                float v = (k < 148) ? npdW[(size_t)k*128 + n] : 0.0f;
                dst[j] = __float2bfloat16(v);
            }
        }
        return;
    }

    int wid = tid >> 6, lane = tid & 63;
    int row0 = blockIdx.x * 4;
    int b = row0 >> 10;
    const float* Xb = X + (size_t)b * LLEN * 12;
    const float* mb = mask + b * LLEN;
    for (int j = tid; j < 1024; j += 256) {
        sx[j]  = Xb[j*12+3];
        syy[j] = Xb[j*12+4];
        sz[j]  = Xb[j*12+5];
        sm[j]  = mb[j];
    }
    __syncthreads();

    int row = row0 + wid, i = row & 1023;
    float cax = sx[i], cay = syy[i], caz = sz[i];
    float mi = sm[i];

    float df[16], mm_[16];
    float lmax = 0.0f;
    #pragma unroll
    for (int q = 0; q < 16; ++q) {
        int j = q*64 + lane;
        float dx = cax - sx[j];
        float dy = cay - syy[j];
        float dz = caz - sz[j];
        float m2 = mi * sm[j];
        float d = sqrtf(dx*dx + dy*dy + dz*dz + 1e-6f) * m2;
        df[q] = d; mm_[q] = m2;
        lmax = fmaxf(lmax, d);
    }
    #pragma unroll
    for (int o = 32; o > 0; o >>= 1) lmax = fmaxf(lmax, __shfl_xor(lmax, o));

    unsigned long long pack[16];
    #pragma unroll
    for (int q = 0; q < 16; ++q) {
        float da = df[q] + (1.0f - mm_[q]) * lmax;
        pack[q] = ((unsigned long long)__float_as_uint(da) << 32) | (unsigned)(q*64 + lane);
    }

    int   myJw = 0;
    float myDv = 0.0f;
    for (int it = 0; it < KK; ++it) {
        unsigned long long lmin = pack[0];
        #pragma unroll
        for (int q = 1; q < 16; ++q) if (pack[q] < lmin) lmin = pack[q];
        #pragma unroll
        for (int o = 32; o > 0; o >>= 1) {
            unsigned long long other = __shfl_xor(lmin, o);
            if (other < lmin) lmin = other;
        }
        int jw = (int)(lmin & 0xffffffffu);
        if (lane == it) { myJw = jw; myDv = __uint_as_float((unsigned)(lmin >> 32)); }
        int lw = jw & 63, qw = jw >> 6;
        #pragma unroll
        for (int q = 0; q < 16; ++q)
            if (lane == lw && q == qw) pack[q] = ~0ull;
    }
    if (lane < KK) {
        eidx[row*KK + lane]  = myJw;
        dnb [row*KK + lane]  = myDv;
        outEI[row*KK + lane] = (float)myJw;
    }
}

// ---------------------------------------------------------------- unified main kernel
// vb in [0,2048): Y_edges | [2048,3072): E | [3072,3482): V | [3482,16282): Y_nodes
// All branches are the validated R10 bodies; LDS shared via union.
union SMem {
    struct { __hip_bfloat16 A[64*KP]; float aj[64][16]; float ai[2][16]; int didx[64]; } e;
    struct { __hip_bfloat16 A[128*KP2]; float sat[NR][15]; float sfr[NR][9]; } n;
    struct { float sy4[32][4]; float stage[4][16*132]; } y;
};

__global__ __launch_bounds__(256) void k_main(
    int vbase,
    const float* __restrict__ X, const float* __restrict__ Y,
    const int* __restrict__ Ridx, const int* __restrict__ chain,
    const float* __restrict__ posW, const float* __restrict__ posb,
    const __hip_bfloat16* __restrict__ Bpack,
    const float* __restrict__ lnEg, const float* __restrict__ lnEb,
    const int* __restrict__ eidx, const float* __restrict__ dnb,
    const int* __restrict__ Yt,
    const float* __restrict__ typeW, const float* __restrict__ typeb,
    const int* __restrict__ ptab,
    const __hip_bfloat16* __restrict__ Bpack3, const float* __restrict__ npdb,
    const float* __restrict__ lnNg, const float* __restrict__ lnNb,
    const __hip_bfloat16* __restrict__ Bpack2,
    const float* __restrict__ lnYEg, const float* __restrict__ lnYEb,
    const float* __restrict__ Ym, const float* __restrict__ ynW,
    const float* __restrict__ lnYNg, const float* __restrict__ lnYNb,
    float* __restrict__ outV, float* __restrict__ outE,
    float* __restrict__ outYN, float* __restrict__ outYE,
    float* __restrict__ outYM)
{
    __shared__ __align__(16) SMem sm;
    int vb = blockIdx.x + vbase;
    int tid = threadIdx.x;
    int wv = tid >> 6, lane = tid & 63;
    int col16 = lane & 15, kg = lane >> 4;

    if (vb >= VB_YN) {                     // ==== Y_nodes ====
        int row = (vb - VB_YN) * 4 + wv;
        int t = Yt[row];
        int p1 = ptab[120 + t], p2 = ptab[240 + t];
        int r0 = t, r1 = 120 + p1, r2 = 139 + p2;
        float x0 = ynW[r0*128 + lane] + ynW[r1*128 + lane] + ynW[r2*128 + lane];
        float x1 = ynW[r0*128 + 64 + lane] + ynW[r1*128 + 64 + lane] + ynW[r2*128 + 64 + lane];
        float s = x0 + x1, s2 = x0*x0 + x1*x1;
        #pragma unroll
        for (int o = 1; o < 64; o <<= 1) { s += __shfl_xor(s, o); s2 += __shfl_xor(s2, o); }
        float mean = s * (1.0f/128.0f);
        float var  = s2 * (1.0f/128.0f) - mean*mean;
        float inv  = rsqrtf(var + 1e-5f);
        size_t base = (size_t)row * 128;
        outYN[base + lane]      = (x0 - mean)*inv*lnYNg[lane]    + lnYNb[lane];
        outYN[base + 64 + lane] = (x1 - mean)*inv*lnYNg[64+lane] + lnYNb[64+lane];
        if (lane == 0) outYM[row] = Ym[row];
        return;
    }

    if (vb < NB_YE) {                      // ==== Y_edges ====
        int row = vb;
        if (tid < 32) { sm.y.sy4[tid][0]=0.f; sm.y.sy4[tid][1]=0.f; sm.y.sy4[tid][2]=0.f; sm.y.sy4[tid][3]=0.f; }
        __syncthreads();
        if (tid < MM*3) ((float*)sm.y.sy4)[ (tid/3)*4 + (tid%3) ] = Y[(size_t)row * MM * 3 + tid];

        short8_t bfr[8];
        const short8_t* B2 = (const short8_t*)Bpack2;
        #pragma unroll
        for (int t = 0; t < 8; ++t) bfr[t] = B2[t*64 + lane];
        float g[8], be[8];
        #pragma unroll
        for (int t = 0; t < 8; ++t) { g[t] = lnYEg[t*16 + col16]; be[t] = lnYEb[t*16 + col16]; }
        __syncthreads();

        float* outR = outYE + (size_t)row * 625 * 128;
        float* sbuf = sm.y.stage[wv];
        for (int T = wv; T < 40; T += 4) {
            int p0 = T * 16;
            int p  = p0 + col16;
            int pc = p < 624 ? p : 624;
            int m1 = pc / 25, m2 = pc - 25*m1;
            float dx = sm.y.sy4[m1][0] - sm.y.sy4[m2][0];
            float dy = sm.y.sy4[m1][1] - sm.y.sy4[m2][1];
            float dz = sm.y.sy4[m1][2] - sm.y.sy4[m2][2];
            float d = sqrtf(dx*dx + dy*dy + dz*dz + 1e-6f);
            union { short8_t v; __hip_bfloat16 h[8]; } ua;
            if (kg < 2) {
                #pragma unroll
                for (int j = 0; j < 8; ++j) ua.h[j] = __float2bfloat16(rbf_val(d, kg*8 + j));
            } else {
                ua.v = (short8_t){0,0,0,0,0,0,0,0};
            }
            f32x4 acc[8];
            #pragma unroll
            for (int t = 0; t < 8; ++t)
                acc[t] = __builtin_amdgcn_mfma_f32_16x16x32_bf16(ua.v, bfr[t],
                             (f32x4){0.f,0.f,0.f,0.f}, 0, 0, 0);
            #pragma unroll
            for (int r = 0; r < 4; ++r) {
                float s = 0.0f;
                #pragma unroll
                for (int t = 0; t < 8; ++t) s += acc[t][r];
                s += __shfl_xor(s, 1); s += __shfl_xor(s, 2);
                s += __shfl_xor(s, 4); s += __shfl_xor(s, 8);
                float mean = s * (1.0f/128.0f);
                float q2 = 0.0f;
                #pragma unroll
                for (int t = 0; t < 8; ++t) { float c0 = acc[t][r] - mean; q2 += c0*c0; }
                q2 += __shfl_xor(q2, 1); q2 += __shfl_xor(q2, 2);
                q2 += __shfl_xor(q2, 4); q2 += __shfl_xor(q2, 8);
                float inv = rsqrtf(q2 * (1.0f/128.0f) + 1e-5f);
                float* sr = sbuf + (kg*4 + r) * 132;
                #pragma unroll
                for (int t = 0; t < 8; ++t) sr[t*16 + col16] = (acc[t][r] - mean)*inv*g[t] + be[t];
            }
            #pragma unroll
            for (int it = 0; it < 8; ++it) {
                int off = it*256 + lane*4;
                int rr = (off >> 7), cc = off & 127;
                float4 v = *(const float4*)(sbuf + rr*132 + cc);
                int gbase = p0*128 + off;
                if (gbase < 80000) *(float4*)(outR + gbase) = v;
            }
        }
        return;
    }

    if (vb < VB_N) {                       // ==== E (edges) ====
        int r0 = (vb - VB_E) * 2;
        int b  = r0 >> 10;
        const float* Xb = X + (size_t)b * LLEN * 12;

        if (tid < 64) {
            int e = tid, row = r0 + (e >> 5), k = e & 31;
            int j = eidx[row*KK + k];
            const float* xr = Xb + j*12;
            float nx=xr[0], ny=xr[1], nz=xr[2];
            float ax=xr[3], ay=xr[4], az=xr[5];
            float cx=xr[6], cy=xr[7], cz=xr[8];
            float bx=ax-nx, by=ay-ny, bz=az-nz;
            float vx=cx-ax, vy=cy-ay, vz=cz-az;
            float qx = by*vz - bz*vy, qy = bz*vx - bx*vz, qz = bx*vy - by*vx;
            sm.e.aj[e][0]=nx; sm.e.aj[e][1]=ny; sm.e.aj[e][2]=nz;
            sm.e.aj[e][3]=ax; sm.e.aj[e][4]=ay; sm.e.aj[e][5]=az;
            sm.e.aj[e][6]=cx; sm.e.aj[e][7]=cy; sm.e.aj[e][8]=cz;
            sm.e.aj[e][9]=xr[9]; sm.e.aj[e][10]=xr[10]; sm.e.aj[e][11]=xr[11];
            sm.e.aj[e][12] = -0.58273431f*qx + 0.56802827f*bx - 0.54067466f*vx + ax;
            sm.e.aj[e][13] = -0.58273431f*qy + 0.56802827f*by - 0.54067466f*vy + ay;
            sm.e.aj[e][14] = -0.58273431f*qz + 0.56802827f*bz - 0.54067466f*vz + az;
            int off = Ridx[row] - Ridx[b*LLEN + j];
            int ec = (chain[row] == chain[b*LLEN + j]) ? 1 : 0;
            int dc = off + 32; dc = dc < 0 ? 0 : (dc > 64 ? 64 : dc);
            sm.e.didx[e] = ec ? dc : 65;
        }
        if (tid >= 64 && tid < 66) {
            int rl = tid - 64;
            int i = (r0 + rl) & 1023;
            const float* xr = Xb + i*12;
            float nx=xr[0], ny=xr[1], nz=xr[2];
            float ax=xr[3], ay=xr[4], az=xr[5];
            float cx=xr[6], cy=xr[7], cz=xr[8];
            float bx=ax-nx, by=ay-ny, bz=az-nz;
            float vx=cx-ax, vy=cy-ay, vz=cz-az;
            float qx = by*vz - bz*vy, qy = bz*vx - bx*vz, qz = bx*vy - by*vx;
            sm.e.ai[rl][0]=nx; sm.e.ai[rl][1]=ny; sm.e.ai[rl][2]=nz;
            sm.e.ai[rl][3]=ax; sm.e.ai[rl][4]=ay; sm.e.ai[rl][5]=az;
            sm.e.ai[rl][6]=cx; sm.e.ai[rl][7]=cy; sm.e.ai[rl][8]=cz;
            sm.e.ai[rl][9]=xr[9]; sm.e.ai[rl][10]=xr[10]; sm.e.ai[rl][11]=xr[11];
            sm.e.ai[rl][12] = -0.58273431f*qx + 0.56802827f*bx - 0.54067466f*vx + ax;
            sm.e.ai[rl][13] = -0.58273431f*qy + 0.56802827f*by - 0.54067466f*vy + ay;
            sm.e.ai[rl][14] = -0.58273431f*qz + 0.56802827f*bz - 0.54067466f*vz + az;
        }
        __syncthreads();

        for (int item = tid; item < 64 * 26; item += 256) {
            int e = item / 26, it = item - e * 26;
            int rl = e >> 5;
            union { short8_t v[2]; __hip_bfloat16 h[16]; } uf;
            if (it == 0) {
                int d = sm.e.didx[e];
                #pragma unroll
                for (int c = 0; c < 16; ++c) uf.h[c] = __float2bfloat16(posW[d*16 + c] + posb[c]);
            } else {
                float dist;
                if (it == 1) {
                    dist = dnb[(r0 + rl)*KK + (e & 31)];
                } else {
                    int p = it - 2;
                    int a = g_PA[p], q = g_PB[p];
                    float dx = sm.e.ai[rl][a*3+0] - sm.e.aj[e][q*3+0];
                    float dy = sm.e.ai[rl][a*3+1] - sm.e.aj[e][q*3+1];
                    float dz = sm.e.ai[rl][a*3+2] - sm.e.aj[e][q*3+2];
                    dist = sqrtf(dx*dx + dy*dy + dz*dz + 1e-6f);
                }
                #pragma unroll
                for (int r = 0; r < 16; ++r) uf.h[r] = __float2bfloat16(rbf_val(dist, r));
            }
            short8_t* dst = (short8_t*)(sm.e.A + e * KP + it * 16);
            dst[0] = uf.v[0];
            dst[1] = uf.v[1];
        }
        __syncthreads();

        int wid = tid >> 6;
        f32x4 acc[8];
        #pragma unroll
        for (int t = 0; t < 8; ++t) acc[t] = (f32x4){0.f, 0.f, 0.f, 0.f};
        const __hip_bfloat16* Ar = sm.e.A + (wid*16 + col16) * KP + kg * 8;
        const short8_t* Bp = (const short8_t*)Bpack;
        for (int ks = 0; ks < 13; ++ks) {
            short8_t a = *(const short8_t*)(Ar + ks*32);
            #pragma unroll
            for (int t = 0; t < 8; ++t) {
                short8_t bf = Bp[(ks*8 + t)*64 + lane];
                acc[t] = __builtin_amdgcn_mfma_f32_16x16x32_bf16(a, bf, acc[t], 0, 0, 0);
            }
        }
        __syncthreads();

        float* sbuf = (float*)sm.e.A + wid * (16*132);
        float g[8], be[8];
        #pragma unroll
        for (int t = 0; t < 8; ++t) { g[t] = lnEg[t*16 + col16]; be[t] = lnEb[t*16 + col16]; }
        #pragma unroll
        for (int r = 0; r < 4; ++r) {
            float s = 0.0f;
            #pragma unroll
            for (int t = 0; t < 8; ++t) s += acc[t][r];
            s += __shfl_xor(s, 1); s += __shfl_xor(s, 2);
            s += __shfl_xor(s, 4); s += __shfl_xor(s, 8);
            float mean = s * (1.0f/128.0f);
            float q2 = 0.0f;
            #pragma unroll
            for (int t = 0; t < 8; ++t) { float c0 = acc[t][r] - mean; q2 += c0*c0; }
            q2 += __shfl_xor(q2, 1); q2 += __shfl_xor(q2, 2);
            q2 += __shfl_xor(q2, 4); q2 += __shfl_xor(q2, 8);
            float inv = rsqrtf(q2 * (1.0f/128.0f) + 1e-5f);
            float* sr = sbuf + (kg*4 + r) * 132;
            #pragma unroll
            for (int t = 0; t < 8; ++t) sr[t*16 + col16] = (acc[t][r] - mean)*inv*g[t] + be[t];
        }
        float* gdst = outE + ((size_t)r0 * KK + wid*16) * 128;
        #pragma unroll
        for (int it = 0; it < 8; ++it) {
            int off = it*256 + lane*4;
            int rr = off >> 7, cc = off & 127;
            float4 v = *(const float4*)(sbuf + rr*132 + cc);
            *(float4*)(gdst + off) = v;
        }
        return;
    }

    // ==== V (nodes) ====
    {
        int r0 = (vb - VB_N) * NR;
        int nrows = (2048 - r0) < NR ? (2048 - r0) : NR;
        int natoms = nrows * MM;

        if (tid < nrows) {
            int row = r0 + tid;
            int b = row >> 10, i = row & 1023;
            const float* xr = X + ((size_t)b * LLEN + i) * 12;
            float nx=xr[0], ny=xr[1], nz=xr[2];
            float ax=xr[3], ay=xr[4], az=xr[5];
            float cx=xr[6], cy=xr[7], cz=xr[8];
            float bx=ax-nx, by=ay-ny, bz=az-nz;
            float vx=cx-ax, vy=cy-ay, vz=cz-az;
            float qx = by*vz - bz*vy, qy = bz*vx - bx*vz, qz = bx*vy - by*vx;
            sm.n.sat[tid][0]=nx; sm.n.sat[tid][1]=ny; sm.n.sat[tid][2]=nz;
            sm.n.sat[tid][3]=ax; sm.n.sat[tid][4]=ay; sm.n.sat[tid][5]=az;
            sm.n.sat[tid][6]=cx; sm.n.sat[tid][7]=cy; sm.n.sat[tid][8]=cz;
            sm.n.sat[tid][9]=xr[9]; sm.n.sat[tid][10]=xr[10]; sm.n.sat[tid][11]=xr[11];
            sm.n.sat[tid][12] = -0.58273431f*qx + 0.56802827f*bx - 0.54067466f*vx + ax;
            sm.n.sat[tid][13] = -0.58273431f*qy + 0.56802827f*by - 0.54067466f*vy + ay;
            sm.n.sat[tid][14] = -0.58273431f*qz + 0.56802827f*bz - 0.54067466f*vz + az;
            float e1x = nx-ax, e1y = ny-ay, e1z = nz-az;
            float n1 = fmaxf(sqrtf(e1x*e1x+e1y*e1y+e1z*e1z), 1e-12f);
            e1x/=n1; e1y/=n1; e1z/=n1;
            float dd = e1x*vx + e1y*vy + e1z*vz;
            float u2x = vx - e1x*dd, u2y = vy - e1y*dd, u2z = vz - e1z*dd;
            float n2 = fmaxf(sqrtf(u2x*u2x+u2y*u2y+u2z*u2z), 1e-12f);
            u2x/=n2; u2y/=n2; u2z/=n2;
            sm.n.sfr[tid][0]=e1x; sm.n.sfr[tid][1]=e1y; sm.n.sfr[tid][2]=e1z;
            sm.n.sfr[tid][3]=u2x; sm.n.sfr[tid][4]=u2y; sm.n.sfr[tid][5]=u2z;
            sm.n.sfr[tid][6]=e1y*u2z - e1z*u2y;
            sm.n.sfr[tid][7]=e1z*u2x - e1x*u2z;
            sm.n.sfr[tid][8]=e1x*u2y - e1y*u2x;
        }
        __syncthreads();

        for (int item = tid; item < natoms * 10; item += 256) {
            int a = item / 10, it = item - a * 10;
            int rl = a / MM, m = a - rl * MM;
            int row = r0 + rl;
            const float* Yb = Y + (size_t)row * MM * 3 + m * 3;
            union { short8_t v[2]; __hip_bfloat16 h[16]; } uf;
            if (it < 5) {
                float dx = sm.n.sat[rl][it*3+0] - Yb[0];
                float dy = sm.n.sat[rl][it*3+1] - Yb[1];
                float dz = sm.n.sat[rl][it*3+2] - Yb[2];
                float dist = sqrtf(dx*dx + dy*dy + dz*dz + 1e-6f);
                #pragma unroll
                for (int r = 0; r < 16; ++r) uf.h[r] = __float2bfloat16(rbf_val(dist, r));
            } else if (it < 9) {
                int qq = it - 5;
                int t = Yt[row*MM + m];
                int p1 = ptab[120 + t], p2 = ptab[240 + t];
                #pragma unroll
                for (int c = 0; c < 16; ++c) {
                    int cc = qq*16 + c;
                    uf.h[c] = __float2bfloat16(typeW[t*64 + cc] + typeW[(120+p1)*64 + cc]
                            + typeW[(139+p2)*64 + cc] + typeb[cc]);
                }
            } else {
                float vx = Yb[0] - sm.n.sat[rl][3];
                float vy = Yb[1] - sm.n.sat[rl][4];
                float vz = Yb[2] - sm.n.sat[rl][5];
                float l0 = sm.n.sfr[rl][0]*vx + sm.n.sfr[rl][1]*vy + sm.n.sfr[rl][2]*vz;
                float l1 = sm.n.sfr[rl][3]*vx + sm.n.sfr[rl][4]*vy + sm.n.sfr[rl][5]*vz;
                float l2 = sm.n.sfr[rl][6]*vx + sm.n.sfr[rl][7]*vy + sm.n.sfr[rl][8]*vz;
                float rxy  = sqrtf(l0*l0 + l1*l1 + 1e-8f);
                float rxyz = sqrtf(l0*l0 + l1*l1 + l2*l2) + 1e-8f;
                uf.h[0] = __float2bfloat16(l0 / rxy);
                uf.h[1] = __float2bfloat16(l1 / rxy);
                uf.h[2] = __float2bfloat16(rxy / rxyz);
                uf.h[3] = __float2bfloat16(l2 / rxyz);
                #pragma unroll
                for (int c = 4; c < 16; ++c) uf.h[c] = __float2bfloat16(0.0f);
            }
            short8_t* dst = (short8_t*)(sm.n.A + a * KP2 + it * 16);
            dst[0] = uf.v[0];
            dst[1] = uf.v[1];
        }
        __syncthreads();

        int wid = tid >> 6;
        const short8_t* Bp = (const short8_t*)Bpack3;
        float g[8], be[8], bias[8];
        #pragma unroll
        for (int t = 0; t < 8; ++t) {
            g[t] = lnNg[t*16 + col16]; be[t] = lnNb[t*16 + col16];
            bias[t] = npdb[t*16 + col16];
        }
        #pragma unroll
        for (int half = 0; half < 2; ++half) {
            int tile = wid + half*4;
            int abase = tile * 16;
            if (abase < natoms) {
                const __hip_bfloat16* Ar = sm.n.A + (abase + col16) * KP2 + kg * 8;
                f32x4 acc[8];
                #pragma unroll
                for (int t = 0; t < 8; ++t) acc[t] = (f32x4){0.f, 0.f, 0.f, 0.f};
                for (int ks = 0; ks < 5; ++ks) {
                    short8_t a = *(const short8_t*)(Ar + ks*32);
                    #pragma unroll
                    for (int t = 0; t < 8; ++t) {
                        short8_t bf = Bp[(ks*8 + t)*64 + lane];
                        acc[t] = __builtin_amdgcn_mfma_f32_16x16x32_bf16(a, bf, acc[t], 0, 0, 0);
                    }
                }
                #pragma unroll
                for (int r = 0; r < 4; ++r) {
                    float s = 0.0f;
                    #pragma unroll
                    for (int t = 0; t < 8; ++t) { acc[t][r] += bias[t]; s += acc[t][r]; }
                    s += __shfl_xor(s, 1); s += __shfl_xor(s, 2);
                    s += __shfl_xor(s, 4); s += __shfl_xor(s, 8);
                    float mean = s * (1.0f/128.0f);
                    float q2 = 0.0f;
                    #pragma unroll
                    for (int t = 0; t < 8; ++t) { float c0 = acc[t][r] - mean; q2 += c0*c0; }
                    q2 += __shfl_xor(q2, 1); q2 += __shfl_xor(q2, 2);
                    q2 += __shfl_xor(q2, 4); q2 += __shfl_xor(q2, 8);
                    float inv = rsqrtf(q2 * (1.0f/128.0f) + 1e-5f);
                    int aa = abase + kg*4 + r;
                    if (aa < natoms) {
                        float* dst = outV + ((size_t)r0 * MM + aa) * 128 + col16;
                        #pragma unroll
                        for (int t = 0; t < 8; ++t) dst[t*16] = (acc[t][r] - mean)*inv*g[t] + be[t];
                    }
                }
            }
        }
    }
}

// ---------------------------------------------------------------- launcher
extern "C" void kernel_launch(void* const* d_in, const int* in_sizes, int n_in,
                              void* d_out, int out_size, void* d_ws, size_t ws_size,
                              hipStream_t stream) {
    const float* X     = (const float*)d_in[0];
    const float* Y     = (const float*)d_in[1];
    const float* Ym    = (const float*)d_in[2];
    const int*   Yt    = (const int*)d_in[3];
    const float* mask  = (const float*)d_in[4];
    const int*   Ridx  = (const int*)d_in[5];
    const int*   chain = (const int*)d_in[6];
    const float* posW  = (const float*)d_in[7];
    const float* posb  = (const float*)d_in[8];
    const float* edgeW = (const float*)d_in[9];
    const float* lnEg  = (const float*)d_in[10];
    const float* lnEb  = (const float*)d_in[11];
    const float* npdW  = (const float*)d_in[12];
    const float* npdb  = (const float*)d_in[13];
    const float* lnNg  = (const float*)d_in[14];
    const float* lnNb  = (const float*)d_in[15];
    const float* typeW = (const float*)d_in[16];
    const float* typeb = (const float*)d_in[17];
    const float* ynW   = (const float*)d_in[18];
    const float* yeW   = (const float*)d_in[19];
    const float* lnYEg = (const float*)d_in[20];
    const float* lnYEb = (const float*)d_in[21];
    const float* lnYNg = (const float*)d_in[22];
    const float* lnYNb = (const float*)d_in[23];
    const int*   ptab  = (const int*)d_in[24];

    float* o = (float*)d_out;
    // Scratch: d_ws preferred (disjoint from outputs -> full single-kernel merge).
    // Fallback: head of Y_nodes region; then Y_nodes blocks must run in a second
    // launch AFTER all scratch readers (validated R10 schedule).
    bool ws_ok = (ws_size >= (size_t)SCRATCH_BYTES);
    char* scratch = ws_ok ? (char*)d_ws : (char*)(o + OFF_YN);
    int*   eidx = (int*)scratch;
    float* dnb  = (float*)(scratch + BB*LLEN*KK*4);
    __hip_bfloat16* Bpack  = (__hip_bfloat16*)(scratch + 2*BB*LLEN*KK*4);
    __hip_bfloat16* Bpack2 = Bpack + 6656*8;
    __hip_bfloat16* Bpack3 = Bpack2 + 512*8;

    k_pretopk<<<550, 256, 0, stream>>>(X, mask, edgeW, yeW, npdW,
                                       Bpack, Bpack2, Bpack3,
                                       eidx, dnb, o + OFF_EI);
    if (ws_ok) {
        k_main<<<VB_END, 256, 0, stream>>>(0,
            X, Y, Ridx, chain, posW, posb, Bpack, lnEg, lnEb, eidx, dnb,
            Yt, typeW, typeb, ptab, Bpack3, npdb, lnNg, lnNb,
            Bpack2, lnYEg, lnYEb, Ym, ynW, lnYNg, lnYNb,
            o + OFF_V, o + OFF_E, o + OFF_YN, o + OFF_YE, o + OFF_YM);
    } else {
        k_main<<<VB_YN, 256, 0, stream>>>(0,
            X, Y, Ridx, chain, posW, posb, Bpack, lnEg, lnEb, eidx, dnb,
            Yt, typeW, typeb, ptab, Bpack3, npdb, lnNg, lnNb,
            Bpack2, lnYEg, lnYEb, Ym, ynW, lnYNg, lnYNb,
            o + OFF_V, o + OFF_E, o + OFF_YN, o + OFF_YE, o + OFF_YM);
        k_main<<<NB_YN, 256, 0, stream>>>(VB_YN,
            X, Y, Ridx, chain, posW, posb, Bpack, lnEg, lnEb, eidx, dnb,
            Yt, typeW, typeb, ptab, Bpack3, npdb, lnNg, lnNb,
            Bpack2, lnYEg, lnYEb, Ym, ynW, lnYNg, lnYNb,
            o + OFF_V, o + OFF_E, o + OFF_YN, o + OFF_YE, o + OFF_YM);
    }
}

// Round 12
// 218.757 us; speedup vs baseline: 6.8571x; 1.0960x over previous
//
#include <hip/hip_runtime.h>
#include <hip/hip_bf16.h>
#include <stdint.h>

#define BB 2
#define LLEN 1024
#define MM 25
#define KK 32

// d_out is FLOAT32, concatenated in return order:
// (V, E, E_idx, Y_nodes, Y_edges, Y_m) — offsets in f32 elements.
#define OFF_V   0
#define OFF_E   6553600
#define OFF_EI  14942208
#define OFF_YN  15007744
#define OFF_YE  21561344
#define OFF_YM  185401344

#define KP 424          // edge A-tile row stride (bf16)
#define KP2 168         // node A-tile row stride (bf16)
#define NR 5            // rows per nodes block

// phase-1 virtual blocks: [0,512) topk | [512,550) prep | [550,13350) ynodes
#define P1_PREP 512
#define P1_YN   550
#define P1_END  (P1_YN + BB*LLEN*MM/4)   // 13350
// phase-2 virtual blocks: [0,2048) yedges | [2048,3072) edges | [3072,3482) nodes
#define NB_YE  (BB*LLEN)
#define VB_E   NB_YE
#define VB_N   (VB_E + BB*LLEN/2)
#define VB_END (VB_N + (BB*LLEN+NR-1)/NR)

#define SCRATCH_BYTES (680*1024)

typedef __attribute__((ext_vector_type(8))) short short8_t;
typedef __attribute__((ext_vector_type(4))) float f32x4;

__constant__ int g_PA[24] = {0,2,3,4,1,1,1,1,0,0,0,4,4,3,0,2,3,4,2,3,4,2,3,2};
__constant__ int g_PB[24] = {0,2,3,4,0,2,3,4,2,3,4,2,3,2,1,1,1,1,0,0,0,4,4,3};

__device__ __forceinline__ float rbf_val(float d, int r) {
    float mu = 2.0f + (20.0f / 15.0f) * (float)r;
    float z = (d - mu) * 0.8f;
    return __expf(-z * z);
}

// ------------------------------------------------- phase 1: topk + prep + ynodes
__global__ __launch_bounds__(256) void k_phase1(
    int vbase,
    const float* __restrict__ X, const float* __restrict__ mask,
    const float* __restrict__ W, const float* __restrict__ yeW,
    const float* __restrict__ npdW,
    __hip_bfloat16* __restrict__ Bp, __hip_bfloat16* __restrict__ Bp2,
    __hip_bfloat16* __restrict__ Bp3,
    int* __restrict__ eidx, float* __restrict__ dnb,
    float* __restrict__ outEI,
    const int* __restrict__ Yt, const float* __restrict__ Ym,
    const int* __restrict__ ptab, const float* __restrict__ ynW,
    const float* __restrict__ lnYNg, const float* __restrict__ lnYNb,
    float* __restrict__ outYN, float* __restrict__ outYM)
{
    __shared__ float sx[1024], syy[1024], sz[1024], smk[1024];
    int vb = blockIdx.x + vbase;
    int tid = threadIdx.x;
    int wid = tid >> 6, lane = tid & 63;

    if (vb >= P1_YN) {                    // ---- ynodes (light, input-only deps)
        int row = (vb - P1_YN) * 4 + wid;
        int t = Yt[row];
        int p1 = ptab[120 + t], p2 = ptab[240 + t];
        int r0 = t, r1 = 120 + p1, r2 = 139 + p2;
        float x0 = ynW[r0*128 + lane] + ynW[r1*128 + lane] + ynW[r2*128 + lane];
        float x1 = ynW[r0*128 + 64 + lane] + ynW[r1*128 + 64 + lane] + ynW[r2*128 + 64 + lane];
        float s = x0 + x1, s2 = x0*x0 + x1*x1;
        #pragma unroll
        for (int o = 1; o < 64; o <<= 1) { s += __shfl_xor(s, o); s2 += __shfl_xor(s2, o); }
        float mean = s * (1.0f/128.0f);
        float var  = s2 * (1.0f/128.0f) - mean*mean;
        float inv  = rsqrtf(var + 1e-5f);
        size_t base = (size_t)row * 128;
        outYN[base + lane]      = (x0 - mean)*inv*lnYNg[lane]    + lnYNb[lane];
        outYN[base + 64 + lane] = (x1 - mean)*inv*lnYNg[64+lane] + lnYNb[64+lane];
        if (lane == 0) outYM[row] = Ym[row];
        return;
    }

    if (vb >= P1_PREP) {                  // ---- B-pack prep
        int idx = (vb - P1_PREP) * 256 + tid;
        if (idx < 6656) {
            int ln = idx & 63, tt = (idx >> 6) & 7, ks = idx >> 9;
            int k0 = ks*32 + (ln >> 4)*8;
            int n  = tt*16 + (ln & 15);
            __hip_bfloat16* dst = Bp + (size_t)idx * 8;
            #pragma unroll
            for (int j = 0; j < 8; ++j) dst[j] = __float2bfloat16(W[(size_t)(k0 + j)*128 + n]);
        } else if (idx < 7168) {
            int i2 = idx - 6656;
            int ln = i2 & 63, tt = i2 >> 6;
            int kg = ln >> 4;
            int n  = tt*16 + (ln & 15);
            __hip_bfloat16* dst = Bp2 + (size_t)i2 * 8;
            #pragma unroll
            for (int j = 0; j < 8; ++j) {
                float v = (kg < 2) ? yeW[(size_t)(kg*8 + j)*128 + n] : 0.0f;
                dst[j] = __float2bfloat16(v);
            }
        } else if (idx < 9728) {
            int i3 = idx - 7168;
            int ln = i3 & 63, tt = (i3 >> 6) & 7, ks = i3 >> 9;
            int k0 = ks*32 + (ln >> 4)*8;
            int n  = tt*16 + (ln & 15);
            __hip_bfloat16* dst = Bp3 + (size_t)i3 * 8;
            #pragma unroll
            for (int j = 0; j < 8; ++j) {
                int k = k0 + j;
                float v = (k < 148) ? npdW[(size_t)k*128 + n] : 0.0f;
                dst[j] = __float2bfloat16(v);
            }
        }
        return;
    }

    // ---- top-k (validated wave tournament, LDS-staged coords)
    int row0 = vb * 4;
    int b = row0 >> 10;
    const float* Xb = X + (size_t)b * LLEN * 12;
    const float* mb = mask + b * LLEN;
    for (int j = tid; j < 1024; j += 256) {
        sx[j]  = Xb[j*12+3];
        syy[j] = Xb[j*12+4];
        sz[j]  = Xb[j*12+5];
        smk[j] = mb[j];
    }
    __syncthreads();

    int row = row0 + wid, i = row & 1023;
    float cax = sx[i], cay = syy[i], caz = sz[i];
    float mi = smk[i];

    float df[16], mm_[16];
    float lmax = 0.0f;
    #pragma unroll
    for (int q = 0; q < 16; ++q) {
        int j = q*64 + lane;
        float dx = cax - sx[j];
        float dy = cay - syy[j];
        float dz = caz - sz[j];
        float m2 = mi * smk[j];
        float d = sqrtf(dx*dx + dy*dy + dz*dz + 1e-6f) * m2;
        df[q] = d; mm_[q] = m2;
        lmax = fmaxf(lmax, d);
    }
    #pragma unroll
    for (int o = 32; o > 0; o >>= 1) lmax = fmaxf(lmax, __shfl_xor(lmax, o));

    unsigned long long pack[16];
    #pragma unroll
    for (int q = 0; q < 16; ++q) {
        float da = df[q] + (1.0f - mm_[q]) * lmax;
        pack[q] = ((unsigned long long)__float_as_uint(da) << 32) | (unsigned)(q*64 + lane);
    }

    int   myJw = 0;
    float myDv = 0.0f;
    for (int it = 0; it < KK; ++it) {
        unsigned long long lmin = pack[0];
        #pragma unroll
        for (int q = 1; q < 16; ++q) if (pack[q] < lmin) lmin = pack[q];
        #pragma unroll
        for (int o = 32; o > 0; o >>= 1) {
            unsigned long long other = __shfl_xor(lmin, o);
            if (other < lmin) lmin = other;
        }
        int jw = (int)(lmin & 0xffffffffu);
        if (lane == it) { myJw = jw; myDv = __uint_as_float((unsigned)(lmin >> 32)); }
        int lw = jw & 63, qw = jw >> 6;
        #pragma unroll
        for (int q = 0; q < 16; ++q)
            if (lane == lw && q == qw) pack[q] = ~0ull;
    }
    if (lane < KK) {
        eidx[row*KK + lane]  = myJw;
        dnb [row*KK + lane]  = myDv;
        outEI[row*KK + lane] = (float)myJw;
    }
}

// ---------------------------------------------------------------- phase 2: yedges + edges + nodes
union SMem {
    struct { __hip_bfloat16 A[64*KP]; float aj[64][16]; float ai[2][16]; int didx[64]; } e;
    struct { __hip_bfloat16 A[128*KP2]; float sat[NR][15]; float sfr[NR][9]; } n;
    struct { float sy4[32][4]; float stage[4][16*132]; } y;
};

__global__ __launch_bounds__(256) void k_phase2(
    const float* __restrict__ X, const float* __restrict__ Y,
    const int* __restrict__ Ridx, const int* __restrict__ chain,
    const float* __restrict__ posW, const float* __restrict__ posb,
    const __hip_bfloat16* __restrict__ Bpack,
    const float* __restrict__ lnEg, const float* __restrict__ lnEb,
    const int* __restrict__ eidx, const float* __restrict__ dnb,
    const int* __restrict__ Yt,
    const float* __restrict__ typeW, const float* __restrict__ typeb,
    const int* __restrict__ ptab,
    const __hip_bfloat16* __restrict__ Bpack3, const float* __restrict__ npdb,
    const float* __restrict__ lnNg, const float* __restrict__ lnNb,
    const __hip_bfloat16* __restrict__ Bpack2,
    const float* __restrict__ lnYEg, const float* __restrict__ lnYEb,
    float* __restrict__ outV, float* __restrict__ outE,
    float* __restrict__ outYE)
{
    __shared__ __align__(16) SMem sm;
    int vb = blockIdx.x;
    int tid = threadIdx.x;
    int wv = tid >> 6, lane = tid & 63;
    int col16 = lane & 15, kg = lane >> 4;

    if (vb < NB_YE) {                      // ==== Y_edges ====
        int row = vb;
        if (tid < 32) { sm.y.sy4[tid][0]=0.f; sm.y.sy4[tid][1]=0.f; sm.y.sy4[tid][2]=0.f; sm.y.sy4[tid][3]=0.f; }
        __syncthreads();
        if (tid < MM*3) ((float*)sm.y.sy4)[ (tid/3)*4 + (tid%3) ] = Y[(size_t)row * MM * 3 + tid];

        short8_t bfr[8];
        const short8_t* B2 = (const short8_t*)Bpack2;
        #pragma unroll
        for (int t = 0; t < 8; ++t) bfr[t] = B2[t*64 + lane];
        float g[8], be[8];
        #pragma unroll
        for (int t = 0; t < 8; ++t) { g[t] = lnYEg[t*16 + col16]; be[t] = lnYEb[t*16 + col16]; }
        __syncthreads();

        float* outR = outYE + (size_t)row * 625 * 128;
        float* sbuf = sm.y.stage[wv];
        for (int T = wv; T < 40; T += 4) {
            int p0 = T * 16;
            int p  = p0 + col16;
            int pc = p < 624 ? p : 624;
            int m1 = pc / 25, m2 = pc - 25*m1;
            float dx = sm.y.sy4[m1][0] - sm.y.sy4[m2][0];
            float dy = sm.y.sy4[m1][1] - sm.y.sy4[m2][1];
            float dz = sm.y.sy4[m1][2] - sm.y.sy4[m2][2];
            float d = sqrtf(dx*dx + dy*dy + dz*dz + 1e-6f);
            union { short8_t v; __hip_bfloat16 h[8]; } ua;
            if (kg < 2) {
                #pragma unroll
                for (int j = 0; j < 8; ++j) ua.h[j] = __float2bfloat16(rbf_val(d, kg*8 + j));
            } else {
                ua.v = (short8_t){0,0,0,0,0,0,0,0};
            }
            f32x4 acc[8];
            #pragma unroll
            for (int t = 0; t < 8; ++t)
                acc[t] = __builtin_amdgcn_mfma_f32_16x16x32_bf16(ua.v, bfr[t],
                             (f32x4){0.f,0.f,0.f,0.f}, 0, 0, 0);
            #pragma unroll
            for (int r = 0; r < 4; ++r) {
                float s = 0.0f;
                #pragma unroll
                for (int t = 0; t < 8; ++t) s += acc[t][r];
                s += __shfl_xor(s, 1); s += __shfl_xor(s, 2);
                s += __shfl_xor(s, 4); s += __shfl_xor(s, 8);
                float mean = s * (1.0f/128.0f);
                float q2 = 0.0f;
                #pragma unroll
                for (int t = 0; t < 8; ++t) { float c0 = acc[t][r] - mean; q2 += c0*c0; }
                q2 += __shfl_xor(q2, 1); q2 += __shfl_xor(q2, 2);
                q2 += __shfl_xor(q2, 4); q2 += __shfl_xor(q2, 8);
                float inv = rsqrtf(q2 * (1.0f/128.0f) + 1e-5f);
                float* sr = sbuf + (kg*4 + r) * 132;
                #pragma unroll
                for (int t = 0; t < 8; ++t) sr[t*16 + col16] = (acc[t][r] - mean)*inv*g[t] + be[t];
            }
            #pragma unroll
            for (int it = 0; it < 8; ++it) {
                int off = it*256 + lane*4;
                int rr = (off >> 7), cc = off & 127;
                float4 v = *(const float4*)(sbuf + rr*132 + cc);
                int gbase = p0*128 + off;
                if (gbase < 80000) *(float4*)(outR + gbase) = v;
            }
        }
        return;
    }

    if (vb < VB_N) {                       // ==== E (edges) ====
        int r0 = (vb - VB_E) * 2;
        int b  = r0 >> 10;
        const float* Xb = X + (size_t)b * LLEN * 12;

        if (tid < 64) {
            int e = tid, row = r0 + (e >> 5), k = e & 31;
            int j = eidx[row*KK + k];
            const float* xr = Xb + j*12;
            float nx=xr[0], ny=xr[1], nz=xr[2];
            float ax=xr[3], ay=xr[4], az=xr[5];
            float cx=xr[6], cy=xr[7], cz=xr[8];
            float bx=ax-nx, by=ay-ny, bz=az-nz;
            float vx=cx-ax, vy=cy-ay, vz=cz-az;
            float qx = by*vz - bz*vy, qy = bz*vx - bx*vz, qz = bx*vy - by*vx;
            sm.e.aj[e][0]=nx; sm.e.aj[e][1]=ny; sm.e.aj[e][2]=nz;
            sm.e.aj[e][3]=ax; sm.e.aj[e][4]=ay; sm.e.aj[e][5]=az;
            sm.e.aj[e][6]=cx; sm.e.aj[e][7]=cy; sm.e.aj[e][8]=cz;
            sm.e.aj[e][9]=xr[9]; sm.e.aj[e][10]=xr[10]; sm.e.aj[e][11]=xr[11];
            sm.e.aj[e][12] = -0.58273431f*qx + 0.56802827f*bx - 0.54067466f*vx + ax;
            sm.e.aj[e][13] = -0.58273431f*qy + 0.56802827f*by - 0.54067466f*vy + ay;
            sm.e.aj[e][14] = -0.58273431f*qz + 0.56802827f*bz - 0.54067466f*vz + az;
            int off = Ridx[row] - Ridx[b*LLEN + j];
            int ec = (chain[row] == chain[b*LLEN + j]) ? 1 : 0;
            int dc = off + 32; dc = dc < 0 ? 0 : (dc > 64 ? 64 : dc);
            sm.e.didx[e] = ec ? dc : 65;
        }
        if (tid >= 64 && tid < 66) {
            int rl = tid - 64;
            int i = (r0 + rl) & 1023;
            const float* xr = Xb + i*12;
            float nx=xr[0], ny=xr[1], nz=xr[2];
            float ax=xr[3], ay=xr[4], az=xr[5];
            float cx=xr[6], cy=xr[7], cz=xr[8];
            float bx=ax-nx, by=ay-ny, bz=az-nz;
            float vx=cx-ax, vy=cy-ay, vz=cz-az;
            float qx = by*vz - bz*vy, qy = bz*vx - bx*vz, qz = bx*vy - by*vx;
            sm.e.ai[rl][0]=nx; sm.e.ai[rl][1]=ny; sm.e.ai[rl][2]=nz;
            sm.e.ai[rl][3]=ax; sm.e.ai[rl][4]=ay; sm.e.ai[rl][5]=az;
            sm.e.ai[rl][6]=cx; sm.e.ai[rl][7]=cy; sm.e.ai[rl][8]=cz;
            sm.e.ai[rl][9]=xr[9]; sm.e.ai[rl][10]=xr[10]; sm.e.ai[rl][11]=xr[11];
            sm.e.ai[rl][12] = -0.58273431f*qx + 0.56802827f*bx - 0.54067466f*vx + ax;
            sm.e.ai[rl][13] = -0.58273431f*qy + 0.56802827f*by - 0.54067466f*vy + ay;
            sm.e.ai[rl][14] = -0.58273431f*qz + 0.56802827f*bz - 0.54067466f*vz + az;
        }
        __syncthreads();

        for (int item = tid; item < 64 * 26; item += 256) {
            int e = item / 26, it = item - e * 26;
            int rl = e >> 5;
            union { short8_t v[2]; __hip_bfloat16 h[16]; } uf;
            if (it == 0) {
                int d = sm.e.didx[e];
                #pragma unroll
                for (int c = 0; c < 16; ++c) uf.h[c] = __float2bfloat16(posW[d*16 + c] + posb[c]);
            } else {
                float dist;
                if (it == 1) {
                    dist = dnb[(r0 + rl)*KK + (e & 31)];
                } else {
                    int p = it - 2;
                    int a = g_PA[p], q = g_PB[p];
                    float dx = sm.e.ai[rl][a*3+0] - sm.e.aj[e][q*3+0];
                    float dy = sm.e.ai[rl][a*3+1] - sm.e.aj[e][q*3+1];
                    float dz = sm.e.ai[rl][a*3+2] - sm.e.aj[e][q*3+2];
                    dist = sqrtf(dx*dx + dy*dy + dz*dz + 1e-6f);
                }
                #pragma unroll
                for (int r = 0; r < 16; ++r) uf.h[r] = __float2bfloat16(rbf_val(dist, r));
            }
            short8_t* dst = (short8_t*)(sm.e.A + e * KP + it * 16);
            dst[0] = uf.v[0];
            dst[1] = uf.v[1];
        }
        __syncthreads();

        int wid = tid >> 6;
        f32x4 acc[8];
        #pragma unroll
        for (int t = 0; t < 8; ++t) acc[t] = (f32x4){0.f, 0.f, 0.f, 0.f};
        const __hip_bfloat16* Ar = sm.e.A + (wid*16 + col16) * KP + kg * 8;
        const short8_t* Bp = (const short8_t*)Bpack;
        for (int ks = 0; ks < 13; ++ks) {
            short8_t a = *(const short8_t*)(Ar + ks*32);
            #pragma unroll
            for (int t = 0; t < 8; ++t) {
                short8_t bf = Bp[(ks*8 + t)*64 + lane];
                acc[t] = __builtin_amdgcn_mfma_f32_16x16x32_bf16(a, bf, acc[t], 0, 0, 0);
            }
        }
        __syncthreads();

        float* sbuf = (float*)sm.e.A + wid * (16*132);
        float g[8], be[8];
        #pragma unroll
        for (int t = 0; t < 8; ++t) { g[t] = lnEg[t*16 + col16]; be[t] = lnEb[t*16 + col16]; }
        #pragma unroll
        for (int r = 0; r < 4; ++r) {
            float s = 0.0f;
            #pragma unroll
            for (int t = 0; t < 8; ++t) s += acc[t][r];
            s += __shfl_xor(s, 1); s += __shfl_xor(s, 2);
            s += __shfl_xor(s, 4); s += __shfl_xor(s, 8);
            float mean = s * (1.0f/128.0f);
            float q2 = 0.0f;
            #pragma unroll
            for (int t = 0; t < 8; ++t) { float c0 = acc[t][r] - mean; q2 += c0*c0; }
            q2 += __shfl_xor(q2, 1); q2 += __shfl_xor(q2, 2);
            q2 += __shfl_xor(q2, 4); q2 += __shfl_xor(q2, 8);
            float inv = rsqrtf(q2 * (1.0f/128.0f) + 1e-5f);
            float* sr = sbuf + (kg*4 + r) * 132;
            #pragma unroll
            for (int t = 0; t < 8; ++t) sr[t*16 + col16] = (acc[t][r] - mean)*inv*g[t] + be[t];
        }
        float* gdst = outE + ((size_t)r0 * KK + wid*16) * 128;
        #pragma unroll
        for (int it = 0; it < 8; ++it) {
            int off = it*256 + lane*4;
            int rr = off >> 7, cc = off & 127;
            float4 v = *(const float4*)(sbuf + rr*132 + cc);
            *(float4*)(gdst + off) = v;
        }
        return;
    }

    // ==== V (nodes) ====
    {
        int r0 = (vb - VB_N) * NR;
        int nrows = (2048 - r0) < NR ? (2048 - r0) : NR;
        int natoms = nrows * MM;

        if (tid < nrows) {
            int row = r0 + tid;
            int b = row >> 10, i = row & 1023;
            const float* xr = X + ((size_t)b * LLEN + i) * 12;
            float nx=xr[0], ny=xr[1], nz=xr[2];
            float ax=xr[3], ay=xr[4], az=xr[5];
            float cx=xr[6], cy=xr[7], cz=xr[8];
            float bx=ax-nx, by=ay-ny, bz=az-nz;
            float vx=cx-ax, vy=cy-ay, vz=cz-az;
            float qx = by*vz - bz*vy, qy = bz*vx - bx*vz, qz = bx*vy - by*vx;
            sm.n.sat[tid][0]=nx; sm.n.sat[tid][1]=ny; sm.n.sat[tid][2]=nz;
            sm.n.sat[tid][3]=ax; sm.n.sat[tid][4]=ay; sm.n.sat[tid][5]=az;
            sm.n.sat[tid][6]=cx; sm.n.sat[tid][7]=cy; sm.n.sat[tid][8]=cz;
            sm.n.sat[tid][9]=xr[9]; sm.n.sat[tid][10]=xr[10]; sm.n.sat[tid][11]=xr[11];
            sm.n.sat[tid][12] = -0.58273431f*qx + 0.56802827f*bx - 0.54067466f*vx + ax;
            sm.n.sat[tid][13] = -0.58273431f*qy + 0.56802827f*by - 0.54067466f*vy + ay;
            sm.n.sat[tid][14] = -0.58273431f*qz + 0.56802827f*bz - 0.54067466f*vz + az;
            float e1x = nx-ax, e1y = ny-ay, e1z = nz-az;
            float n1 = fmaxf(sqrtf(e1x*e1x+e1y*e1y+e1z*e1z), 1e-12f);
            e1x/=n1; e1y/=n1; e1z/=n1;
            float dd = e1x*vx + e1y*vy + e1z*vz;
            float u2x = vx - e1x*dd, u2y = vy - e1y*dd, u2z = vz - e1z*dd;
            float n2 = fmaxf(sqrtf(u2x*u2x+u2y*u2y+u2z*u2z), 1e-12f);
            u2x/=n2; u2y/=n2; u2z/=n2;
            sm.n.sfr[tid][0]=e1x; sm.n.sfr[tid][1]=e1y; sm.n.sfr[tid][2]=e1z;
            sm.n.sfr[tid][3]=u2x; sm.n.sfr[tid][4]=u2y; sm.n.sfr[tid][5]=u2z;
            sm.n.sfr[tid][6]=e1y*u2z - e1z*u2y;
            sm.n.sfr[tid][7]=e1z*u2x - e1x*u2z;
            sm.n.sfr[tid][8]=e1x*u2y - e1y*u2x;
        }
        __syncthreads();

        for (int item = tid; item < natoms * 10; item += 256) {
            int a = item / 10, it = item - a * 10;
            int rl = a / MM, m = a - rl * MM;
            int row = r0 + rl;
            const float* Yb = Y + (size_t)row * MM * 3 + m * 3;
            union { short8_t v[2]; __hip_bfloat16 h[16]; } uf;
            if (it < 5) {
                float dx = sm.n.sat[rl][it*3+0] - Yb[0];
                float dy = sm.n.sat[rl][it*3+1] - Yb[1];
                float dz = sm.n.sat[rl][it*3+2] - Yb[2];
                float dist = sqrtf(dx*dx + dy*dy + dz*dz + 1e-6f);
                #pragma unroll
                for (int r = 0; r < 16; ++r) uf.h[r] = __float2bfloat16(rbf_val(dist, r));
            } else if (it < 9) {
                int qq = it - 5;
                int t = Yt[row*MM + m];
                int p1 = ptab[120 + t], p2 = ptab[240 + t];
                #pragma unroll
                for (int c = 0; c < 16; ++c) {
                    int cc = qq*16 + c;
                    uf.h[c] = __float2bfloat16(typeW[t*64 + cc] + typeW[(120+p1)*64 + cc]
                            + typeW[(139+p2)*64 + cc] + typeb[cc]);
                }
            } else {
                float vx = Yb[0] - sm.n.sat[rl][3];
                float vy = Yb[1] - sm.n.sat[rl][4];
                float vz = Yb[2] - sm.n.sat[rl][5];
                float l0 = sm.n.sfr[rl][0]*vx + sm.n.sfr[rl][1]*vy + sm.n.sfr[rl][2]*vz;
                float l1 = sm.n.sfr[rl][3]*vx + sm.n.sfr[rl][4]*vy + sm.n.sfr[rl][5]*vz;
                float l2 = sm.n.sfr[rl][6]*vx + sm.n.sfr[rl][7]*vy + sm.n.sfr[rl][8]*vz;
                float rxy  = sqrtf(l0*l0 + l1*l1 + 1e-8f);
                float rxyz = sqrtf(l0*l0 + l1*l1 + l2*l2) + 1e-8f;
                uf.h[0] = __float2bfloat16(l0 / rxy);
                uf.h[1] = __float2bfloat16(l1 / rxy);
                uf.h[2] = __float2bfloat16(rxy / rxyz);
                uf.h[3] = __float2bfloat16(l2 / rxyz);
                #pragma unroll
                for (int c = 4; c < 16; ++c) uf.h[c] = __float2bfloat16(0.0f);
            }
            short8_t* dst = (short8_t*)(sm.n.A + a * KP2 + it * 16);
            dst[0] = uf.v[0];
            dst[1] = uf.v[1];
        }
        __syncthreads();

        int wid = tid >> 6;
        const short8_t* Bp = (const short8_t*)Bpack3;
        float g[8], be[8], bias[8];
        #pragma unroll
        for (int t = 0; t < 8; ++t) {
            g[t] = lnNg[t*16 + col16]; be[t] = lnNb[t*16 + col16];
            bias[t] = npdb[t*16 + col16];
        }
        #pragma unroll
        for (int half = 0; half < 2; ++half) {
            int tile = wid + half*4;
            int abase = tile * 16;
            if (abase < natoms) {
                const __hip_bfloat16* Ar = sm.n.A + (abase + col16) * KP2 + kg * 8;
                f32x4 acc[8];
                #pragma unroll
                for (int t = 0; t < 8; ++t) acc[t] = (f32x4){0.f, 0.f, 0.f, 0.f};
                for (int ks = 0; ks < 5; ++ks) {
                    short8_t a = *(const short8_t*)(Ar + ks*32);
                    #pragma unroll
                    for (int t = 0; t < 8; ++t) {
                        short8_t bf = Bp[(ks*8 + t)*64 + lane];
                        acc[t] = __builtin_amdgcn_mfma_f32_16x16x32_bf16(a, bf, acc[t], 0, 0, 0);
                    }
                }
                #pragma unroll
                for (int r = 0; r < 4; ++r) {
                    float s = 0.0f;
                    #pragma unroll
                    for (int t = 0; t < 8; ++t) { acc[t][r] += bias[t]; s += acc[t][r]; }
                    s += __shfl_xor(s, 1); s += __shfl_xor(s, 2);
                    s += __shfl_xor(s, 4); s += __shfl_xor(s, 8);
                    float mean = s * (1.0f/128.0f);
                    float q2 = 0.0f;
                    #pragma unroll
                    for (int t = 0; t < 8; ++t) { float c0 = acc[t][r] - mean; q2 += c0*c0; }
                    q2 += __shfl_xor(q2, 1); q2 += __shfl_xor(q2, 2);
                    q2 += __shfl_xor(q2, 4); q2 += __shfl_xor(q2, 8);
                    float inv = rsqrtf(q2 * (1.0f/128.0f) + 1e-5f);
                    int aa = abase + kg*4 + r;
                    if (aa < natoms) {
                        float* dst = outV + ((size_t)r0 * MM + aa) * 128 + col16;
                        #pragma unroll
                        for (int t = 0; t < 8; ++t) dst[t*16] = (acc[t][r] - mean)*inv*g[t] + be[t];
                    }
                }
            }
        }
    }
}

// ---------------------------------------------------------------- launcher
extern "C" void kernel_launch(void* const* d_in, const int* in_sizes, int n_in,
                              void* d_out, int out_size, void* d_ws, size_t ws_size,
                              hipStream_t stream) {
    const float* X     = (const float*)d_in[0];
    const float* Y     = (const float*)d_in[1];
    const float* Ym    = (const float*)d_in[2];
    const int*   Yt    = (const int*)d_in[3];
    const float* mask  = (const float*)d_in[4];
    const int*   Ridx  = (const int*)d_in[5];
    const int*   chain = (const int*)d_in[6];
    const float* posW  = (const float*)d_in[7];
    const float* posb  = (const float*)d_in[8];
    const float* edgeW = (const float*)d_in[9];
    const float* lnEg  = (const float*)d_in[10];
    const float* lnEb  = (const float*)d_in[11];
    const float* npdW  = (const float*)d_in[12];
    const float* npdb  = (const float*)d_in[13];
    const float* lnNg  = (const float*)d_in[14];
    const float* lnNb  = (const float*)d_in[15];
    const float* typeW = (const float*)d_in[16];
    const float* typeb = (const float*)d_in[17];
    const float* ynW   = (const float*)d_in[18];
    const float* yeW   = (const float*)d_in[19];
    const float* lnYEg = (const float*)d_in[20];
    const float* lnYEb = (const float*)d_in[21];
    const float* lnYNg = (const float*)d_in[22];
    const float* lnYNb = (const float*)d_in[23];
    const int*   ptab  = (const int*)d_in[24];

    float* o = (float*)d_out;
    bool ws_ok = (ws_size >= (size_t)SCRATCH_BYTES);
    char* scratch = ws_ok ? (char*)d_ws : (char*)(o + OFF_YN);
    int*   eidx = (int*)scratch;
    float* dnb  = (float*)(scratch + BB*LLEN*KK*4);
    __hip_bfloat16* Bpack  = (__hip_bfloat16*)(scratch + 2*BB*LLEN*KK*4);
    __hip_bfloat16* Bpack2 = Bpack + 6656*8;
    __hip_bfloat16* Bpack3 = Bpack2 + 512*8;

    if (ws_ok) {
        // phase1: topk + prep + ynodes (ynodes has input-only deps, 16KB-LDS kernel)
        k_phase1<<<P1_END, 256, 0, stream>>>(0, X, mask, edgeW, yeW, npdW,
            Bpack, Bpack2, Bpack3, eidx, dnb, o + OFF_EI,
            Yt, Ym, ptab, ynW, lnYNg, lnYNb, o + OFF_YN, o + OFF_YM);
        k_phase2<<<VB_END, 256, 0, stream>>>(
            X, Y, Ridx, chain, posW, posb, Bpack, lnEg, lnEb, eidx, dnb,
            Yt, typeW, typeb, ptab, Bpack3, npdb, lnNg, lnNb,
            Bpack2, lnYEg, lnYEb, o + OFF_V, o + OFF_E, o + OFF_YE);
    } else {
        // fallback: scratch overlaps YN region -> ynodes must run LAST
        k_phase1<<<P1_YN, 256, 0, stream>>>(0, X, mask, edgeW, yeW, npdW,
            Bpack, Bpack2, Bpack3, eidx, dnb, o + OFF_EI,
            Yt, Ym, ptab, ynW, lnYNg, lnYNb, o + OFF_YN, o + OFF_YM);
        k_phase2<<<VB_END, 256, 0, stream>>>(
            X, Y, Ridx, chain, posW, posb, Bpack, lnEg, lnEb, eidx, dnb,
            Yt, typeW, typeb, ptab, Bpack3, npdb, lnNg, lnNb,
            Bpack2, lnYEg, lnYEb, o + OFF_V, o + OFF_E, o + OFF_YE);
        k_phase1<<<P1_END - P1_YN, 256, 0, stream>>>(P1_YN, X, mask, edgeW, yeW, npdW,
            Bpack, Bpack2, Bpack3, eidx, dnb, o + OFF_EI,
            Yt, Ym, ptab, ynW, lnYNg, lnYNb, o + OFF_YN, o + OFF_YM);
    }
}

// Round 13
// 202.040 us; speedup vs baseline: 7.4245x; 1.0827x over previous
//
#include <hip/hip_runtime.h>
#include <hip/hip_bf16.h>
#include <stdint.h>

#define BB 2
#define LLEN 1024
#define MM 25
#define KK 32

// d_out is FLOAT32, concatenated in return order:
// (V, E, E_idx, Y_nodes, Y_edges, Y_m) — offsets in f32 elements.
#define OFF_V   0
#define OFF_E   6553600
#define OFF_EI  14942208
#define OFF_YN  15007744
#define OFF_YE  21561344
#define OFF_YM  185401344

#define KP 424          // edge A-tile row stride (bf16)
#define KP2 168         // node A-tile row stride (bf16)
#define NR 5            // rows per nodes block

// phase-1 virtual blocks: [0,512) topk | [512,550) prep | [550,13350) ynodes
#define P1_PREP 512
#define P1_YN   550
#define P1_END  (P1_YN + BB*LLEN*MM/4)   // 13350
// phase-2 virtual blocks: [0,2048) yedges | [2048,3072) edges | [3072,3482) nodes
#define NB_YE  (BB*LLEN)                      // 2048
#define VB_E   NB_YE
#define VB_N   (VB_E + BB*LLEN/2)             // 3072
#define VB_END (VB_N + (BB*LLEN+NR-1)/NR)     // 3482
#define NB_OTH (VB_END - NB_YE)               // 1434 (edges+nodes)
#define INTERL (2*NB_OTH)                     // 2868

#define SCRATCH_BYTES (680*1024)

typedef __attribute__((ext_vector_type(8))) short short8_t;
typedef __attribute__((ext_vector_type(4))) float f32x4;

__constant__ int g_PA[24] = {0,2,3,4,1,1,1,1,0,0,0,4,4,3,0,2,3,4,2,3,4,2,3,2};
__constant__ int g_PB[24] = {0,2,3,4,0,2,3,4,2,3,4,2,3,2,1,1,1,1,0,0,0,4,4,3};

__device__ __forceinline__ float rbf_val(float d, int r) {
    float mu = 2.0f + (20.0f / 15.0f) * (float)r;
    float z = (d - mu) * 0.8f;
    return __expf(-z * z);
}

// ------------------------------------------------- phase 1: topk + prep + ynodes
__global__ __launch_bounds__(256) void k_phase1(
    int vbase,
    const float* __restrict__ X, const float* __restrict__ mask,
    const float* __restrict__ W, const float* __restrict__ yeW,
    const float* __restrict__ npdW,
    __hip_bfloat16* __restrict__ Bp, __hip_bfloat16* __restrict__ Bp2,
    __hip_bfloat16* __restrict__ Bp3,
    int* __restrict__ eidx, float* __restrict__ dnb,
    float* __restrict__ outEI,
    const int* __restrict__ Yt, const float* __restrict__ Ym,
    const int* __restrict__ ptab, const float* __restrict__ ynW,
    const float* __restrict__ lnYNg, const float* __restrict__ lnYNb,
    float* __restrict__ outYN, float* __restrict__ outYM)
{
    __shared__ float sx[1024], syy[1024], sz[1024], smk[1024];
    int vb = blockIdx.x + vbase;
    int tid = threadIdx.x;
    int wid = tid >> 6, lane = tid & 63;

    if (vb >= P1_YN) {                    // ---- ynodes (light, input-only deps)
        int row = (vb - P1_YN) * 4 + wid;
        int t = Yt[row];
        int p1 = ptab[120 + t], p2 = ptab[240 + t];
        int r0 = t, r1 = 120 + p1, r2 = 139 + p2;
        float x0 = ynW[r0*128 + lane] + ynW[r1*128 + lane] + ynW[r2*128 + lane];
        float x1 = ynW[r0*128 + 64 + lane] + ynW[r1*128 + 64 + lane] + ynW[r2*128 + 64 + lane];
        float s = x0 + x1, s2 = x0*x0 + x1*x1;
        #pragma unroll
        for (int o = 1; o < 64; o <<= 1) { s += __shfl_xor(s, o); s2 += __shfl_xor(s2, o); }
        float mean = s * (1.0f/128.0f);
        float var  = s2 * (1.0f/128.0f) - mean*mean;
        float inv  = rsqrtf(var + 1e-5f);
        size_t base = (size_t)row * 128;
        outYN[base + lane]      = (x0 - mean)*inv*lnYNg[lane]    + lnYNb[lane];
        outYN[base + 64 + lane] = (x1 - mean)*inv*lnYNg[64+lane] + lnYNb[64+lane];
        if (lane == 0) outYM[row] = Ym[row];
        return;
    }

    if (vb >= P1_PREP) {                  // ---- B-pack prep
        int idx = (vb - P1_PREP) * 256 + tid;
        if (idx < 6656) {
            int ln = idx & 63, tt = (idx >> 6) & 7, ks = idx >> 9;
            int k0 = ks*32 + (ln >> 4)*8;
            int n  = tt*16 + (ln & 15);
            __hip_bfloat16* dst = Bp + (size_t)idx * 8;
            #pragma unroll
            for (int j = 0; j < 8; ++j) dst[j] = __float2bfloat16(W[(size_t)(k0 + j)*128 + n]);
        } else if (idx < 7168) {
            int i2 = idx - 6656;
            int ln = i2 & 63, tt = i2 >> 6;
            int kg = ln >> 4;
            int n  = tt*16 + (ln & 15);
            __hip_bfloat16* dst = Bp2 + (size_t)i2 * 8;
            #pragma unroll
            for (int j = 0; j < 8; ++j) {
                float v = (kg < 2) ? yeW[(size_t)(kg*8 + j)*128 + n] : 0.0f;
                dst[j] = __float2bfloat16(v);
            }
        } else if (idx < 9728) {
            int i3 = idx - 7168;
            int ln = i3 & 63, tt = (i3 >> 6) & 7, ks = i3 >> 9;
            int k0 = ks*32 + (ln >> 4)*8;
            int n  = tt*16 + (ln & 15);
            __hip_bfloat16* dst = Bp3 + (size_t)i3 * 8;
            #pragma unroll
            for (int j = 0; j < 8; ++j) {
                int k = k0 + j;
                float v = (k < 148) ? npdW[(size_t)k*128 + n] : 0.0f;
                dst[j] = __float2bfloat16(v);
            }
        }
        return;
    }

    // ---- top-k (validated wave tournament, LDS-staged coords)
    int row0 = vb * 4;
    int b = row0 >> 10;
    const float* Xb = X + (size_t)b * LLEN * 12;
    const float* mb = mask + b * LLEN;
    for (int j = tid; j < 1024; j += 256) {
        sx[j]  = Xb[j*12+3];
        syy[j] = Xb[j*12+4];
        sz[j]  = Xb[j*12+5];
        smk[j] = mb[j];
    }
    __syncthreads();

    int row = row0 + wid, i = row & 1023;
    float cax = sx[i], cay = syy[i], caz = sz[i];
    float mi = smk[i];

    float df[16], mm_[16];
    float lmax = 0.0f;
    #pragma unroll
    for (int q = 0; q < 16; ++q) {
        int j = q*64 + lane;
        float dx = cax - sx[j];
        float dy = cay - syy[j];
        float dz = caz - sz[j];
        float m2 = mi * smk[j];
        float d = sqrtf(dx*dx + dy*dy + dz*dz + 1e-6f) * m2;
        df[q] = d; mm_[q] = m2;
        lmax = fmaxf(lmax, d);
    }
    #pragma unroll
    for (int o = 32; o > 0; o >>= 1) lmax = fmaxf(lmax, __shfl_xor(lmax, o));

    unsigned long long pack[16];
    #pragma unroll
    for (int q = 0; q < 16; ++q) {
        float da = df[q] + (1.0f - mm_[q]) * lmax;
        pack[q] = ((unsigned long long)__float_as_uint(da) << 32) | (unsigned)(q*64 + lane);
    }

    int   myJw = 0;
    float myDv = 0.0f;
    for (int it = 0; it < KK; ++it) {
        unsigned long long lmin = pack[0];
        #pragma unroll
        for (int q = 1; q < 16; ++q) if (pack[q] < lmin) lmin = pack[q];
        #pragma unroll
        for (int o = 32; o > 0; o >>= 1) {
            unsigned long long other = __shfl_xor(lmin, o);
            if (other < lmin) lmin = other;
        }
        int jw = (int)(lmin & 0xffffffffu);
        if (lane == it) { myJw = jw; myDv = __uint_as_float((unsigned)(lmin >> 32)); }
        int lw = jw & 63, qw = jw >> 6;
        #pragma unroll
        for (int q = 0; q < 16; ++q)
            if (lane == lw && q == qw) pack[q] = ~0ull;
    }
    if (lane < KK) {
        eidx[row*KK + lane]  = myJw;
        dnb [row*KK + lane]  = myDv;
        outEI[row*KK + lane] = (float)myJw;
    }
}

// ---------------------------------------------------------------- phase 2: yedges + edges + nodes
union SMem {
    struct { __hip_bfloat16 A[64*KP]; float aj[64][16]; float ai[2][16]; int didx[64]; } e;
    struct { __hip_bfloat16 A[128*KP2]; float sat[NR][15]; float sfr[NR][9]; } n;
    struct { float sy4[32][4]; float stage[4][16*132]; } y;
};

__global__ __launch_bounds__(256) void k_phase2(
    const float* __restrict__ X, const float* __restrict__ Y,
    const int* __restrict__ Ridx, const int* __restrict__ chain,
    const float* __restrict__ posW, const float* __restrict__ posb,
    const __hip_bfloat16* __restrict__ Bpack,
    const float* __restrict__ lnEg, const float* __restrict__ lnEb,
    const int* __restrict__ eidx, const float* __restrict__ dnb,
    const int* __restrict__ Yt,
    const float* __restrict__ typeW, const float* __restrict__ typeb,
    const int* __restrict__ ptab,
    const __hip_bfloat16* __restrict__ Bpack3, const float* __restrict__ npdb,
    const float* __restrict__ lnNg, const float* __restrict__ lnNb,
    const __hip_bfloat16* __restrict__ Bpack2,
    const float* __restrict__ lnYEg, const float* __restrict__ lnYEb,
    float* __restrict__ outV, float* __restrict__ outE,
    float* __restrict__ outYE)
{
    __shared__ __align__(16) SMem sm;
    // Interleave dispatch order: even raw -> yedges (write-bound), odd raw ->
    // edges/nodes (compute-bound), so each CU co-hosts one of each and compute
    // hides under the HBM write pole. Tail raw>=INTERL -> remaining yedges.
    int raw = blockIdx.x;
    int vb;
    if (raw < INTERL) {
        int pair = raw >> 1;
        vb = (raw & 1) ? (NB_YE + pair) : pair;
    } else {
        vb = (raw - INTERL) + NB_OTH;       // yedges NB_OTH..2047
    }
    int tid = threadIdx.x;
    int wv = tid >> 6, lane = tid & 63;
    int col16 = lane & 15, kg = lane >> 4;

    if (vb < NB_YE) {                      // ==== Y_edges ====
        int row = vb;
        if (tid < 32) { sm.y.sy4[tid][0]=0.f; sm.y.sy4[tid][1]=0.f; sm.y.sy4[tid][2]=0.f; sm.y.sy4[tid][3]=0.f; }
        __syncthreads();
        if (tid < MM*3) ((float*)sm.y.sy4)[ (tid/3)*4 + (tid%3) ] = Y[(size_t)row * MM * 3 + tid];

        short8_t bfr[8];
        const short8_t* B2 = (const short8_t*)Bpack2;
        #pragma unroll
        for (int t = 0; t < 8; ++t) bfr[t] = B2[t*64 + lane];
        float g[8], be[8];
        #pragma unroll
        for (int t = 0; t < 8; ++t) { g[t] = lnYEg[t*16 + col16]; be[t] = lnYEb[t*16 + col16]; }
        __syncthreads();

        float* outR = outYE + (size_t)row * 625 * 128;
        float* sbuf = sm.y.stage[wv];
        for (int T = wv; T < 40; T += 4) {
            int p0 = T * 16;
            int p  = p0 + col16;
            int pc = p < 624 ? p : 624;
            int m1 = pc / 25, m2 = pc - 25*m1;
            float dx = sm.y.sy4[m1][0] - sm.y.sy4[m2][0];
            float dy = sm.y.sy4[m1][1] - sm.y.sy4[m2][1];
            float dz = sm.y.sy4[m1][2] - sm.y.sy4[m2][2];
            float d = sqrtf(dx*dx + dy*dy + dz*dz + 1e-6f);
            union { short8_t v; __hip_bfloat16 h[8]; } ua;
            if (kg < 2) {
                #pragma unroll
                for (int j = 0; j < 8; ++j) ua.h[j] = __float2bfloat16(rbf_val(d, kg*8 + j));
            } else {
                ua.v = (short8_t){0,0,0,0,0,0,0,0};
            }
            f32x4 acc[8];
            #pragma unroll
            for (int t = 0; t < 8; ++t)
                acc[t] = __builtin_amdgcn_mfma_f32_16x16x32_bf16(ua.v, bfr[t],
                             (f32x4){0.f,0.f,0.f,0.f}, 0, 0, 0);
            #pragma unroll
            for (int r = 0; r < 4; ++r) {
                float s = 0.0f;
                #pragma unroll
                for (int t = 0; t < 8; ++t) s += acc[t][r];
                s += __shfl_xor(s, 1); s += __shfl_xor(s, 2);
                s += __shfl_xor(s, 4); s += __shfl_xor(s, 8);
                float mean = s * (1.0f/128.0f);
                float q2 = 0.0f;
                #pragma unroll
                for (int t = 0; t < 8; ++t) { float c0 = acc[t][r] - mean; q2 += c0*c0; }
                q2 += __shfl_xor(q2, 1); q2 += __shfl_xor(q2, 2);
                q2 += __shfl_xor(q2, 4); q2 += __shfl_xor(q2, 8);
                float inv = rsqrtf(q2 * (1.0f/128.0f) + 1e-5f);
                float* sr = sbuf + (kg*4 + r) * 132;
                #pragma unroll
                for (int t = 0; t < 8; ++t) sr[t*16 + col16] = (acc[t][r] - mean)*inv*g[t] + be[t];
            }
            #pragma unroll
            for (int it = 0; it < 8; ++it) {
                int off = it*256 + lane*4;
                int rr = (off >> 7), cc = off & 127;
                float4 v = *(const float4*)(sbuf + rr*132 + cc);
                int gbase = p0*128 + off;
                if (gbase < 80000) *(float4*)(outR + gbase) = v;
            }
        }
        return;
    }

    if (vb < VB_N) {                       // ==== E (edges) ====
        int r0 = (vb - VB_E) * 2;
        int b  = r0 >> 10;
        const float* Xb = X + (size_t)b * LLEN * 12;

        if (tid < 64) {
            int e = tid, row = r0 + (e >> 5), k = e & 31;
            int j = eidx[row*KK + k];
            const float* xr = Xb + j*12;
            float nx=xr[0], ny=xr[1], nz=xr[2];
            float ax=xr[3], ay=xr[4], az=xr[5];
            float cx=xr[6], cy=xr[7], cz=xr[8];
            float bx=ax-nx, by=ay-ny, bz=az-nz;
            float vx=cx-ax, vy=cy-ay, vz=cz-az;
            float qx = by*vz - bz*vy, qy = bz*vx - bx*vz, qz = bx*vy - by*vx;
            sm.e.aj[e][0]=nx; sm.e.aj[e][1]=ny; sm.e.aj[e][2]=nz;
            sm.e.aj[e][3]=ax; sm.e.aj[e][4]=ay; sm.e.aj[e][5]=az;
            sm.e.aj[e][6]=cx; sm.e.aj[e][7]=cy; sm.e.aj[e][8]=cz;
            sm.e.aj[e][9]=xr[9]; sm.e.aj[e][10]=xr[10]; sm.e.aj[e][11]=xr[11];
            sm.e.aj[e][12] = -0.58273431f*qx + 0.56802827f*bx - 0.54067466f*vx + ax;
            sm.e.aj[e][13] = -0.58273431f*qy + 0.56802827f*by - 0.54067466f*vy + ay;
            sm.e.aj[e][14] = -0.58273431f*qz + 0.56802827f*bz - 0.54067466f*vz + az;
            int off = Ridx[row] - Ridx[b*LLEN + j];
            int ec = (chain[row] == chain[b*LLEN + j]) ? 1 : 0;
            int dc = off + 32; dc = dc < 0 ? 0 : (dc > 64 ? 64 : dc);
            sm.e.didx[e] = ec ? dc : 65;
        }
        if (tid >= 64 && tid < 66) {
            int rl = tid - 64;
            int i = (r0 + rl) & 1023;
            const float* xr = Xb + i*12;
            float nx=xr[0], ny=xr[1], nz=xr[2];
            float ax=xr[3], ay=xr[4], az=xr[5];
            float cx=xr[6], cy=xr[7], cz=xr[8];
            float bx=ax-nx, by=ay-ny, bz=az-nz;
            float vx=cx-ax, vy=cy-ay, vz=cz-az;
            float qx = by*vz - bz*vy, qy = bz*vx - bx*vz, qz = bx*vy - by*vx;
            sm.e.ai[rl][0]=nx; sm.e.ai[rl][1]=ny; sm.e.ai[rl][2]=nz;
            sm.e.ai[rl][3]=ax; sm.e.ai[rl][4]=ay; sm.e.ai[rl][5]=az;
            sm.e.ai[rl][6]=cx; sm.e.ai[rl][7]=cy; sm.e.ai[rl][8]=cz;
            sm.e.ai[rl][9]=xr[9]; sm.e.ai[rl][10]=xr[10]; sm.e.ai[rl][11]=xr[11];
            sm.e.ai[rl][12] = -0.58273431f*qx + 0.56802827f*bx - 0.54067466f*vx + ax;
            sm.e.ai[rl][13] = -0.58273431f*qy + 0.56802827f*by - 0.54067466f*vy + ay;
            sm.e.ai[rl][14] = -0.58273431f*qz + 0.56802827f*bz - 0.54067466f*vz + az;
        }
        __syncthreads();

        for (int item = tid; item < 64 * 26; item += 256) {
            int e = item / 26, it = item - e * 26;
            int rl = e >> 5;
            union { short8_t v[2]; __hip_bfloat16 h[16]; } uf;
            if (it == 0) {
                int d = sm.e.didx[e];
                #pragma unroll
                for (int c = 0; c < 16; ++c) uf.h[c] = __float2bfloat16(posW[d*16 + c] + posb[c]);
            } else {
                float dist;
                if (it == 1) {
                    dist = dnb[(r0 + rl)*KK + (e & 31)];
                } else {
                    int p = it - 2;
                    int a = g_PA[p], q = g_PB[p];
                    float dx = sm.e.ai[rl][a*3+0] - sm.e.aj[e][q*3+0];
                    float dy = sm.e.ai[rl][a*3+1] - sm.e.aj[e][q*3+1];
                    float dz = sm.e.ai[rl][a*3+2] - sm.e.aj[e][q*3+2];
                    dist = sqrtf(dx*dx + dy*dy + dz*dz + 1e-6f);
                }
                #pragma unroll
                for (int r = 0; r < 16; ++r) uf.h[r] = __float2bfloat16(rbf_val(dist, r));
            }
            short8_t* dst = (short8_t*)(sm.e.A + e * KP + it * 16);
            dst[0] = uf.v[0];
            dst[1] = uf.v[1];
        }
        __syncthreads();

        int wid = tid >> 6;
        f32x4 acc[8];
        #pragma unroll
        for (int t = 0; t < 8; ++t) acc[t] = (f32x4){0.f, 0.f, 0.f, 0.f};
        const __hip_bfloat16* Ar = sm.e.A + (wid*16 + col16) * KP + kg * 8;
        const short8_t* Bp = (const short8_t*)Bpack;
        for (int ks = 0; ks < 13; ++ks) {
            short8_t a = *(const short8_t*)(Ar + ks*32);
            #pragma unroll
            for (int t = 0; t < 8; ++t) {
                short8_t bf = Bp[(ks*8 + t)*64 + lane];
                acc[t] = __builtin_amdgcn_mfma_f32_16x16x32_bf16(a, bf, acc[t], 0, 0, 0);
            }
        }
        __syncthreads();

        float* sbuf = (float*)sm.e.A + wid * (16*132);
        float g[8], be[8];
        #pragma unroll
        for (int t = 0; t < 8; ++t) { g[t] = lnEg[t*16 + col16]; be[t] = lnEb[t*16 + col16]; }
        #pragma unroll
        for (int r = 0; r < 4; ++r) {
            float s = 0.0f;
            #pragma unroll
            for (int t = 0; t < 8; ++t) s += acc[t][r];
            s += __shfl_xor(s, 1); s += __shfl_xor(s, 2);
            s += __shfl_xor(s, 4); s += __shfl_xor(s, 8);
            float mean = s * (1.0f/128.0f);
            float q2 = 0.0f;
            #pragma unroll
            for (int t = 0; t < 8; ++t) { float c0 = acc[t][r] - mean; q2 += c0*c0; }
            q2 += __shfl_xor(q2, 1); q2 += __shfl_xor(q2, 2);
            q2 += __shfl_xor(q2, 4); q2 += __shfl_xor(q2, 8);
            float inv = rsqrtf(q2 * (1.0f/128.0f) + 1e-5f);
            float* sr = sbuf + (kg*4 + r) * 132;
            #pragma unroll
            for (int t = 0; t < 8; ++t) sr[t*16 + col16] = (acc[t][r] - mean)*inv*g[t] + be[t];
        }
        float* gdst = outE + ((size_t)r0 * KK + wid*16) * 128;
        #pragma unroll
        for (int it = 0; it < 8; ++it) {
            int off = it*256 + lane*4;
            int rr = off >> 7, cc = off & 127;
            float4 v = *(const float4*)(sbuf + rr*132 + cc);
            *(float4*)(gdst + off) = v;
        }
        return;
    }

    // ==== V (nodes) ====
    {
        int r0 = (vb - VB_N) * NR;
        int nrows = (2048 - r0) < NR ? (2048 - r0) : NR;
        int natoms = nrows * MM;

        if (tid < nrows) {
            int row = r0 + tid;
            int b = row >> 10, i = row & 1023;
            const float* xr = X + ((size_t)b * LLEN + i) * 12;
            float nx=xr[0], ny=xr[1], nz=xr[2];
            float ax=xr[3], ay=xr[4], az=xr[5];
            float cx=xr[6], cy=xr[7], cz=xr[8];
            float bx=ax-nx, by=ay-ny, bz=az-nz;
            float vx=cx-ax, vy=cy-ay, vz=cz-az;
            float qx = by*vz - bz*vy, qy = bz*vx - bx*vz, qz = bx*vy - by*vx;
            sm.n.sat[tid][0]=nx; sm.n.sat[tid][1]=ny; sm.n.sat[tid][2]=nz;
            sm.n.sat[tid][3]=ax; sm.n.sat[tid][4]=ay; sm.n.sat[tid][5]=az;
            sm.n.sat[tid][6]=cx; sm.n.sat[tid][7]=cy; sm.n.sat[tid][8]=cz;
            sm.n.sat[tid][9]=xr[9]; sm.n.sat[tid][10]=xr[10]; sm.n.sat[tid][11]=xr[11];
            sm.n.sat[tid][12] = -0.58273431f*qx + 0.56802827f*bx - 0.54067466f*vx + ax;
            sm.n.sat[tid][13] = -0.58273431f*qy + 0.56802827f*by - 0.54067466f*vy + ay;
            sm.n.sat[tid][14] = -0.58273431f*qz + 0.56802827f*bz - 0.54067466f*vz + az;
            float e1x = nx-ax, e1y = ny-ay, e1z = nz-az;
            float n1 = fmaxf(sqrtf(e1x*e1x+e1y*e1y+e1z*e1z), 1e-12f);
            e1x/=n1; e1y/=n1; e1z/=n1;
            float dd = e1x*vx + e1y*vy + e1z*vz;
            float u2x = vx - e1x*dd, u2y = vy - e1y*dd, u2z = vz - e1z*dd;
            float n2 = fmaxf(sqrtf(u2x*u2x+u2y*u2y+u2z*u2z), 1e-12f);
            u2x/=n2; u2y/=n2; u2z/=n2;
            sm.n.sfr[tid][0]=e1x; sm.n.sfr[tid][1]=e1y; sm.n.sfr[tid][2]=e1z;
            sm.n.sfr[tid][3]=u2x; sm.n.sfr[tid][4]=u2y; sm.n.sfr[tid][5]=u2z;
            sm.n.sfr[tid][6]=e1y*u2z - e1z*u2y;
            sm.n.sfr[tid][7]=e1z*u2x - e1x*u2z;
            sm.n.sfr[tid][8]=e1x*u2y - e1y*u2x;
        }
        __syncthreads();

        for (int item = tid; item < natoms * 10; item += 256) {
            int a = item / 10, it = item - a * 10;
            int rl = a / MM, m = a - rl * MM;
            int row = r0 + rl;
            const float* Yb = Y + (size_t)row * MM * 3 + m * 3;
            union { short8_t v[2]; __hip_bfloat16 h[16]; } uf;
            if (it < 5) {
                float dx = sm.n.sat[rl][it*3+0] - Yb[0];
                float dy = sm.n.sat[rl][it*3+1] - Yb[1];
                float dz = sm.n.sat[rl][it*3+2] - Yb[2];
                float dist = sqrtf(dx*dx + dy*dy + dz*dz + 1e-6f);
                #pragma unroll
                for (int r = 0; r < 16; ++r) uf.h[r] = __float2bfloat16(rbf_val(dist, r));
            } else if (it < 9) {
                int qq = it - 5;
                int t = Yt[row*MM + m];
                int p1 = ptab[120 + t], p2 = ptab[240 + t];
                #pragma unroll
                for (int c = 0; c < 16; ++c) {
                    int cc = qq*16 + c;
                    uf.h[c] = __float2bfloat16(typeW[t*64 + cc] + typeW[(120+p1)*64 + cc]
                            + typeW[(139+p2)*64 + cc] + typeb[cc]);
                }
            } else {
                float vx = Yb[0] - sm.n.sat[rl][3];
                float vy = Yb[1] - sm.n.sat[rl][4];
                float vz = Yb[2] - sm.n.sat[rl][5];
                float l0 = sm.n.sfr[rl][0]*vx + sm.n.sfr[rl][1]*vy + sm.n.sfr[rl][2]*vz;
                float l1 = sm.n.sfr[rl][3]*vx + sm.n.sfr[rl][4]*vy + sm.n.sfr[rl][5]*vz;
                float l2 = sm.n.sfr[rl][6]*vx + sm.n.sfr[rl][7]*vy + sm.n.sfr[rl][8]*vz;
                float rxy  = sqrtf(l0*l0 + l1*l1 + 1e-8f);
                float rxyz = sqrtf(l0*l0 + l1*l1 + l2*l2) + 1e-8f;
                uf.h[0] = __float2bfloat16(l0 / rxy);
                uf.h[1] = __float2bfloat16(l1 / rxy);
                uf.h[2] = __float2bfloat16(rxy / rxyz);
                uf.h[3] = __float2bfloat16(l2 / rxyz);
                #pragma unroll
                for (int c = 4; c < 16; ++c) uf.h[c] = __float2bfloat16(0.0f);
            }
            short8_t* dst = (short8_t*)(sm.n.A + a * KP2 + it * 16);
            dst[0] = uf.v[0];
            dst[1] = uf.v[1];
        }
        __syncthreads();

        int wid = tid >> 6;
        const short8_t* Bp = (const short8_t*)Bpack3;
        float g[8], be[8], bias[8];
        #pragma unroll
        for (int t = 0; t < 8; ++t) {
            g[t] = lnNg[t*16 + col16]; be[t] = lnNb[t*16 + col16];
            bias[t] = npdb[t*16 + col16];
        }
        #pragma unroll
        for (int half = 0; half < 2; ++half) {
            int tile = wid + half*4;
            int abase = tile * 16;
            if (abase < natoms) {
                const __hip_bfloat16* Ar = sm.n.A + (abase + col16) * KP2 + kg * 8;
                f32x4 acc[8];
                #pragma unroll
                for (int t = 0; t < 8; ++t) acc[t] = (f32x4){0.f, 0.f, 0.f, 0.f};
                for (int ks = 0; ks < 5; ++ks) {
                    short8_t a = *(const short8_t*)(Ar + ks*32);
                    #pragma unroll
                    for (int t = 0; t < 8; ++t) {
                        short8_t bf = Bp[(ks*8 + t)*64 + lane];
                        acc[t] = __builtin_amdgcn_mfma_f32_16x16x32_bf16(a, bf, acc[t], 0, 0, 0);
                    }
                }
                #pragma unroll
                for (int r = 0; r < 4; ++r) {
                    float s = 0.0f;
                    #pragma unroll
                    for (int t = 0; t < 8; ++t) { acc[t][r] += bias[t]; s += acc[t][r]; }
                    s += __shfl_xor(s, 1); s += __shfl_xor(s, 2);
                    s += __shfl_xor(s, 4); s += __shfl_xor(s, 8);
                    float mean = s * (1.0f/128.0f);
                    float q2 = 0.0f;
                    #pragma unroll
                    for (int t = 0; t < 8; ++t) { float c0 = acc[t][r] - mean; q2 += c0*c0; }
                    q2 += __shfl_xor(q2, 1); q2 += __shfl_xor(q2, 2);
                    q2 += __shfl_xor(q2, 4); q2 += __shfl_xor(q2, 8);
                    float inv = rsqrtf(q2 * (1.0f/128.0f) + 1e-5f);
                    int aa = abase + kg*4 + r;
                    if (aa < natoms) {
                        float* dst = outV + ((size_t)r0 * MM + aa) * 128 + col16;
                        #pragma unroll
                        for (int t = 0; t < 8; ++t) dst[t*16] = (acc[t][r] - mean)*inv*g[t] + be[t];
                    }
                }
            }
        }
    }
}

// ---------------------------------------------------------------- launcher
extern "C" void kernel_launch(void* const* d_in, const int* in_sizes, int n_in,
                              void* d_out, int out_size, void* d_ws, size_t ws_size,
                              hipStream_t stream) {
    const float* X     = (const float*)d_in[0];
    const float* Y     = (const float*)d_in[1];
    const float* Ym    = (const float*)d_in[2];
    const int*   Yt    = (const int*)d_in[3];
    const float* mask  = (const float*)d_in[4];
    const int*   Ridx  = (const int*)d_in[5];
    const int*   chain = (const int*)d_in[6];
    const float* posW  = (const float*)d_in[7];
    const float* posb  = (const float*)d_in[8];
    const float* edgeW = (const float*)d_in[9];
    const float* lnEg  = (const float*)d_in[10];
    const float* lnEb  = (const float*)d_in[11];
    const float* npdW  = (const float*)d_in[12];
    const float* npdb  = (const float*)d_in[13];
    const float* lnNg  = (const float*)d_in[14];
    const float* lnNb  = (const float*)d_in[15];
    const float* typeW = (const float*)d_in[16];
    const float* typeb = (const float*)d_in[17];
    const float* ynW   = (const float*)d_in[18];
    const float* yeW   = (const float*)d_in[19];
    const float* lnYEg = (const float*)d_in[20];
    const float* lnYEb = (const float*)d_in[21];
    const float* lnYNg = (const float*)d_in[22];
    const float* lnYNb = (const float*)d_in[23];
    const int*   ptab  = (const int*)d_in[24];

    float* o = (float*)d_out;
    bool ws_ok = (ws_size >= (size_t)SCRATCH_BYTES);
    char* scratch = ws_ok ? (char*)d_ws : (char*)(o + OFF_YN);
    int*   eidx = (int*)scratch;
    float* dnb  = (float*)(scratch + BB*LLEN*KK*4);
    __hip_bfloat16* Bpack  = (__hip_bfloat16*)(scratch + 2*BB*LLEN*KK*4);
    __hip_bfloat16* Bpack2 = Bpack + 6656*8;
    __hip_bfloat16* Bpack3 = Bpack2 + 512*8;

    if (ws_ok) {
        k_phase1<<<P1_END, 256, 0, stream>>>(0, X, mask, edgeW, yeW, npdW,
            Bpack, Bpack2, Bpack3, eidx, dnb, o + OFF_EI,
            Yt, Ym, ptab, ynW, lnYNg, lnYNb, o + OFF_YN, o + OFF_YM);
        k_phase2<<<VB_END, 256, 0, stream>>>(
            X, Y, Ridx, chain, posW, posb, Bpack, lnEg, lnEb, eidx, dnb,
            Yt, typeW, typeb, ptab, Bpack3, npdb, lnNg, lnNb,
            Bpack2, lnYEg, lnYEb, o + OFF_V, o + OFF_E, o + OFF_YE);
    } else {
        k_phase1<<<P1_YN, 256, 0, stream>>>(0, X, mask, edgeW, yeW, npdW,
            Bpack, Bpack2, Bpack3, eidx, dnb, o + OFF_EI,
            Yt, Ym, ptab, ynW, lnYNg, lnYNb, o + OFF_YN, o + OFF_YM);
        k_phase2<<<VB_END, 256, 0, stream>>>(
            X, Y, Ridx, chain, posW, posb, Bpack, lnEg, lnEb, eidx, dnb,
            Yt, typeW, typeb, ptab, Bpack3, npdb, lnNg, lnNb,
            Bpack2, lnYEg, lnYEb, o + OFF_V, o + OFF_E, o + OFF_YE);
        k_phase1<<<P1_END - P1_YN, 256, 0, stream>>>(P1_YN, X, mask, edgeW, yeW, npdW,
            Bpack, Bpack2, Bpack3, eidx, dnb, o + OFF_EI,
            Yt, Ym, ptab, ynW, lnYNg, lnYNb, o + OFF_YN, o + OFF_YM);
    }
}

// Round 15
// 197.132 us; speedup vs baseline: 7.6093x; 1.0249x over previous
//
#include <hip/hip_runtime.h>
#include <hip/hip_bf16.h>
#include <stdint.h>

#define BB 2
#define LLEN 1024
#define MM 25
#define KK 32

// d_out is FLOAT32, concatenated in return order:
// (V, E, E_idx, Y_nodes, Y_edges, Y_m) — offsets in f32 elements.
#define OFF_V   0
#define OFF_E   6553600
#define OFF_EI  14942208
#define OFF_YN  15007744
#define OFF_YE  21561344
#define OFF_YM  185401344

#define KP 424          // edge A-tile row stride (bf16)
#define KP2 168         // node A-tile row stride (bf16)
#define NR 5            // rows per nodes block

// phase-1 virtual blocks: [0,512) topk | [512,550) prep | [550,13350) ynodes
#define P1_PREP 512
#define P1_YN   550
#define P1_END  (P1_YN + BB*LLEN*MM/4)   // 13350
// phase-2 virtual blocks: [0,2048) yedges | [2048,3072) edges | [3072,3482) nodes
#define NB_YE  (BB*LLEN)                      // 2048
#define VB_E   NB_YE
#define VB_N   (VB_E + BB*LLEN/2)             // 3072
#define VB_END (VB_N + (BB*LLEN+NR-1)/NR)     // 3482
#define NB_OTH (VB_END - NB_YE)               // 1434 (edges+nodes)
#define INTERL (2*NB_OTH)                     // 2868

#define SCRATCH_BYTES (680*1024)

typedef __attribute__((ext_vector_type(8))) short short8_t;
typedef __attribute__((ext_vector_type(4))) float f32x4;

__constant__ int g_PA[24] = {0,2,3,4,1,1,1,1,0,0,0,4,4,3,0,2,3,4,2,3,4,2,3,2};
__constant__ int g_PB[24] = {0,2,3,4,0,2,3,4,2,3,4,2,3,2,1,1,1,1,0,0,0,4,4,3};

__device__ __forceinline__ float rbf_val(float d, int r) {
    float mu = 2.0f + (20.0f / 15.0f) * (float)r;
    float z = (d - mu) * 0.8f;
    return __expf(-z * z);
}

// ------------------------------------------------- phase 1: topk + prep + ynodes
__global__ __launch_bounds__(256) void k_phase1(
    int vbase,
    const float* __restrict__ X, const float* __restrict__ mask,
    const float* __restrict__ W, const float* __restrict__ yeW,
    const float* __restrict__ npdW,
    __hip_bfloat16* __restrict__ Bp, __hip_bfloat16* __restrict__ Bp2,
    __hip_bfloat16* __restrict__ Bp3,
    int* __restrict__ eidx, float* __restrict__ dnb,
    float* __restrict__ outEI,
    const int* __restrict__ Yt, const float* __restrict__ Ym,
    const int* __restrict__ ptab, const float* __restrict__ ynW,
    const float* __restrict__ lnYNg, const float* __restrict__ lnYNb,
    float* __restrict__ outYN, float* __restrict__ outYM)
{
    __shared__ float sx[1024], syy[1024], sz[1024], smk[1024];
    int vb = blockIdx.x + vbase;
    int tid = threadIdx.x;
    int wid = tid >> 6, lane = tid & 63;

    if (vb >= P1_YN) {                    // ---- ynodes (light, input-only deps)
        int row = (vb - P1_YN) * 4 + wid;
        int t = Yt[row];
        int p1 = ptab[120 + t], p2 = ptab[240 + t];
        int r0 = t, r1 = 120 + p1, r2 = 139 + p2;
        float x0 = ynW[r0*128 + lane] + ynW[r1*128 + lane] + ynW[r2*128 + lane];
        float x1 = ynW[r0*128 + 64 + lane] + ynW[r1*128 + 64 + lane] + ynW[r2*128 + 64 + lane];
        float s = x0 + x1, s2 = x0*x0 + x1*x1;
        #pragma unroll
        for (int o = 1; o < 64; o <<= 1) { s += __shfl_xor(s, o); s2 += __shfl_xor(s2, o); }
        float mean = s * (1.0f/128.0f);
        float var  = s2 * (1.0f/128.0f) - mean*mean;
        float inv  = rsqrtf(var + 1e-5f);
        size_t base = (size_t)row * 128;
        outYN[base + lane]      = (x0 - mean)*inv*lnYNg[lane]    + lnYNb[lane];
        outYN[base + 64 + lane] = (x1 - mean)*inv*lnYNg[64+lane] + lnYNb[64+lane];
        if (lane == 0) outYM[row] = Ym[row];
        return;
    }

    if (vb >= P1_PREP) {                  // ---- B-pack prep
        int idx = (vb - P1_PREP) * 256 + tid;
        if (idx < 6656) {
            int ln = idx & 63, tt = (idx >> 6) & 7, ks = idx >> 9;
            int k0 = ks*32 + (ln >> 4)*8;
            int n  = tt*16 + (ln & 15);
            __hip_bfloat16* dst = Bp + (size_t)idx * 8;
            #pragma unroll
            for (int j = 0; j < 8; ++j) dst[j] = __float2bfloat16(W[(size_t)(k0 + j)*128 + n]);
        } else if (idx < 7168) {
            int i2 = idx - 6656;
            int ln = i2 & 63, tt = i2 >> 6;
            int kg = ln >> 4;
            int n  = tt*16 + (ln & 15);
            __hip_bfloat16* dst = Bp2 + (size_t)i2 * 8;
            #pragma unroll
            for (int j = 0; j < 8; ++j) {
                float v = (kg < 2) ? yeW[(size_t)(kg*8 + j)*128 + n] : 0.0f;
                dst[j] = __float2bfloat16(v);
            }
        } else if (idx < 9728) {
            int i3 = idx - 7168;
            int ln = i3 & 63, tt = (i3 >> 6) & 7, ks = i3 >> 9;
            int k0 = ks*32 + (ln >> 4)*8;
            int n  = tt*16 + (ln & 15);
            __hip_bfloat16* dst = Bp3 + (size_t)i3 * 8;
            #pragma unroll
            for (int j = 0; j < 8; ++j) {
                int k = k0 + j;
                float v = (k < 148) ? npdW[(size_t)k*128 + n] : 0.0f;
                dst[j] = __float2bfloat16(v);
            }
        }
        return;
    }

    // ---- top-k (validated wave tournament, LDS-staged coords)
    int row0 = vb * 4;
    int b = row0 >> 10;
    const float* Xb = X + (size_t)b * LLEN * 12;
    const float* mb = mask + b * LLEN;
    for (int j = tid; j < 1024; j += 256) {
        sx[j]  = Xb[j*12+3];
        syy[j] = Xb[j*12+4];
        sz[j]  = Xb[j*12+5];
        smk[j] = mb[j];
    }
    __syncthreads();

    int row = row0 + wid, i = row & 1023;
    float cax = sx[i], cay = syy[i], caz = sz[i];
    float mi = smk[i];

    float df[16], mm_[16];
    float lmax = 0.0f;
    #pragma unroll
    for (int q = 0; q < 16; ++q) {
        int j = q*64 + lane;
        float dx = cax - sx[j];
        float dy = cay - syy[j];
        float dz = caz - sz[j];
        float m2 = mi * smk[j];
        float d = sqrtf(dx*dx + dy*dy + dz*dz + 1e-6f) * m2;
        df[q] = d; mm_[q] = m2;
        lmax = fmaxf(lmax, d);
    }
    #pragma unroll
    for (int o = 32; o > 0; o >>= 1) lmax = fmaxf(lmax, __shfl_xor(lmax, o));

    unsigned long long pack[16];
    #pragma unroll
    for (int q = 0; q < 16; ++q) {
        float da = df[q] + (1.0f - mm_[q]) * lmax;
        pack[q] = ((unsigned long long)__float_as_uint(da) << 32) | (unsigned)(q*64 + lane);
    }

    int   myJw = 0;
    float myDv = 0.0f;
    for (int it = 0; it < KK; ++it) {
        unsigned long long lmin = pack[0];
        #pragma unroll
        for (int q = 1; q < 16; ++q) if (pack[q] < lmin) lmin = pack[q];
        #pragma unroll
        for (int o = 32; o > 0; o >>= 1) {
            unsigned long long other = __shfl_xor(lmin, o);
            if (other < lmin) lmin = other;
        }
        int jw = (int)(lmin & 0xffffffffu);
        if (lane == it) { myJw = jw; myDv = __uint_as_float((unsigned)(lmin >> 32)); }
        int lw = jw & 63, qw = jw >> 6;
        #pragma unroll
        for (int q = 0; q < 16; ++q)
            if (lane == lw && q == qw) pack[q] = ~0ull;
    }
    if (lane < KK) {
        eidx[row*KK + lane]  = myJw;
        dnb [row*KK + lane]  = myDv;
        outEI[row*KK + lane] = (float)myJw;
    }
}

// ---------------------------------------------------------------- phase 2: yedges + edges + nodes
union SMem {
    struct { __hip_bfloat16 A[64*KP]; float aj[64][16]; float ai[2][16]; int didx[64]; } e;
    struct { __hip_bfloat16 A[128*KP2]; float sat[NR][15]; float sfr[NR][9]; } n;
    struct { float sy4[32][4]; float stage[4][16*132]; } y;
};

__global__ __launch_bounds__(256) void k_phase2(
    const float* __restrict__ X, const float* __restrict__ Y,
    const int* __restrict__ Ridx, const int* __restrict__ chain,
    const float* __restrict__ posW, const float* __restrict__ posb,
    const __hip_bfloat16* __restrict__ Bpack,
    const float* __restrict__ lnEg, const float* __restrict__ lnEb,
    const int* __restrict__ eidx, const float* __restrict__ dnb,
    const int* __restrict__ Yt,
    const float* __restrict__ typeW, const float* __restrict__ typeb,
    const int* __restrict__ ptab,
    const __hip_bfloat16* __restrict__ Bpack3, const float* __restrict__ npdb,
    const float* __restrict__ lnNg, const float* __restrict__ lnNb,
    const __hip_bfloat16* __restrict__ Bpack2,
    const float* __restrict__ lnYEg, const float* __restrict__ lnYEb,
    float* __restrict__ outV, float* __restrict__ outE,
    float* __restrict__ outYE)
{
    __shared__ __align__(16) SMem sm;
    // Interleave dispatch order: even raw -> yedges (write-bound), odd raw ->
    // edges/nodes (compute-bound). NT stores on all outputs keep L2 clean for
    // the per-block Bpack re-reads.
    int raw = blockIdx.x;
    int vb;
    if (raw < INTERL) {
        int pair = raw >> 1;
        vb = (raw & 1) ? (NB_YE + pair) : pair;
    } else {
        vb = (raw - INTERL) + NB_OTH;       // yedges NB_OTH..2047
    }
    int tid = threadIdx.x;
    int wv = tid >> 6, lane = tid & 63;
    int col16 = lane & 15, kg = lane >> 4;

    if (vb < NB_YE) {                      // ==== Y_edges ====
        int row = vb;
        if (tid < 32) { sm.y.sy4[tid][0]=0.f; sm.y.sy4[tid][1]=0.f; sm.y.sy4[tid][2]=0.f; sm.y.sy4[tid][3]=0.f; }
        __syncthreads();
        if (tid < MM*3) ((float*)sm.y.sy4)[ (tid/3)*4 + (tid%3) ] = Y[(size_t)row * MM * 3 + tid];

        short8_t bfr[8];
        const short8_t* B2 = (const short8_t*)Bpack2;
        #pragma unroll
        for (int t = 0; t < 8; ++t) bfr[t] = B2[t*64 + lane];
        float g[8], be[8];
        #pragma unroll
        for (int t = 0; t < 8; ++t) { g[t] = lnYEg[t*16 + col16]; be[t] = lnYEb[t*16 + col16]; }
        __syncthreads();

        float* outR = outYE + (size_t)row * 625 * 128;
        float* sbuf = sm.y.stage[wv];
        for (int T = wv; T < 40; T += 4) {
            int p0 = T * 16;
            int p  = p0 + col16;
            int pc = p < 624 ? p : 624;
            int m1 = pc / 25, m2 = pc - 25*m1;
            float dx = sm.y.sy4[m1][0] - sm.y.sy4[m2][0];
            float dy = sm.y.sy4[m1][1] - sm.y.sy4[m2][1];
            float dz = sm.y.sy4[m1][2] - sm.y.sy4[m2][2];
            float d = sqrtf(dx*dx + dy*dy + dz*dz + 1e-6f);
            union { short8_t v; __hip_bfloat16 h[8]; } ua;
            if (kg < 2) {
                #pragma unroll
                for (int j = 0; j < 8; ++j) ua.h[j] = __float2bfloat16(rbf_val(d, kg*8 + j));
            } else {
                ua.v = (short8_t){0,0,0,0,0,0,0,0};
            }
            f32x4 acc[8];
            #pragma unroll
            for (int t = 0; t < 8; ++t)
                acc[t] = __builtin_amdgcn_mfma_f32_16x16x32_bf16(ua.v, bfr[t],
                             (f32x4){0.f,0.f,0.f,0.f}, 0, 0, 0);
            #pragma unroll
            for (int r = 0; r < 4; ++r) {
                float s = 0.0f;
                #pragma unroll
                for (int t = 0; t < 8; ++t) s += acc[t][r];
                s += __shfl_xor(s, 1); s += __shfl_xor(s, 2);
                s += __shfl_xor(s, 4); s += __shfl_xor(s, 8);
                float mean = s * (1.0f/128.0f);
                float q2 = 0.0f;
                #pragma unroll
                for (int t = 0; t < 8; ++t) { float c0 = acc[t][r] - mean; q2 += c0*c0; }
                q2 += __shfl_xor(q2, 1); q2 += __shfl_xor(q2, 2);
                q2 += __shfl_xor(q2, 4); q2 += __shfl_xor(q2, 8);
                float inv = rsqrtf(q2 * (1.0f/128.0f) + 1e-5f);
                float* sr = sbuf + (kg*4 + r) * 132;
                #pragma unroll
                for (int t = 0; t < 8; ++t) sr[t*16 + col16] = (acc[t][r] - mean)*inv*g[t] + be[t];
            }
            #pragma unroll
            for (int it = 0; it < 8; ++it) {
                int off = it*256 + lane*4;
                int rr = (off >> 7), cc = off & 127;
                f32x4 v = *(const f32x4*)(sbuf + rr*132 + cc);
                int gbase = p0*128 + off;
                if (gbase < 80000) __builtin_nontemporal_store(v, (f32x4*)(outR + gbase));
            }
        }
        return;
    }

    if (vb < VB_N) {                       // ==== E (edges) ====
        int r0 = (vb - VB_E) * 2;
        int b  = r0 >> 10;
        const float* Xb = X + (size_t)b * LLEN * 12;

        if (tid < 64) {
            int e = tid, row = r0 + (e >> 5), k = e & 31;
            int j = eidx[row*KK + k];
            const float* xr = Xb + j*12;
            float nx=xr[0], ny=xr[1], nz=xr[2];
            float ax=xr[3], ay=xr[4], az=xr[5];
            float cx=xr[6], cy=xr[7], cz=xr[8];
            float bx=ax-nx, by=ay-ny, bz=az-nz;
            float vx=cx-ax, vy=cy-ay, vz=cz-az;
            float qx = by*vz - bz*vy, qy = bz*vx - bx*vz, qz = bx*vy - by*vx;
            sm.e.aj[e][0]=nx; sm.e.aj[e][1]=ny; sm.e.aj[e][2]=nz;
            sm.e.aj[e][3]=ax; sm.e.aj[e][4]=ay; sm.e.aj[e][5]=az;
            sm.e.aj[e][6]=cx; sm.e.aj[e][7]=cy; sm.e.aj[e][8]=cz;
            sm.e.aj[e][9]=xr[9]; sm.e.aj[e][10]=xr[10]; sm.e.aj[e][11]=xr[11];
            sm.e.aj[e][12] = -0.58273431f*qx + 0.56802827f*bx - 0.54067466f*vx + ax;
            sm.e.aj[e][13] = -0.58273431f*qy + 0.56802827f*by - 0.54067466f*vy + ay;
            sm.e.aj[e][14] = -0.58273431f*qz + 0.56802827f*bz - 0.54067466f*vz + az;
            int off = Ridx[row] - Ridx[b*LLEN + j];
            int ec = (chain[row] == chain[b*LLEN + j]) ? 1 : 0;
            int dc = off + 32; dc = dc < 0 ? 0 : (dc > 64 ? 64 : dc);
            sm.e.didx[e] = ec ? dc : 65;
        }
        if (tid >= 64 && tid < 66) {
            int rl = tid - 64;
            int i = (r0 + rl) & 1023;
            const float* xr = Xb + i*12;
            float nx=xr[0], ny=xr[1], nz=xr[2];
            float ax=xr[3], ay=xr[4], az=xr[5];
            float cx=xr[6], cy=xr[7], cz=xr[8];
            float bx=ax-nx, by=ay-ny, bz=az-nz;
            float vx=cx-ax, vy=cy-ay, vz=cz-az;
            float qx = by*vz - bz*vy, qy = bz*vx - bx*vz, qz = bx*vy - by*vx;
            sm.e.ai[rl][0]=nx; sm.e.ai[rl][1]=ny; sm.e.ai[rl][2]=nz;
            sm.e.ai[rl][3]=ax; sm.e.ai[rl][4]=ay; sm.e.ai[rl][5]=az;
            sm.e.ai[rl][6]=cx; sm.e.ai[rl][7]=cy; sm.e.ai[rl][8]=cz;
            sm.e.ai[rl][9]=xr[9]; sm.e.ai[rl][10]=xr[10]; sm.e.ai[rl][11]=xr[11];
            sm.e.ai[rl][12] = -0.58273431f*qx + 0.56802827f*bx - 0.54067466f*vx + ax;
            sm.e.ai[rl][13] = -0.58273431f*qy + 0.56802827f*by - 0.54067466f*vy + ay;
            sm.e.ai[rl][14] = -0.58273431f*qz + 0.56802827f*bz - 0.54067466f*vz + az;
        }
        __syncthreads();

        for (int item = tid; item < 64 * 26; item += 256) {
            int e = item / 26, it = item - e * 26;
            int rl = e >> 5;
            union { short8_t v[2]; __hip_bfloat16 h[16]; } uf;
            if (it == 0) {
                int d = sm.e.didx[e];
                #pragma unroll
                for (int c = 0; c < 16; ++c) uf.h[c] = __float2bfloat16(posW[d*16 + c] + posb[c]);
            } else {
                float dist;
                if (it == 1) {
                    dist = dnb[(r0 + rl)*KK + (e & 31)];
                } else {
                    int p = it - 2;
                    int a = g_PA[p], q = g_PB[p];
                    float dx = sm.e.ai[rl][a*3+0] - sm.e.aj[e][q*3+0];
                    float dy = sm.e.ai[rl][a*3+1] - sm.e.aj[e][q*3+1];
                    float dz = sm.e.ai[rl][a*3+2] - sm.e.aj[e][q*3+2];
                    dist = sqrtf(dx*dx + dy*dy + dz*dz + 1e-6f);
                }
                #pragma unroll
                for (int r = 0; r < 16; ++r) uf.h[r] = __float2bfloat16(rbf_val(dist, r));
            }
            short8_t* dst = (short8_t*)(sm.e.A + e * KP + it * 16);
            dst[0] = uf.v[0];
            dst[1] = uf.v[1];
        }
        __syncthreads();

        int wid = tid >> 6;
        f32x4 acc[8];
        #pragma unroll
        for (int t = 0; t < 8; ++t) acc[t] = (f32x4){0.f, 0.f, 0.f, 0.f};
        const __hip_bfloat16* Ar = sm.e.A + (wid*16 + col16) * KP + kg * 8;
        const short8_t* Bp = (const short8_t*)Bpack;
        for (int ks = 0; ks < 13; ++ks) {
            short8_t a = *(const short8_t*)(Ar + ks*32);
            #pragma unroll
            for (int t = 0; t < 8; ++t) {
                short8_t bf = Bp[(ks*8 + t)*64 + lane];
                acc[t] = __builtin_amdgcn_mfma_f32_16x16x32_bf16(a, bf, acc[t], 0, 0, 0);
            }
        }
        __syncthreads();

        float* sbuf = (float*)sm.e.A + wid * (16*132);
        float g[8], be[8];
        #pragma unroll
        for (int t = 0; t < 8; ++t) { g[t] = lnEg[t*16 + col16]; be[t] = lnEb[t*16 + col16]; }
        #pragma unroll
        for (int r = 0; r < 4; ++r) {
            float s = 0.0f;
            #pragma unroll
            for (int t = 0; t < 8; ++t) s += acc[t][r];
            s += __shfl_xor(s, 1); s += __shfl_xor(s, 2);
            s += __shfl_xor(s, 4); s += __shfl_xor(s, 8);
            float mean = s * (1.0f/128.0f);
            float q2 = 0.0f;
            #pragma unroll
            for (int t = 0; t < 8; ++t) { float c0 = acc[t][r] - mean; q2 += c0*c0; }
            q2 += __shfl_xor(q2, 1); q2 += __shfl_xor(q2, 2);
            q2 += __shfl_xor(q2, 4); q2 += __shfl_xor(q2, 8);
            float inv = rsqrtf(q2 * (1.0f/128.0f) + 1e-5f);
            float* sr = sbuf + (kg*4 + r) * 132;
            #pragma unroll
            for (int t = 0; t < 8; ++t) sr[t*16 + col16] = (acc[t][r] - mean)*inv*g[t] + be[t];
        }
        float* gdst = outE + ((size_t)r0 * KK + wid*16) * 128;
        #pragma unroll
        for (int it = 0; it < 8; ++it) {
            int off = it*256 + lane*4;
            int rr = off >> 7, cc = off & 127;
            f32x4 v = *(const f32x4*)(sbuf + rr*132 + cc);
            __builtin_nontemporal_store(v, (f32x4*)(gdst + off));
        }
        return;
    }

    // ==== V (nodes) ====
    {
        int r0 = (vb - VB_N) * NR;
        int nrows = (2048 - r0) < NR ? (2048 - r0) : NR;
        int natoms = nrows * MM;

        if (tid < nrows) {
            int row = r0 + tid;
            int b = row >> 10, i = row & 1023;
            const float* xr = X + ((size_t)b * LLEN + i) * 12;
            float nx=xr[0], ny=xr[1], nz=xr[2];
            float ax=xr[3], ay=xr[4], az=xr[5];
            float cx=xr[6], cy=xr[7], cz=xr[8];
            float bx=ax-nx, by=ay-ny, bz=az-nz;
            float vx=cx-ax, vy=cy-ay, vz=cz-az;
            float qx = by*vz - bz*vy, qy = bz*vx - bx*vz, qz = bx*vy - by*vx;
            sm.n.sat[tid][0]=nx; sm.n.sat[tid][1]=ny; sm.n.sat[tid][2]=nz;
            sm.n.sat[tid][3]=ax; sm.n.sat[tid][4]=ay; sm.n.sat[tid][5]=az;
            sm.n.sat[tid][6]=cx; sm.n.sat[tid][7]=cy; sm.n.sat[tid][8]=cz;
            sm.n.sat[tid][9]=xr[9]; sm.n.sat[tid][10]=xr[10]; sm.n.sat[tid][11]=xr[11];
            sm.n.sat[tid][12] = -0.58273431f*qx + 0.56802827f*bx - 0.54067466f*vx + ax;
            sm.n.sat[tid][13] = -0.58273431f*qy + 0.56802827f*by - 0.54067466f*vy + ay;
            sm.n.sat[tid][14] = -0.58273431f*qz + 0.56802827f*bz - 0.54067466f*vz + az;
            float e1x = nx-ax, e1y = ny-ay, e1z = nz-az;
            float n1 = fmaxf(sqrtf(e1x*e1x+e1y*e1y+e1z*e1z), 1e-12f);
            e1x/=n1; e1y/=n1; e1z/=n1;
            float dd = e1x*vx + e1y*vy + e1z*vz;
            float u2x = vx - e1x*dd, u2y = vy - e1y*dd, u2z = vz - e1z*dd;
            float n2 = fmaxf(sqrtf(u2x*u2x+u2y*u2y+u2z*u2z), 1e-12f);
            u2x/=n2; u2y/=n2; u2z/=n2;
            sm.n.sfr[tid][0]=e1x; sm.n.sfr[tid][1]=e1y; sm.n.sfr[tid][2]=e1z;
            sm.n.sfr[tid][3]=u2x; sm.n.sfr[tid][4]=u2y; sm.n.sfr[tid][5]=u2z;
            sm.n.sfr[tid][6]=e1y*u2z - e1z*u2y;
            sm.n.sfr[tid][7]=e1z*u2x - e1x*u2z;
            sm.n.sfr[tid][8]=e1x*u2y - e1y*u2x;
        }
        __syncthreads();

        for (int item = tid; item < natoms * 10; item += 256) {
            int a = item / 10, it = item - a * 10;
            int rl = a / MM, m = a - rl * MM;
            int row = r0 + rl;
            const float* Yb = Y + (size_t)row * MM * 3 + m * 3;
            union { short8_t v[2]; __hip_bfloat16 h[16]; } uf;
            if (it < 5) {
                float dx = sm.n.sat[rl][it*3+0] - Yb[0];
                float dy = sm.n.sat[rl][it*3+1] - Yb[1];
                float dz = sm.n.sat[rl][it*3+2] - Yb[2];
                float dist = sqrtf(dx*dx + dy*dy + dz*dz + 1e-6f);
                #pragma unroll
                for (int r = 0; r < 16; ++r) uf.h[r] = __float2bfloat16(rbf_val(dist, r));
            } else if (it < 9) {
                int qq = it - 5;
                int t = Yt[row*MM + m];
                int p1 = ptab[120 + t], p2 = ptab[240 + t];
                #pragma unroll
                for (int c = 0; c < 16; ++c) {
                    int cc = qq*16 + c;
                    uf.h[c] = __float2bfloat16(typeW[t*64 + cc] + typeW[(120+p1)*64 + cc]
                            + typeW[(139+p2)*64 + cc] + typeb[cc]);
                }
            } else {
                float vx = Yb[0] - sm.n.sat[rl][3];
                float vy = Yb[1] - sm.n.sat[rl][4];
                float vz = Yb[2] - sm.n.sat[rl][5];
                float l0 = sm.n.sfr[rl][0]*vx + sm.n.sfr[rl][1]*vy + sm.n.sfr[rl][2]*vz;
                float l1 = sm.n.sfr[rl][3]*vx + sm.n.sfr[rl][4]*vy + sm.n.sfr[rl][5]*vz;
                float l2 = sm.n.sfr[rl][6]*vx + sm.n.sfr[rl][7]*vy + sm.n.sfr[rl][8]*vz;
                float rxy  = sqrtf(l0*l0 + l1*l1 + 1e-8f);
                float rxyz = sqrtf(l0*l0 + l1*l1 + l2*l2) + 1e-8f;
                uf.h[0] = __float2bfloat16(l0 / rxy);
                uf.h[1] = __float2bfloat16(l1 / rxy);
                uf.h[2] = __float2bfloat16(rxy / rxyz);
                uf.h[3] = __float2bfloat16(l2 / rxyz);
                #pragma unroll
                for (int c = 4; c < 16; ++c) uf.h[c] = __float2bfloat16(0.0f);
            }
            short8_t* dst = (short8_t*)(sm.n.A + a * KP2 + it * 16);
            dst[0] = uf.v[0];
            dst[1] = uf.v[1];
        }
        __syncthreads();

        int wid = tid >> 6;
        const short8_t* Bp = (const short8_t*)Bpack3;
        float g[8], be[8], bias[8];
        #pragma unroll
        for (int t = 0; t < 8; ++t) {
            g[t] = lnNg[t*16 + col16]; be[t] = lnNb[t*16 + col16];
            bias[t] = npdb[t*16 + col16];
        }
        #pragma unroll
        for (int half = 0; half < 2; ++half) {
            int tile = wid + half*4;
            int abase = tile * 16;
            if (abase < natoms) {
                const __hip_bfloat16* Ar = sm.n.A + (abase + col16) * KP2 + kg * 8;
                f32x4 acc[8];
                #pragma unroll
                for (int t = 0; t < 8; ++t) acc[t] = (f32x4){0.f, 0.f, 0.f, 0.f};
                for (int ks = 0; ks < 5; ++ks) {
                    short8_t a = *(const short8_t*)(Ar + ks*32);
                    #pragma unroll
                    for (int t = 0; t < 8; ++t) {
                        short8_t bf = Bp[(ks*8 + t)*64 + lane];
                        acc[t] = __builtin_amdgcn_mfma_f32_16x16x32_bf16(a, bf, acc[t], 0, 0, 0);
                    }
                }
                #pragma unroll
                for (int r = 0; r < 4; ++r) {
                    float s = 0.0f;
                    #pragma unroll
                    for (int t = 0; t < 8; ++t) { acc[t][r] += bias[t]; s += acc[t][r]; }
                    s += __shfl_xor(s, 1); s += __shfl_xor(s, 2);
                    s += __shfl_xor(s, 4); s += __shfl_xor(s, 8);
                    float mean = s * (1.0f/128.0f);
                    float q2 = 0.0f;
                    #pragma unroll
                    for (int t = 0; t < 8; ++t) { float c0 = acc[t][r] - mean; q2 += c0*c0; }
                    q2 += __shfl_xor(q2, 1); q2 += __shfl_xor(q2, 2);
                    q2 += __shfl_xor(q2, 4); q2 += __shfl_xor(q2, 8);
                    float inv = rsqrtf(q2 * (1.0f/128.0f) + 1e-5f);
                    int aa = abase + kg*4 + r;
                    if (aa < natoms) {
                        float* dst = outV + ((size_t)r0 * MM + aa) * 128 + col16;
                        #pragma unroll
                        for (int t = 0; t < 8; ++t)
                            __builtin_nontemporal_store((acc[t][r] - mean)*inv*g[t] + be[t], dst + t*16);
                    }
                }
            }
        }
    }
}

// ---------------------------------------------------------------- launcher
extern "C" void kernel_launch(void* const* d_in, const int* in_sizes, int n_in,
                              void* d_out, int out_size, void* d_ws, size_t ws_size,
                              hipStream_t stream) {
    const float* X     = (const float*)d_in[0];
    const float* Y     = (const float*)d_in[1];
    const float* Ym    = (const float*)d_in[2];
    const int*   Yt    = (const int*)d_in[3];
    const float* mask  = (const float*)d_in[4];
    const int*   Ridx  = (const int*)d_in[5];
    const int*   chain = (const int*)d_in[6];
    const float* posW  = (const float*)d_in[7];
    const float* posb  = (const float*)d_in[8];
    const float* edgeW = (const float*)d_in[9];
    const float* lnEg  = (const float*)d_in[10];
    const float* lnEb  = (const float*)d_in[11];
    const float* npdW  = (const float*)d_in[12];
    const float* npdb  = (const float*)d_in[13];
    const float* lnNg  = (const float*)d_in[14];
    const float* lnNb  = (const float*)d_in[15];
    const float* typeW = (const float*)d_in[16];
    const float* typeb = (const float*)d_in[17];
    const float* ynW   = (const float*)d_in[18];
    const float* yeW   = (const float*)d_in[19];
    const float* lnYEg = (const float*)d_in[20];
    const float* lnYEb = (const float*)d_in[21];
    const float* lnYNg = (const float*)d_in[22];
    const float* lnYNb = (const float*)d_in[23];
    const int*   ptab  = (const int*)d_in[24];

    float* o = (float*)d_out;
    bool ws_ok = (ws_size >= (size_t)SCRATCH_BYTES);
    char* scratch = ws_ok ? (char*)d_ws : (char*)(o + OFF_YN);
    int*   eidx = (int*)scratch;
    float* dnb  = (float*)(scratch + BB*LLEN*KK*4);
    __hip_bfloat16* Bpack  = (__hip_bfloat16*)(scratch + 2*BB*LLEN*KK*4);
    __hip_bfloat16* Bpack2 = Bpack + 6656*8;
    __hip_bfloat16* Bpack3 = Bpack2 + 512*8;

    if (ws_ok) {
        k_phase1<<<P1_END, 256, 0, stream>>>(0, X, mask, edgeW, yeW, npdW,
            Bpack, Bpack2, Bpack3, eidx, dnb, o + OFF_EI,
            Yt, Ym, ptab, ynW, lnYNg, lnYNb, o + OFF_YN, o + OFF_YM);
        k_phase2<<<VB_END, 256, 0, stream>>>(
            X, Y, Ridx, chain, posW, posb, Bpack, lnEg, lnEb, eidx, dnb,
            Yt, typeW, typeb, ptab, Bpack3, npdb, lnNg, lnNb,
            Bpack2, lnYEg, lnYEb, o + OFF_V, o + OFF_E, o + OFF_YE);
    } else {
        k_phase1<<<P1_YN, 256, 0, stream>>>(0, X, mask, edgeW, yeW, npdW,
            Bpack, Bpack2, Bpack3, eidx, dnb, o + OFF_EI,
            Yt, Ym, ptab, ynW, lnYNg, lnYNb, o + OFF_YN, o + OFF_YM);
        k_phase2<<<VB_END, 256, 0, stream>>>(
            X, Y, Ridx, chain, posW, posb, Bpack, lnEg, lnEb, eidx, dnb,
            Yt, typeW, typeb, ptab, Bpack3, npdb, lnNg, lnNb,
            Bpack2, lnYEg, lnYEb, o + OFF_V, o + OFF_E, o + OFF_YE);
        k_phase1<<<P1_END - P1_YN, 256, 0, stream>>>(P1_YN, X, mask, edgeW, yeW, npdW,
            Bpack, Bpack2, Bpack3, eidx, dnb, o + OFF_EI,
            Yt, Ym, ptab, ynW, lnYNg, lnYNb, o + OFF_YN, o + OFF_YM);
    }
}